// Round 6
// baseline (8529.317 us; speedup 1.0000x reference)
//
#include <hip/hip_runtime.h>
#include <math.h>
#include <stdint.h>

#define N_NODES 10000
#define N_EDGES 160000
#define F 128
#define NB 8
#define HR 64
#define NSPEC 10
#define PI_F 3.14159265358979323846f
#define GEDGE 16
#define BL 4

__device__ __forceinline__ float silu_f(float x){ return x / (1.f + expf(-x)); }

// ---------------- species counting sort ----------------
__global__ void k_scnt(const int* __restrict__ spec, int* __restrict__ scnt)
{
    int n = blockIdx.x * 256 + threadIdx.x;
    if (n < N_NODES) atomicAdd(&scnt[spec[n]], 1);
}

__global__ void k_sscan(const int* __restrict__ scnt, int* __restrict__ sptr)
{
    if (threadIdx.x == 0) {
        int acc = 0;
        for (int s = 0; s < NSPEC; ++s) { sptr[s] = acc; acc += scnt[s]; }
        sptr[NSPEC] = acc;
    }
}

__global__ void k_sfill(const int* __restrict__ spec, const int* __restrict__ sptr,
                        int* __restrict__ scur, int* __restrict__ perm,
                        int* __restrict__ inv, int* __restrict__ specS)
{
    int n = blockIdx.x * 256 + threadIdx.x;
    if (n >= N_NODES) return;
    int s = spec[n];
    int pos = sptr[s] + atomicAdd(&scur[s], 1);
    perm[pos] = n; inv[n] = pos; specS[pos] = s;
}

// ---------------- receiver histogram (sorted ids) ----------------
__global__ void k_count(const int* __restrict__ recv, const int* __restrict__ inv,
                        int* __restrict__ counts)
{
    int e = blockIdx.x * 256 + threadIdx.x;
    if (e >= N_EDGES) return;
    atomicAdd(&counts[inv[recv[e]]], 1);
}

// ---------------- block-wide scan -> row_ptr ----------------
__global__ void k_scan(const int* __restrict__ counts, int* __restrict__ row_ptr)
{
    __shared__ int ps[1024];
    const int t = threadIdx.x;
    int base = t * 10;
    int loc[10];
    int sum = 0;
    #pragma unroll
    for (int j = 0; j < 10; ++j) {
        int idx = base + j;
        int c = (idx < N_NODES) ? counts[idx] : 0;
        loc[j] = c; sum += c;
    }
    ps[t] = sum;
    __syncthreads();
    for (int off = 1; off < 1024; off <<= 1) {
        int v = (t >= off) ? ps[t-off] : 0;
        __syncthreads();
        ps[t] += v;
        __syncthreads();
    }
    int ex = ps[t] - sum;
    #pragma unroll
    for (int j = 0; j < 10; ++j) {
        int idx = base + j;
        if (idx < N_NODES) row_ptr[idx] = ex;
        ex += loc[j];
    }
    if (t == 1023) row_ptr[N_NODES] = ex;
}

// ---------------- fill CSR edge list (sorted ids) ----------------
__global__ void k_fill(const int* __restrict__ recv, const int* __restrict__ inv,
                       const int* __restrict__ row_ptr,
                       int* __restrict__ cursor, int* __restrict__ elist)
{
    int e = blockIdx.x * 256 + threadIdx.x;
    if (e >= N_EDGES) return;
    int r = inv[recv[e]];
    int pos = atomicAdd(&cursor[r], 1);
    elist[row_ptr[r] + pos] = e;
}

// ---------------- position-order edge precompute ----------------
__global__ void k_edge_pre(const int* __restrict__ elist, const int* __restrict__ senders,
                           const int* __restrict__ inv, const float* __restrict__ vec,
                           float* __restrict__ sh_pos, float* __restrict__ basis_pos,
                           int* __restrict__ snd_pos)
{
    int p = blockIdx.x * 256 + threadIdx.x;
    if (p >= N_EDGES) return;
    const int e = elist[p];
    snd_pos[p] = inv[senders[e]];
    float x = vec[e*3+0], y = vec[e*3+1], z = vec[e*3+2];
    float r = sqrtf(x*x + y*y + z*z);
    r = fmaxf(r, 1e-9f);
    float invr = 1.f / r;
    x *= invr; y *= invr; z *= invr;
    const float s3=1.7320508075688772f, s5=2.23606797749979f, s7=2.6457513110645907f,
                s15=3.872983346207417f, s42=6.480740698407860f, s70=8.366600265340756f,
                s105=10.246950765959598f;
    float* S = sh_pos + (size_t)p*16;
    S[0]=1.f; S[1]=s3*x; S[2]=s3*y; S[3]=s3*z;
    S[4]=s15*x*y; S[5]=s15*y*z; S[6]=0.5f*s5*(3.f*z*z-1.f); S[7]=s15*x*z;
    S[8]=0.5f*s15*(x*x-y*y);
    S[9]=0.25f*s70*y*(3.f*x*x-y*y); S[10]=s105*x*y*z; S[11]=0.25f*s42*y*(5.f*z*z-1.f);
    S[12]=0.5f*s7*(5.f*z*z*z-3.f*z); S[13]=0.25f*s42*x*(5.f*z*z-1.f);
    S[14]=0.5f*s105*z*(x*x-y*y); S[15]=0.25f*s70*x*(x*x-3.f*y*y);
    float rc = fminf(r, 5.0f);
    float cut = 0.5f * (cosf(PI_F * rc * 0.2f) + 1.f);
    float pref = sqrtf(0.4f) * cut / r;
    float* B = basis_pos + (size_t)p*8;
    #pragma unroll
    for (int k = 1; k <= 8; ++k) B[k-1] = pref * sinf(PI_F * 0.2f * (float)k * r);
}

// ---------------- init scalA = emb (sorted ids) ----------------
__global__ void k_init_scal(const int* __restrict__ specS, const float* __restrict__ embW,
                            float* __restrict__ scalA)
{
    int tid = blockIdx.x * 256 + threadIdx.x;
    if (tid >= N_NODES * F) return;
    int n = tid >> 7, f = tid & 127;
    scalA[tid] = embW[specS[n]*F + f];
}

// ---------------- fused radial + per-node edge aggregation -> aggG[n][f][m] ----------------
// block = 1 sorted node, 256 threads: f = t&127, mh = t>>7
__global__ __launch_bounds__(256) void k_edge(
    const int layer,
    const int* __restrict__ row_ptr,
    const int* __restrict__ snd_pos,
    const float* __restrict__ sh_pos,
    const float* __restrict__ basis_pos,
    const float* __restrict__ rW1,
    const float* __restrict__ rb1,
    const float* __restrict__ rW2,
    const float* __restrict__ scal_in,
    float* __restrict__ aggG)
{
    __shared__ float W1s[NB*HR];
    __shared__ float b1s[HR];
    __shared__ float hS[GEDGE][HR];     // 4 KB
    __shared__ float rwS[GEDGE*512];    // 32 KB

    const int t = threadIdx.x;
    const int n = blockIdx.x;
    const int f = t & 127;
    const int mh = t >> 7;
    const int e4 = t >> 6;   // wave id 0..3
    const int j64 = t & 63;

    W1s[t] = rW1[layer*NB*HR + t];
    W1s[256 + t] = rW1[layer*NB*HR + 256 + t];
    if (t < HR) b1s[t] = rb1[layer*HR + t];

    const float* W2g = rW2 + (size_t)layer*HR*512;
    const float4* sh4 = (const float4*)sh_pos;

    float acc[8] = {0,0,0,0,0,0,0,0};
    const int istart = row_ptr[n], iend = row_ptr[n+1];
    __syncthreads();

    for (int g0 = istart; g0 < iend; g0 += GEDGE) {
        const int gcnt = min(GEDGE, iend - g0);

        // ---- phase A: h for edges of this group (wave e4 -> e_loc = e4, e4+4, ...)
        #pragma unroll
        for (int q = 0; q < 4; ++q) {
            int e = e4 + q*4;
            float a = b1s[j64];
            if (e < gcnt) {
                const float4* B4 = (const float4*)(basis_pos + (size_t)(g0 + e)*8);
                float4 x0 = B4[0], x1 = B4[1];
                a = fmaf(x0.x, W1s[0*HR + j64], a);
                a = fmaf(x0.y, W1s[1*HR + j64], a);
                a = fmaf(x0.z, W1s[2*HR + j64], a);
                a = fmaf(x0.w, W1s[3*HR + j64], a);
                a = fmaf(x1.x, W1s[4*HR + j64], a);
                a = fmaf(x1.y, W1s[5*HR + j64], a);
                a = fmaf(x1.z, W1s[6*HR + j64], a);
                a = fmaf(x1.w, W1s[7*HR + j64], a);
            }
            hS[e][j64] = a / (1.f + expf(-a));
        }
        __syncthreads();

        // ---- phase B: thread t computes rw columns (2t, 2t+1) for all edges of group
        float r0[GEDGE], r1[GEDGE];
        #pragma unroll
        for (int e = 0; e < GEDGE; ++e) { r0[e] = 0.f; r1[e] = 0.f; }
        for (int jt = 0; jt < 4; ++jt) {
            float2 w[16];
            #pragma unroll
            for (int j = 0; j < 16; ++j)
                w[j] = *(const float2*)(W2g + (size_t)(jt*16 + j)*512 + 2*t);
            #pragma unroll
            for (int e = 0; e < GEDGE; ++e) {
                if (e < gcnt) {
                    const float4 ha = *(const float4*)&hS[e][jt*16 + 0];
                    const float4 hb = *(const float4*)&hS[e][jt*16 + 4];
                    const float4 hc = *(const float4*)&hS[e][jt*16 + 8];
                    const float4 hd = *(const float4*)&hS[e][jt*16 + 12];
                    r0[e]=fmaf(ha.x,w[0].x,r0[e]);  r1[e]=fmaf(ha.x,w[0].y,r1[e]);
                    r0[e]=fmaf(ha.y,w[1].x,r0[e]);  r1[e]=fmaf(ha.y,w[1].y,r1[e]);
                    r0[e]=fmaf(ha.z,w[2].x,r0[e]);  r1[e]=fmaf(ha.z,w[2].y,r1[e]);
                    r0[e]=fmaf(ha.w,w[3].x,r0[e]);  r1[e]=fmaf(ha.w,w[3].y,r1[e]);
                    r0[e]=fmaf(hb.x,w[4].x,r0[e]);  r1[e]=fmaf(hb.x,w[4].y,r1[e]);
                    r0[e]=fmaf(hb.y,w[5].x,r0[e]);  r1[e]=fmaf(hb.y,w[5].y,r1[e]);
                    r0[e]=fmaf(hb.z,w[6].x,r0[e]);  r1[e]=fmaf(hb.z,w[6].y,r1[e]);
                    r0[e]=fmaf(hb.w,w[7].x,r0[e]);  r1[e]=fmaf(hb.w,w[7].y,r1[e]);
                    r0[e]=fmaf(hc.x,w[8].x,r0[e]);  r1[e]=fmaf(hc.x,w[8].y,r1[e]);
                    r0[e]=fmaf(hc.y,w[9].x,r0[e]);  r1[e]=fmaf(hc.y,w[9].y,r1[e]);
                    r0[e]=fmaf(hc.z,w[10].x,r0[e]); r1[e]=fmaf(hc.z,w[10].y,r1[e]);
                    r0[e]=fmaf(hc.w,w[11].x,r0[e]); r1[e]=fmaf(hc.w,w[11].y,r1[e]);
                    r0[e]=fmaf(hd.x,w[12].x,r0[e]); r1[e]=fmaf(hd.x,w[12].y,r1[e]);
                    r0[e]=fmaf(hd.y,w[13].x,r0[e]); r1[e]=fmaf(hd.y,w[13].y,r1[e]);
                    r0[e]=fmaf(hd.z,w[14].x,r0[e]); r1[e]=fmaf(hd.z,w[14].y,r1[e]);
                    r0[e]=fmaf(hd.w,w[15].x,r0[e]); r1[e]=fmaf(hd.w,w[15].y,r1[e]);
                }
            }
        }
        #pragma unroll
        for (int e = 0; e < GEDGE; ++e)
            ((float2*)rwS)[e*256 + t] = make_float2(r0[e], r1[e]);
        __syncthreads();

        // ---- phase C: accumulate messages
        #pragma unroll
        for (int e = 0; e < GEDGE; ++e) {
            if (e < gcnt) {
                const int ii = g0 + e;
                const int snd = snd_pos[ii];
                const float sf = scal_in[(size_t)snd*F + f];
                const float4 rwv = *(const float4*)(rwS + e*512 + 4*f);
                const float4 shA = sh4[(size_t)ii*4 + mh*2 + 0];
                const float4 shB = sh4[(size_t)ii*4 + mh*2 + 1];
                if (mh == 0) {   // m=0..7, l=[0,1,1,1,2,2,2,2]
                    const float a0 = sf*rwv.x, a1 = sf*rwv.y, a2 = sf*rwv.z;
                    acc[0] = fmaf(a0, shA.x, acc[0]);
                    acc[1] = fmaf(a1, shA.y, acc[1]);
                    acc[2] = fmaf(a1, shA.z, acc[2]);
                    acc[3] = fmaf(a1, shA.w, acc[3]);
                    acc[4] = fmaf(a2, shB.x, acc[4]);
                    acc[5] = fmaf(a2, shB.y, acc[5]);
                    acc[6] = fmaf(a2, shB.z, acc[6]);
                    acc[7] = fmaf(a2, shB.w, acc[7]);
                } else {         // m=8..15, l=[2,3,3,3,3,3,3,3]
                    const float a2 = sf*rwv.z, a3 = sf*rwv.w;
                    acc[0] = fmaf(a2, shA.x, acc[0]);
                    acc[1] = fmaf(a3, shA.y, acc[1]);
                    acc[2] = fmaf(a3, shA.z, acc[2]);
                    acc[3] = fmaf(a3, shA.w, acc[3]);
                    acc[4] = fmaf(a3, shB.x, acc[4]);
                    acc[5] = fmaf(a3, shB.y, acc[5]);
                    acc[6] = fmaf(a3, shB.z, acc[6]);
                    acc[7] = fmaf(a3, shB.w, acc[7]);
                }
            }
        }
        __syncthreads();  // protect rwS/hS before next group
    }

    float4* wp = (float4*)(aggG + (size_t)n*2048 + f*16 + mh*8);
    wp[0] = make_float4(acc[0], acc[1], acc[2], acc[3]);
    wp[1] = make_float4(acc[4], acc[5], acc[6], acc[7]);
}

// ---------------- species-batched linears + poly + readouts ----------------
__device__ __forceinline__ void lin_fma(const float4 agA, const float4 agB,
    float w0, float w1, float w2v, float w3, int mh, float* nv)
{
    if (mh == 0) {
        nv[0] = fmaf(agA.x, w0,  nv[0]);
        nv[1] = fmaf(agA.y, w1,  nv[1]);
        nv[2] = fmaf(agA.z, w1,  nv[2]);
        nv[3] = fmaf(agA.w, w1,  nv[3]);
        nv[4] = fmaf(agB.x, w2v, nv[4]);
        nv[5] = fmaf(agB.y, w2v, nv[5]);
        nv[6] = fmaf(agB.z, w2v, nv[6]);
        nv[7] = fmaf(agB.w, w2v, nv[7]);
    } else {
        nv[0] = fmaf(agA.x, w2v, nv[0]);
        nv[1] = fmaf(agA.y, w3,  nv[1]);
        nv[2] = fmaf(agA.z, w3,  nv[2]);
        nv[3] = fmaf(agA.w, w3,  nv[3]);
        nv[4] = fmaf(agB.x, w3,  nv[4]);
        nv[5] = fmaf(agB.y, w3,  nv[5]);
        nv[6] = fmaf(agB.z, w3,  nv[6]);
        nv[7] = fmaf(agB.w, w3,  nv[7]);
    }
}

template<int LAYER>
__global__ __launch_bounds__(256) void k_lin(
    const int* __restrict__ specS,
    const int* __restrict__ perm,
    const float* __restrict__ aggG,
    const float* __restrict__ linW,
    const float* __restrict__ prodc,
    const float* __restrict__ scW,
    const float* __restrict__ ro0,
    const float* __restrict__ ro1W1,
    const float* __restrict__ ro1W2,
    float* __restrict__ feats,
    float* __restrict__ scal_out,
    float* __restrict__ out)
{
    __shared__ float tA[BL][16][16];
    __shared__ float tF[BL][16][16];
    __shared__ float pS[BL][F];
    __shared__ float yS[BL][16];

    const int t = threadIdx.x;
    const int n0 = blockIdx.x * BL;
    const int f = t & 127;
    const int mh = t >> 7;
    const int j64 = t & 63;

    int sp[BL];
    #pragma unroll
    for (int b = 0; b < BL; ++b) sp[b] = specS[n0 + b];
    const bool uni = (sp[0]==sp[1]) && (sp[1]==sp[2]) && (sp[2]==sp[3]);

    float nv[BL][8];
    float scv[BL][8];
    #pragma unroll
    for (int b = 0; b < BL; ++b)
        #pragma unroll
        for (int j = 0; j < 8; ++j) { nv[b][j] = 0.f; scv[b][j] = 0.f; }

    const int n_loc = t >> 6;
    const int f_loc = (t >> 2) & 15;
    const int m4 = (t & 3) * 4;

    for (int kt = 0; kt < 8; ++kt) {
        {
            const size_t off = (size_t)(n0 + n_loc)*2048 + (size_t)(kt*16 + f_loc)*16 + m4;
            *(float4*)&tA[n_loc][f_loc][m4] = *(const float4*)(aggG + off);
            if (LAYER == 1)
                *(float4*)&tF[n_loc][f_loc][m4] = *(const float4*)(feats + off);
        }
        __syncthreads();

        if (uni) {
            const float* Wl = linW + (((size_t)LAYER*NSPEC + sp[0])*4)*(F*F);
            const float* Ws = scW  + (((size_t)LAYER*NSPEC + sp[0])*4)*(F*F);
            #pragma unroll
            for (int k = 0; k < 16; ++k) {
                const int f2 = kt*16 + k;
                float w0=0.f, w1=0.f, w2v, w3=0.f;
                float u0=0.f, u1=0.f, u2v=0.f, u3=0.f;
                if (mh == 0) {
                    w0  = Wl[(0*F + f2)*F + f];
                    w1  = Wl[(1*F + f2)*F + f];
                    w2v = Wl[(2*F + f2)*F + f];
                } else {
                    w2v = Wl[(2*F + f2)*F + f];
                    w3  = Wl[(3*F + f2)*F + f];
                }
                if (LAYER == 1) {
                    if (mh == 0) {
                        u0  = Ws[(0*F + f2)*F + f];
                        u1  = Ws[(1*F + f2)*F + f];
                        u2v = Ws[(2*F + f2)*F + f];
                    } else {
                        u2v = Ws[(2*F + f2)*F + f];
                        u3  = Ws[(3*F + f2)*F + f];
                    }
                }
                #pragma unroll
                for (int b = 0; b < BL; ++b) {
                    const float4 agA = *(const float4*)&tA[b][k][mh*8];
                    const float4 agB = *(const float4*)&tA[b][k][mh*8 + 4];
                    lin_fma(agA, agB, w0, w1, w2v, w3, mh, nv[b]);
                    if (LAYER == 1) {
                        const float4 ftA = *(const float4*)&tF[b][k][mh*8];
                        const float4 ftB = *(const float4*)&tF[b][k][mh*8 + 4];
                        lin_fma(ftA, ftB, u0, u1, u2v, u3, mh, scv[b]);
                    }
                }
            }
        } else {
            #pragma unroll 4
            for (int k = 0; k < 16; ++k) {
                const int f2 = kt*16 + k;
                #pragma unroll
                for (int b = 0; b < BL; ++b) {
                    const float* Wl = linW + (((size_t)LAYER*NSPEC + sp[b])*4)*(F*F);
                    float w0=0.f, w1=0.f, w2v, w3=0.f;
                    if (mh == 0) {
                        w0  = Wl[(0*F + f2)*F + f];
                        w1  = Wl[(1*F + f2)*F + f];
                        w2v = Wl[(2*F + f2)*F + f];
                    } else {
                        w2v = Wl[(2*F + f2)*F + f];
                        w3  = Wl[(3*F + f2)*F + f];
                    }
                    const float4 agA = *(const float4*)&tA[b][k][mh*8];
                    const float4 agB = *(const float4*)&tA[b][k][mh*8 + 4];
                    lin_fma(agA, agB, w0, w1, w2v, w3, mh, nv[b]);
                    if (LAYER == 1) {
                        const float* Ws = scW + (((size_t)LAYER*NSPEC + sp[b])*4)*(F*F);
                        float u0=0.f, u1=0.f, u2v, u3=0.f;
                        if (mh == 0) {
                            u0  = Ws[(0*F + f2)*F + f];
                            u1  = Ws[(1*F + f2)*F + f];
                            u2v = Ws[(2*F + f2)*F + f];
                        } else {
                            u2v = Ws[(2*F + f2)*F + f];
                            u3  = Ws[(3*F + f2)*F + f];
                        }
                        const float4 ftA = *(const float4*)&tF[b][k][mh*8];
                        const float4 ftB = *(const float4*)&tF[b][k][mh*8 + 4];
                        lin_fma(ftA, ftB, u0, u1, u2v, u3, mh, scv[b]);
                    }
                }
            }
        }
        __syncthreads();
    }

    // EPS
    #pragma unroll
    for (int b = 0; b < BL; ++b)
        #pragma unroll
        for (int j = 0; j < 8; ++j) nv[b][j] *= 0.5f;

    // poly gate
    if (mh == 0) {
        #pragma unroll
        for (int b = 0; b < BL; ++b) pS[b][f] = nv[b][0];
    }
    __syncthreads();
    float poly[BL];
    #pragma unroll
    for (int b = 0; b < BL; ++b) {
        const float* pc = prodc + ((size_t)LAYER*NSPEC + sp[b])*3*F;
        float sg = pS[b][f];
        poly[b] = pc[f] + pc[F+f]*sg + pc[2*F+f]*sg*sg;
    }
    #pragma unroll
    for (int b = 0; b < BL; ++b)
        #pragma unroll
        for (int j = 0; j < 8; ++j)
            nv[b][j] = fmaf(nv[b][j], poly[b], (LAYER == 1) ? scv[b][j] : 0.f);

    // write feats
    #pragma unroll
    for (int b = 0; b < BL; ++b) {
        float4* wp = (float4*)(feats + (size_t)(n0+b)*2048 + f*16 + mh*8);
        wp[0] = make_float4(nv[b][0], nv[b][1], nv[b][2], nv[b][3]);
        wp[1] = make_float4(nv[b][4], nv[b][5], nv[b][6], nv[b][7]);
    }
    if (mh == 0) {
        #pragma unroll
        for (int b = 0; b < BL; ++b) scal_out[(size_t)(n0+b)*F + f] = nv[b][0];
    }
    __syncthreads();  // pS reuse below

    if (LAYER == 0) {
        if (mh == 0) {
            #pragma unroll
            for (int b = 0; b < BL; ++b) pS[b][f] = nv[b][0] * ro0[f];
        }
        __syncthreads();
        const int w = t >> 6;   // wave w reduces node w
        float v = pS[w][j64] + pS[w][j64 + 64];
        #pragma unroll
        for (int off = 32; off > 0; off >>= 1) v += __shfl_down(v, off);
        if (j64 == 0) out[(size_t)perm[n0 + w]*2 + 0] = v;
    } else {
        if (mh == 0) {
            #pragma unroll
            for (int b = 0; b < BL; ++b) pS[b][f] = nv[b][0];
        }
        __syncthreads();
        if (t < 64) {
            const int b = t >> 4, c = t & 15;
            float a = 0.f;
            for (int g = 0; g < F; ++g) a = fmaf(pS[b][g], ro1W1[g*16 + c], a);
            a = silu_f(a);
            yS[b][c] = a * ro1W2[c];
        }
        __syncthreads();
        if (t < BL) {
            float s = 0.f;
            #pragma unroll
            for (int j = 0; j < 16; ++j) s += yS[t][j];
            out[(size_t)perm[n0 + t]*2 + 1] = s;
        }
    }
}

extern "C" void kernel_launch(void* const* d_in, const int* in_sizes, int n_in,
                              void* d_out, int out_size, void* d_ws, size_t ws_size,
                              hipStream_t stream)
{
    (void)in_sizes; (void)n_in; (void)out_size; (void)ws_size;
    const float* vectors   = (const float*)d_in[0];
    const int*   spec      = (const int*)d_in[1];
    const int*   senders   = (const int*)d_in[2];
    const int*   receivers = (const int*)d_in[3];
    const float* embW      = (const float*)d_in[4];
    const float* rW1       = (const float*)d_in[5];
    const float* rb1       = (const float*)d_in[6];
    const float* rW2       = (const float*)d_in[7];
    const float* linW      = (const float*)d_in[8];
    const float* prodc     = (const float*)d_in[9];
    const float* scW       = (const float*)d_in[10];
    const float* ro0       = (const float*)d_in[11];
    const float* ro1W1     = (const float*)d_in[12];
    const float* ro1W2     = (const float*)d_in[13];
    float* out = (float*)d_out;

    char* ws = (char*)d_ws;
    float* scalA     = (float*)ws; ws += sizeof(float)*(size_t)N_NODES*F;
    float* scalB     = (float*)ws; ws += sizeof(float)*(size_t)N_NODES*F;
    float* feats     = (float*)ws; ws += sizeof(float)*(size_t)N_NODES*F*16;
    float* aggG      = (float*)ws; ws += sizeof(float)*(size_t)N_NODES*F*16;
    float* sh_pos    = (float*)ws; ws += sizeof(float)*(size_t)N_EDGES*16;
    float* basis_pos = (float*)ws; ws += sizeof(float)*(size_t)N_EDGES*8;
    int*   snd_pos   = (int*)ws;   ws += sizeof(int)*N_EDGES;
    int*   row_ptr   = (int*)ws;   ws += sizeof(int)*(N_NODES+1);
    // zeroed region: counts, cursor, scnt, scur (contiguous)
    int*   counts    = (int*)ws;   ws += sizeof(int)*N_NODES;
    int*   cursor    = (int*)ws;   ws += sizeof(int)*N_NODES;
    int*   scnt      = (int*)ws;   ws += sizeof(int)*16;
    int*   scur      = (int*)ws;   ws += sizeof(int)*16;
    int*   sptr      = (int*)ws;   ws += sizeof(int)*16;
    int*   perm      = (int*)ws;   ws += sizeof(int)*N_NODES;
    int*   inv       = (int*)ws;   ws += sizeof(int)*N_NODES;
    int*   specS     = (int*)ws;   ws += sizeof(int)*N_NODES;
    int*   elist     = (int*)ws;   ws += sizeof(int)*N_EDGES;

    hipMemsetAsync(counts, 0, sizeof(int)*(2*N_NODES + 32), stream);

    const int EB = (N_EDGES + 255) / 256;
    const int NBK = (N_NODES + 255) / 256;

    k_scnt<<<NBK, 256, 0, stream>>>(spec, scnt);
    k_sscan<<<1, 64, 0, stream>>>(scnt, sptr);
    k_sfill<<<NBK, 256, 0, stream>>>(spec, sptr, scur, perm, inv, specS);
    k_count<<<EB, 256, 0, stream>>>(receivers, inv, counts);
    k_scan<<<1, 1024, 0, stream>>>(counts, row_ptr);
    k_fill<<<EB, 256, 0, stream>>>(receivers, inv, row_ptr, cursor, elist);
    k_edge_pre<<<EB, 256, 0, stream>>>(elist, senders, inv, vectors, sh_pos, basis_pos, snd_pos);
    k_init_scal<<<(N_NODES*F + 255)/256, 256, 0, stream>>>(specS, embW, scalA);

    k_edge<<<N_NODES, 256, 0, stream>>>(0, row_ptr, snd_pos, sh_pos, basis_pos,
        rW1, rb1, rW2, scalA, aggG);
    k_lin<0><<<N_NODES/BL, 256, 0, stream>>>(specS, perm, aggG, linW, prodc, scW,
        ro0, ro1W1, ro1W2, feats, scalB, out);

    k_edge<<<N_NODES, 256, 0, stream>>>(1, row_ptr, snd_pos, sh_pos, basis_pos,
        rW1, rb1, rW2, scalB, aggG);
    k_lin<1><<<N_NODES/BL, 256, 0, stream>>>(specS, perm, aggG, linW, prodc, scW,
        ro0, ro1W1, ro1W2, feats, scalA, out);
}

// Round 7
// 1468.089 us; speedup vs baseline: 5.8098x; 5.8098x over previous
//
#include <hip/hip_runtime.h>
#include <math.h>
#include <stdint.h>

#define N_NODES 10000
#define N_EDGES 160000
#define F 128
#define NB 8
#define HR 64
#define NSPEC 10
#define PI_F 3.14159265358979323846f
#define GEDGE 16
#define BL 4

__device__ __forceinline__ float silu_f(float x){ return x / (1.f + expf(-x)); }

// ---------------- species counting sort ----------------
__global__ void k_scnt(const int* __restrict__ spec, int* __restrict__ scnt)
{
    int n = blockIdx.x * 256 + threadIdx.x;
    if (n < N_NODES) atomicAdd(&scnt[spec[n]], 1);
}

__global__ void k_sscan(const int* __restrict__ scnt, int* __restrict__ sptr)
{
    if (threadIdx.x == 0) {
        int acc = 0;
        for (int s = 0; s < NSPEC; ++s) { sptr[s] = acc; acc += scnt[s]; }
        sptr[NSPEC] = acc;
    }
}

__global__ void k_sfill(const int* __restrict__ spec, const int* __restrict__ sptr,
                        int* __restrict__ scur, int* __restrict__ perm,
                        int* __restrict__ inv, int* __restrict__ specS)
{
    int n = blockIdx.x * 256 + threadIdx.x;
    if (n >= N_NODES) return;
    int s = spec[n];
    int pos = sptr[s] + atomicAdd(&scur[s], 1);
    perm[pos] = n; inv[n] = pos; specS[pos] = s;
}

// ---------------- receiver histogram (sorted ids) ----------------
__global__ void k_count(const int* __restrict__ recv, const int* __restrict__ inv,
                        int* __restrict__ counts)
{
    int e = blockIdx.x * 256 + threadIdx.x;
    if (e >= N_EDGES) return;
    atomicAdd(&counts[inv[recv[e]]], 1);
}

// ---------------- block-wide scan -> row_ptr ----------------
__global__ void k_scan(const int* __restrict__ counts, int* __restrict__ row_ptr)
{
    __shared__ int ps[1024];
    const int t = threadIdx.x;
    int base = t * 10;
    int loc[10];
    int sum = 0;
    #pragma unroll
    for (int j = 0; j < 10; ++j) {
        int idx = base + j;
        int c = (idx < N_NODES) ? counts[idx] : 0;
        loc[j] = c; sum += c;
    }
    ps[t] = sum;
    __syncthreads();
    for (int off = 1; off < 1024; off <<= 1) {
        int v = (t >= off) ? ps[t-off] : 0;
        __syncthreads();
        ps[t] += v;
        __syncthreads();
    }
    int ex = ps[t] - sum;
    #pragma unroll
    for (int j = 0; j < 10; ++j) {
        int idx = base + j;
        if (idx < N_NODES) row_ptr[idx] = ex;
        ex += loc[j];
    }
    if (t == 1023) row_ptr[N_NODES] = ex;
}

// ---------------- fill CSR edge list (sorted ids) ----------------
__global__ void k_fill(const int* __restrict__ recv, const int* __restrict__ inv,
                       const int* __restrict__ row_ptr,
                       int* __restrict__ cursor, int* __restrict__ elist)
{
    int e = blockIdx.x * 256 + threadIdx.x;
    if (e >= N_EDGES) return;
    int r = inv[recv[e]];
    int pos = atomicAdd(&cursor[r], 1);
    elist[row_ptr[r] + pos] = e;
}

// ---------------- position-order edge precompute ----------------
__global__ void k_edge_pre(const int* __restrict__ elist, const int* __restrict__ senders,
                           const int* __restrict__ inv, const float* __restrict__ vec,
                           float* __restrict__ sh_pos, float* __restrict__ basis_pos,
                           int* __restrict__ snd_pos)
{
    int p = blockIdx.x * 256 + threadIdx.x;
    if (p >= N_EDGES) return;
    const int e = elist[p];
    snd_pos[p] = inv[senders[e]];
    float x = vec[e*3+0], y = vec[e*3+1], z = vec[e*3+2];
    float r = sqrtf(x*x + y*y + z*z);
    r = fmaxf(r, 1e-9f);
    float invr = 1.f / r;
    x *= invr; y *= invr; z *= invr;
    const float s3=1.7320508075688772f, s5=2.23606797749979f, s7=2.6457513110645907f,
                s15=3.872983346207417f, s42=6.480740698407860f, s70=8.366600265340756f,
                s105=10.246950765959598f;
    float* S = sh_pos + (size_t)p*16;
    S[0]=1.f; S[1]=s3*x; S[2]=s3*y; S[3]=s3*z;
    S[4]=s15*x*y; S[5]=s15*y*z; S[6]=0.5f*s5*(3.f*z*z-1.f); S[7]=s15*x*z;
    S[8]=0.5f*s15*(x*x-y*y);
    S[9]=0.25f*s70*y*(3.f*x*x-y*y); S[10]=s105*x*y*z; S[11]=0.25f*s42*y*(5.f*z*z-1.f);
    S[12]=0.5f*s7*(5.f*z*z*z-3.f*z); S[13]=0.25f*s42*x*(5.f*z*z-1.f);
    S[14]=0.5f*s105*z*(x*x-y*y); S[15]=0.25f*s70*x*(x*x-3.f*y*y);
    float rc = fminf(r, 5.0f);
    float cut = 0.5f * (cosf(PI_F * rc * 0.2f) + 1.f);
    float pref = sqrtf(0.4f) * cut / r;
    float* B = basis_pos + (size_t)p*8;
    #pragma unroll
    for (int k = 1; k <= 8; ++k) B[k-1] = pref * sinf(PI_F * 0.2f * (float)k * r);
}

// ---------------- init scalA = emb (sorted ids) ----------------
__global__ void k_init_scal(const int* __restrict__ specS, const float* __restrict__ embW,
                            float* __restrict__ scalA)
{
    int tid = blockIdx.x * 256 + threadIdx.x;
    if (tid >= N_NODES * F) return;
    int n = tid >> 7, f = tid & 127;
    scalA[tid] = embW[specS[n]*F + f];
}

// ---------------- fused radial + per-node edge aggregation -> aggG[n][f][m] ----------------
// block = 1 sorted node, 256 threads: f = t&127, mh = t>>7
__global__ __launch_bounds__(256) void k_edge(
    const int layer,
    const int* __restrict__ row_ptr,
    const int* __restrict__ snd_pos,
    const float* __restrict__ sh_pos,
    const float* __restrict__ basis_pos,
    const float* __restrict__ rW1,
    const float* __restrict__ rb1,
    const float* __restrict__ rW2,
    const float* __restrict__ scal_in,
    float* __restrict__ aggG)
{
    __shared__ float W1s[NB*HR];
    __shared__ float b1s[HR];
    __shared__ float hS[GEDGE][HR];     // 4 KB
    __shared__ float rwS[GEDGE*512];    // 32 KB

    const int t = threadIdx.x;
    const int n = blockIdx.x;
    const int f = t & 127;
    const int mh = t >> 7;
    const int e4 = t >> 6;   // wave id 0..3
    const int j64 = t & 63;

    W1s[t] = rW1[layer*NB*HR + t];
    W1s[256 + t] = rW1[layer*NB*HR + 256 + t];
    if (t < HR) b1s[t] = rb1[layer*HR + t];

    const float* W2g = rW2 + (size_t)layer*HR*512;
    const float4* sh4 = (const float4*)sh_pos;

    float acc[8] = {0,0,0,0,0,0,0,0};
    const int istart = row_ptr[n], iend = row_ptr[n+1];
    __syncthreads();

    for (int g0 = istart; g0 < iend; g0 += GEDGE) {
        const int gcnt = min(GEDGE, iend - g0);

        // ---- phase A: h for edges of this group (wave e4 -> e_loc = e4, e4+4, ...)
        #pragma unroll
        for (int q = 0; q < 4; ++q) {
            int e = e4 + q*4;
            float a = b1s[j64];
            if (e < gcnt) {
                const float4* B4 = (const float4*)(basis_pos + (size_t)(g0 + e)*8);
                float4 x0 = B4[0], x1 = B4[1];
                a = fmaf(x0.x, W1s[0*HR + j64], a);
                a = fmaf(x0.y, W1s[1*HR + j64], a);
                a = fmaf(x0.z, W1s[2*HR + j64], a);
                a = fmaf(x0.w, W1s[3*HR + j64], a);
                a = fmaf(x1.x, W1s[4*HR + j64], a);
                a = fmaf(x1.y, W1s[5*HR + j64], a);
                a = fmaf(x1.z, W1s[6*HR + j64], a);
                a = fmaf(x1.w, W1s[7*HR + j64], a);
            }
            hS[e][j64] = a / (1.f + expf(-a));
        }
        __syncthreads();

        // ---- phase B: thread t computes rw columns (2t, 2t+1) for all edges of group
        float r0[GEDGE], r1[GEDGE];
        #pragma unroll
        for (int e = 0; e < GEDGE; ++e) { r0[e] = 0.f; r1[e] = 0.f; }
        for (int jt = 0; jt < 4; ++jt) {
            float2 w[16];
            #pragma unroll
            for (int j = 0; j < 16; ++j)
                w[j] = *(const float2*)(W2g + (size_t)(jt*16 + j)*512 + 2*t);
            #pragma unroll
            for (int e = 0; e < GEDGE; ++e) {
                if (e < gcnt) {
                    const float4 ha = *(const float4*)&hS[e][jt*16 + 0];
                    const float4 hb = *(const float4*)&hS[e][jt*16 + 4];
                    const float4 hc = *(const float4*)&hS[e][jt*16 + 8];
                    const float4 hd = *(const float4*)&hS[e][jt*16 + 12];
                    r0[e]=fmaf(ha.x,w[0].x,r0[e]);  r1[e]=fmaf(ha.x,w[0].y,r1[e]);
                    r0[e]=fmaf(ha.y,w[1].x,r0[e]);  r1[e]=fmaf(ha.y,w[1].y,r1[e]);
                    r0[e]=fmaf(ha.z,w[2].x,r0[e]);  r1[e]=fmaf(ha.z,w[2].y,r1[e]);
                    r0[e]=fmaf(ha.w,w[3].x,r0[e]);  r1[e]=fmaf(ha.w,w[3].y,r1[e]);
                    r0[e]=fmaf(hb.x,w[4].x,r0[e]);  r1[e]=fmaf(hb.x,w[4].y,r1[e]);
                    r0[e]=fmaf(hb.y,w[5].x,r0[e]);  r1[e]=fmaf(hb.y,w[5].y,r1[e]);
                    r0[e]=fmaf(hb.z,w[6].x,r0[e]);  r1[e]=fmaf(hb.z,w[6].y,r1[e]);
                    r0[e]=fmaf(hb.w,w[7].x,r0[e]);  r1[e]=fmaf(hb.w,w[7].y,r1[e]);
                    r0[e]=fmaf(hc.x,w[8].x,r0[e]);  r1[e]=fmaf(hc.x,w[8].y,r1[e]);
                    r0[e]=fmaf(hc.y,w[9].x,r0[e]);  r1[e]=fmaf(hc.y,w[9].y,r1[e]);
                    r0[e]=fmaf(hc.z,w[10].x,r0[e]); r1[e]=fmaf(hc.z,w[10].y,r1[e]);
                    r0[e]=fmaf(hc.w,w[11].x,r0[e]); r1[e]=fmaf(hc.w,w[11].y,r1[e]);
                    r0[e]=fmaf(hd.x,w[12].x,r0[e]); r1[e]=fmaf(hd.x,w[12].y,r1[e]);
                    r0[e]=fmaf(hd.y,w[13].x,r0[e]); r1[e]=fmaf(hd.y,w[13].y,r1[e]);
                    r0[e]=fmaf(hd.z,w[14].x,r0[e]); r1[e]=fmaf(hd.z,w[14].y,r1[e]);
                    r0[e]=fmaf(hd.w,w[15].x,r0[e]); r1[e]=fmaf(hd.w,w[15].y,r1[e]);
                }
            }
        }
        #pragma unroll
        for (int e = 0; e < GEDGE; ++e)
            ((float2*)rwS)[e*256 + t] = make_float2(r0[e], r1[e]);
        __syncthreads();

        // ---- phase C: accumulate messages
        #pragma unroll
        for (int e = 0; e < GEDGE; ++e) {
            if (e < gcnt) {
                const int ii = g0 + e;
                const int snd = snd_pos[ii];
                const float sf = scal_in[(size_t)snd*F + f];
                const float4 rwv = *(const float4*)(rwS + e*512 + 4*f);
                const float4 shA = sh4[(size_t)ii*4 + mh*2 + 0];
                const float4 shB = sh4[(size_t)ii*4 + mh*2 + 1];
                if (mh == 0) {   // m=0..7, l=[0,1,1,1,2,2,2,2]
                    const float a0 = sf*rwv.x, a1 = sf*rwv.y, a2 = sf*rwv.z;
                    acc[0] = fmaf(a0, shA.x, acc[0]);
                    acc[1] = fmaf(a1, shA.y, acc[1]);
                    acc[2] = fmaf(a1, shA.z, acc[2]);
                    acc[3] = fmaf(a1, shA.w, acc[3]);
                    acc[4] = fmaf(a2, shB.x, acc[4]);
                    acc[5] = fmaf(a2, shB.y, acc[5]);
                    acc[6] = fmaf(a2, shB.z, acc[6]);
                    acc[7] = fmaf(a2, shB.w, acc[7]);
                } else {         // m=8..15, l=[2,3,3,3,3,3,3,3]
                    const float a2 = sf*rwv.z, a3 = sf*rwv.w;
                    acc[0] = fmaf(a2, shA.x, acc[0]);
                    acc[1] = fmaf(a3, shA.y, acc[1]);
                    acc[2] = fmaf(a3, shA.z, acc[2]);
                    acc[3] = fmaf(a3, shA.w, acc[3]);
                    acc[4] = fmaf(a3, shB.x, acc[4]);
                    acc[5] = fmaf(a3, shB.y, acc[5]);
                    acc[6] = fmaf(a3, shB.z, acc[6]);
                    acc[7] = fmaf(a3, shB.w, acc[7]);
                }
            }
        }
        __syncthreads();  // protect rwS/hS before next group
    }

    float4* wp = (float4*)(aggG + (size_t)n*2048 + f*16 + mh*8);
    wp[0] = make_float4(acc[0], acc[1], acc[2], acc[3]);
    wp[1] = make_float4(acc[4], acc[5], acc[6], acc[7]);
}

// ---------------- species-batched linears: tile GEMM helpers ----------------
// mh branch wraps the whole k-loop (wave-uniform -> no predication blowup).
__device__ __forceinline__ void tile_mm(const float (&tile)[BL][16][16],
    const float* __restrict__ W, const int kt, const int f, const int mh,
    float (&acc)[BL][8])
{
    if (mh == 0) {
        #pragma unroll 4
        for (int k = 0; k < 16; ++k) {
            const int f2 = kt*16 + k;
            const float w0 = W[(0*F + f2)*F + f];
            const float w1 = W[(1*F + f2)*F + f];
            const float w2 = W[(2*F + f2)*F + f];
            #pragma unroll
            for (int b = 0; b < BL; ++b) {
                const float4 A  = *(const float4*)&tile[b][k][0];
                const float4 Bv = *(const float4*)&tile[b][k][4];
                acc[b][0] = fmaf(A.x,  w0, acc[b][0]);
                acc[b][1] = fmaf(A.y,  w1, acc[b][1]);
                acc[b][2] = fmaf(A.z,  w1, acc[b][2]);
                acc[b][3] = fmaf(A.w,  w1, acc[b][3]);
                acc[b][4] = fmaf(Bv.x, w2, acc[b][4]);
                acc[b][5] = fmaf(Bv.y, w2, acc[b][5]);
                acc[b][6] = fmaf(Bv.z, w2, acc[b][6]);
                acc[b][7] = fmaf(Bv.w, w2, acc[b][7]);
            }
        }
    } else {
        #pragma unroll 4
        for (int k = 0; k < 16; ++k) {
            const int f2 = kt*16 + k;
            const float w2 = W[(2*F + f2)*F + f];
            const float w3 = W[(3*F + f2)*F + f];
            #pragma unroll
            for (int b = 0; b < BL; ++b) {
                const float4 A  = *(const float4*)&tile[b][k][8];
                const float4 Bv = *(const float4*)&tile[b][k][12];
                acc[b][0] = fmaf(A.x,  w2, acc[b][0]);
                acc[b][1] = fmaf(A.y,  w3, acc[b][1]);
                acc[b][2] = fmaf(A.z,  w3, acc[b][2]);
                acc[b][3] = fmaf(A.w,  w3, acc[b][3]);
                acc[b][4] = fmaf(Bv.x, w3, acc[b][4]);
                acc[b][5] = fmaf(Bv.y, w3, acc[b][5]);
                acc[b][6] = fmaf(Bv.z, w3, acc[b][6]);
                acc[b][7] = fmaf(Bv.w, w3, acc[b][7]);
            }
        }
    }
}

// slow path for rare mixed-species blocks: one node at a time, no jam
__device__ __forceinline__ void tile_mm_one(const float (&tile)[16][16],
    const float* __restrict__ W, const int kt, const int f, const int mh,
    float (&acc)[8])
{
    if (mh == 0) {
        for (int k = 0; k < 16; ++k) {
            const int f2 = kt*16 + k;
            const float w0 = W[(0*F + f2)*F + f];
            const float w1 = W[(1*F + f2)*F + f];
            const float w2 = W[(2*F + f2)*F + f];
            const float4 A  = *(const float4*)&tile[k][0];
            const float4 Bv = *(const float4*)&tile[k][4];
            acc[0] = fmaf(A.x,  w0, acc[0]);
            acc[1] = fmaf(A.y,  w1, acc[1]);
            acc[2] = fmaf(A.z,  w1, acc[2]);
            acc[3] = fmaf(A.w,  w1, acc[3]);
            acc[4] = fmaf(Bv.x, w2, acc[4]);
            acc[5] = fmaf(Bv.y, w2, acc[5]);
            acc[6] = fmaf(Bv.z, w2, acc[6]);
            acc[7] = fmaf(Bv.w, w2, acc[7]);
        }
    } else {
        for (int k = 0; k < 16; ++k) {
            const int f2 = kt*16 + k;
            const float w2 = W[(2*F + f2)*F + f];
            const float w3 = W[(3*F + f2)*F + f];
            const float4 A  = *(const float4*)&tile[k][8];
            const float4 Bv = *(const float4*)&tile[k][12];
            acc[0] = fmaf(A.x,  w2, acc[0]);
            acc[1] = fmaf(A.y,  w3, acc[1]);
            acc[2] = fmaf(A.z,  w3, acc[2]);
            acc[3] = fmaf(A.w,  w3, acc[3]);
            acc[4] = fmaf(Bv.x, w3, acc[4]);
            acc[5] = fmaf(Bv.y, w3, acc[5]);
            acc[6] = fmaf(Bv.z, w3, acc[6]);
            acc[7] = fmaf(Bv.w, w3, acc[7]);
        }
    }
}

// ---------------- species-batched linears + poly + readouts ----------------
template<int LAYER>
__global__ __launch_bounds__(256) void k_lin(
    const int* __restrict__ specS,
    const int* __restrict__ perm,
    const float* __restrict__ aggG,
    const float* __restrict__ linW,
    const float* __restrict__ prodc,
    const float* __restrict__ scW,
    const float* __restrict__ ro0,
    const float* __restrict__ ro1W1,
    const float* __restrict__ ro1W2,
    float* __restrict__ feats,
    float* __restrict__ scal_out,
    float* __restrict__ out)
{
    __shared__ float tA[BL][16][16];   // 4 KB, reused by both passes
    __shared__ float pS[BL][F];
    __shared__ float yS[BL][16];

    const int t = threadIdx.x;
    const int n0 = blockIdx.x * BL;
    const int f = t & 127;
    const int mh = t >> 7;
    const int j64 = t & 63;

    int sp[BL];
    #pragma unroll
    for (int b = 0; b < BL; ++b) sp[b] = specS[n0 + b];
    const bool uni = (sp[0]==sp[1]) && (sp[1]==sp[2]) && (sp[2]==sp[3]);

    float nv[BL][8];
    #pragma unroll
    for (int b = 0; b < BL; ++b)
        #pragma unroll
        for (int j = 0; j < 8; ++j) nv[b][j] = 0.f;

    const int n_loc = t >> 6;
    const int f_loc = (t >> 2) & 15;
    const int m4 = (t & 3) * 4;
    const float* Wl0 = linW + (((size_t)LAYER*NSPEC + sp[0])*4)*(F*F);

    // ---- pass 1: lin over aggG
    for (int kt = 0; kt < 8; ++kt) {
        const size_t off = (size_t)(n0 + n_loc)*2048 + (size_t)(kt*16 + f_loc)*16 + m4;
        *(float4*)&tA[n_loc][f_loc][m4] = *(const float4*)(aggG + off);
        __syncthreads();
        if (uni) {
            tile_mm(tA, Wl0, kt, f, mh, nv);
        } else {
            #pragma unroll
            for (int b = 0; b < BL; ++b)
                tile_mm_one(tA[b], linW + (((size_t)LAYER*NSPEC + sp[b])*4)*(F*F),
                            kt, f, mh, nv[b]);
        }
        __syncthreads();
    }

    // EPS
    #pragma unroll
    for (int b = 0; b < BL; ++b)
        #pragma unroll
        for (int j = 0; j < 8; ++j) nv[b][j] *= 0.5f;

    // poly gate
    if (mh == 0) {
        #pragma unroll
        for (int b = 0; b < BL; ++b) pS[b][f] = nv[b][0];
    }
    __syncthreads();
    #pragma unroll
    for (int b = 0; b < BL; ++b) {
        const float* pc = prodc + ((size_t)LAYER*NSPEC + sp[b])*3*F;
        float sg = pS[b][f];
        float poly = pc[f] + pc[F+f]*sg + pc[2*F+f]*sg*sg;
        #pragma unroll
        for (int j = 0; j < 8; ++j) nv[b][j] *= poly;
    }
    __syncthreads();   // pS reads done before reuse

    // ---- pass 2 (LAYER 1 only): skip-connection over old feats, same accumulators
    if (LAYER == 1) {
        const float* Ws0 = scW + (((size_t)LAYER*NSPEC + sp[0])*4)*(F*F);
        for (int kt = 0; kt < 8; ++kt) {
            const size_t off = (size_t)(n0 + n_loc)*2048 + (size_t)(kt*16 + f_loc)*16 + m4;
            *(float4*)&tA[n_loc][f_loc][m4] = *(const float4*)(feats + off);
            __syncthreads();
            if (uni) {
                tile_mm(tA, Ws0, kt, f, mh, nv);
            } else {
                #pragma unroll
                for (int b = 0; b < BL; ++b)
                    tile_mm_one(tA[b], scW + (((size_t)LAYER*NSPEC + sp[b])*4)*(F*F),
                                kt, f, mh, nv[b]);
            }
            __syncthreads();
        }
    }

    // write feats
    #pragma unroll
    for (int b = 0; b < BL; ++b) {
        float4* wp = (float4*)(feats + (size_t)(n0+b)*2048 + f*16 + mh*8);
        wp[0] = make_float4(nv[b][0], nv[b][1], nv[b][2], nv[b][3]);
        wp[1] = make_float4(nv[b][4], nv[b][5], nv[b][6], nv[b][7]);
    }
    if (mh == 0) {
        #pragma unroll
        for (int b = 0; b < BL; ++b) scal_out[(size_t)(n0+b)*F + f] = nv[b][0];
    }
    __syncthreads();  // pS reuse below

    if (LAYER == 0) {
        if (mh == 0) {
            #pragma unroll
            for (int b = 0; b < BL; ++b) pS[b][f] = nv[b][0] * ro0[f];
        }
        __syncthreads();
        const int w = t >> 6;   // wave w reduces node w
        float v = pS[w][j64] + pS[w][j64 + 64];
        #pragma unroll
        for (int off = 32; off > 0; off >>= 1) v += __shfl_down(v, off);
        if (j64 == 0) out[(size_t)perm[n0 + w]*2 + 0] = v;
    } else {
        if (mh == 0) {
            #pragma unroll
            for (int b = 0; b < BL; ++b) pS[b][f] = nv[b][0];
        }
        __syncthreads();
        if (t < 64) {
            const int b = t >> 4, c = t & 15;
            float a = 0.f;
            for (int g = 0; g < F; ++g) a = fmaf(pS[b][g], ro1W1[g*16 + c], a);
            a = silu_f(a);
            yS[b][c] = a * ro1W2[c];
        }
        __syncthreads();
        if (t < BL) {
            float s = 0.f;
            #pragma unroll
            for (int j = 0; j < 16; ++j) s += yS[t][j];
            out[(size_t)perm[n0 + t]*2 + 1] = s;
        }
    }
}

extern "C" void kernel_launch(void* const* d_in, const int* in_sizes, int n_in,
                              void* d_out, int out_size, void* d_ws, size_t ws_size,
                              hipStream_t stream)
{
    (void)in_sizes; (void)n_in; (void)out_size; (void)ws_size;
    const float* vectors   = (const float*)d_in[0];
    const int*   spec      = (const int*)d_in[1];
    const int*   senders   = (const int*)d_in[2];
    const int*   receivers = (const int*)d_in[3];
    const float* embW      = (const float*)d_in[4];
    const float* rW1       = (const float*)d_in[5];
    const float* rb1       = (const float*)d_in[6];
    const float* rW2       = (const float*)d_in[7];
    const float* linW      = (const float*)d_in[8];
    const float* prodc     = (const float*)d_in[9];
    const float* scW       = (const float*)d_in[10];
    const float* ro0       = (const float*)d_in[11];
    const float* ro1W1     = (const float*)d_in[12];
    const float* ro1W2     = (const float*)d_in[13];
    float* out = (float*)d_out;

    char* ws = (char*)d_ws;
    float* scalA     = (float*)ws; ws += sizeof(float)*(size_t)N_NODES*F;
    float* scalB     = (float*)ws; ws += sizeof(float)*(size_t)N_NODES*F;
    float* feats     = (float*)ws; ws += sizeof(float)*(size_t)N_NODES*F*16;
    float* aggG      = (float*)ws; ws += sizeof(float)*(size_t)N_NODES*F*16;
    float* sh_pos    = (float*)ws; ws += sizeof(float)*(size_t)N_EDGES*16;
    float* basis_pos = (float*)ws; ws += sizeof(float)*(size_t)N_EDGES*8;
    int*   snd_pos   = (int*)ws;   ws += sizeof(int)*N_EDGES;
    int*   row_ptr   = (int*)ws;   ws += sizeof(int)*(N_NODES+1);
    // zeroed region: counts, cursor, scnt, scur (contiguous)
    int*   counts    = (int*)ws;   ws += sizeof(int)*N_NODES;
    int*   cursor    = (int*)ws;   ws += sizeof(int)*N_NODES;
    int*   scnt      = (int*)ws;   ws += sizeof(int)*16;
    int*   scur      = (int*)ws;   ws += sizeof(int)*16;
    int*   sptr      = (int*)ws;   ws += sizeof(int)*16;
    int*   perm      = (int*)ws;   ws += sizeof(int)*N_NODES;
    int*   inv       = (int*)ws;   ws += sizeof(int)*N_NODES;
    int*   specS     = (int*)ws;   ws += sizeof(int)*N_NODES;
    int*   elist     = (int*)ws;   ws += sizeof(int)*N_EDGES;

    hipMemsetAsync(counts, 0, sizeof(int)*(2*N_NODES + 32), stream);

    const int EB = (N_EDGES + 255) / 256;
    const int NBK = (N_NODES + 255) / 256;

    k_scnt<<<NBK, 256, 0, stream>>>(spec, scnt);
    k_sscan<<<1, 64, 0, stream>>>(scnt, sptr);
    k_sfill<<<NBK, 256, 0, stream>>>(spec, sptr, scur, perm, inv, specS);
    k_count<<<EB, 256, 0, stream>>>(receivers, inv, counts);
    k_scan<<<1, 1024, 0, stream>>>(counts, row_ptr);
    k_fill<<<EB, 256, 0, stream>>>(receivers, inv, row_ptr, cursor, elist);
    k_edge_pre<<<EB, 256, 0, stream>>>(elist, senders, inv, vectors, sh_pos, basis_pos, snd_pos);
    k_init_scal<<<(N_NODES*F + 255)/256, 256, 0, stream>>>(specS, embW, scalA);

    k_edge<<<N_NODES, 256, 0, stream>>>(0, row_ptr, snd_pos, sh_pos, basis_pos,
        rW1, rb1, rW2, scalA, aggG);
    k_lin<0><<<N_NODES/BL, 256, 0, stream>>>(specS, perm, aggG, linW, prodc, scW,
        ro0, ro1W1, ro1W2, feats, scalB, out);

    k_edge<<<N_NODES, 256, 0, stream>>>(1, row_ptr, snd_pos, sh_pos, basis_pos,
        rW1, rb1, rW2, scalB, aggG);
    k_lin<1><<<N_NODES/BL, 256, 0, stream>>>(specS, perm, aggG, linW, prodc, scW,
        ro0, ro1W1, ro1W2, feats, scalA, out);
}

// Round 8
// 1439.745 us; speedup vs baseline: 5.9242x; 1.0197x over previous
//
#include <hip/hip_runtime.h>
#include <math.h>
#include <stdint.h>

#define N_NODES 10000
#define N_EDGES 160000
#define F 128
#define NB 8
#define HR 64
#define NSPEC 10
#define PI_F 3.14159265358979323846f
#define GEDGE 16
#define BL 4

__device__ __forceinline__ float silu_f(float x){ return x / (1.f + expf(-x)); }

// ---------------- species counting sort ----------------
__global__ void k_scnt(const int* __restrict__ spec, int* __restrict__ scnt)
{
    int n = blockIdx.x * 256 + threadIdx.x;
    if (n < N_NODES) atomicAdd(&scnt[spec[n]], 1);
}

__global__ void k_sscan(const int* __restrict__ scnt, int* __restrict__ sptr)
{
    if (threadIdx.x == 0) {
        int acc = 0;
        for (int s = 0; s < NSPEC; ++s) { sptr[s] = acc; acc += scnt[s]; }
        sptr[NSPEC] = acc;
    }
}

__global__ void k_sfill(const int* __restrict__ spec, const int* __restrict__ sptr,
                        int* __restrict__ scur, int* __restrict__ perm,
                        int* __restrict__ inv, int* __restrict__ specS)
{
    int n = blockIdx.x * 256 + threadIdx.x;
    if (n >= N_NODES) return;
    int s = spec[n];
    int pos = sptr[s] + atomicAdd(&scur[s], 1);
    perm[pos] = n; inv[n] = pos; specS[pos] = s;
}

// ---------------- receiver histogram (sorted ids) ----------------
__global__ void k_count(const int* __restrict__ recv, const int* __restrict__ inv,
                        int* __restrict__ counts)
{
    int e = blockIdx.x * 256 + threadIdx.x;
    if (e >= N_EDGES) return;
    atomicAdd(&counts[inv[recv[e]]], 1);
}

// ---------------- block-wide scan -> row_ptr ----------------
__global__ void k_scan(const int* __restrict__ counts, int* __restrict__ row_ptr)
{
    __shared__ int ps[1024];
    const int t = threadIdx.x;
    int base = t * 10;
    int loc[10];
    int sum = 0;
    #pragma unroll
    for (int j = 0; j < 10; ++j) {
        int idx = base + j;
        int c = (idx < N_NODES) ? counts[idx] : 0;
        loc[j] = c; sum += c;
    }
    ps[t] = sum;
    __syncthreads();
    for (int off = 1; off < 1024; off <<= 1) {
        int v = (t >= off) ? ps[t-off] : 0;
        __syncthreads();
        ps[t] += v;
        __syncthreads();
    }
    int ex = ps[t] - sum;
    #pragma unroll
    for (int j = 0; j < 10; ++j) {
        int idx = base + j;
        if (idx < N_NODES) row_ptr[idx] = ex;
        ex += loc[j];
    }
    if (t == 1023) row_ptr[N_NODES] = ex;
}

// ---------------- fill CSR edge list (sorted ids) ----------------
__global__ void k_fill(const int* __restrict__ recv, const int* __restrict__ inv,
                       const int* __restrict__ row_ptr,
                       int* __restrict__ cursor, int* __restrict__ elist)
{
    int e = blockIdx.x * 256 + threadIdx.x;
    if (e >= N_EDGES) return;
    int r = inv[recv[e]];
    int pos = atomicAdd(&cursor[r], 1);
    elist[row_ptr[r] + pos] = e;
}

// ---------------- position-order edge precompute ----------------
__global__ void k_edge_pre(const int* __restrict__ elist, const int* __restrict__ senders,
                           const int* __restrict__ inv, const float* __restrict__ vec,
                           float* __restrict__ sh_pos, float* __restrict__ basis_pos,
                           int* __restrict__ snd_pos)
{
    int p = blockIdx.x * 256 + threadIdx.x;
    if (p >= N_EDGES) return;
    const int e = elist[p];
    snd_pos[p] = inv[senders[e]];
    float x = vec[e*3+0], y = vec[e*3+1], z = vec[e*3+2];
    float r = sqrtf(x*x + y*y + z*z);
    r = fmaxf(r, 1e-9f);
    float invr = 1.f / r;
    x *= invr; y *= invr; z *= invr;
    const float s3=1.7320508075688772f, s5=2.23606797749979f, s7=2.6457513110645907f,
                s15=3.872983346207417f, s42=6.480740698407860f, s70=8.366600265340756f,
                s105=10.246950765959598f;
    float* S = sh_pos + (size_t)p*16;
    S[0]=1.f; S[1]=s3*x; S[2]=s3*y; S[3]=s3*z;
    S[4]=s15*x*y; S[5]=s15*y*z; S[6]=0.5f*s5*(3.f*z*z-1.f); S[7]=s15*x*z;
    S[8]=0.5f*s15*(x*x-y*y);
    S[9]=0.25f*s70*y*(3.f*x*x-y*y); S[10]=s105*x*y*z; S[11]=0.25f*s42*y*(5.f*z*z-1.f);
    S[12]=0.5f*s7*(5.f*z*z*z-3.f*z); S[13]=0.25f*s42*x*(5.f*z*z-1.f);
    S[14]=0.5f*s105*z*(x*x-y*y); S[15]=0.25f*s70*x*(x*x-3.f*y*y);
    float rc = fminf(r, 5.0f);
    float cut = 0.5f * (cosf(PI_F * rc * 0.2f) + 1.f);
    float pref = sqrtf(0.4f) * cut / r;
    float* B = basis_pos + (size_t)p*8;
    #pragma unroll
    for (int k = 1; k <= 8; ++k) B[k-1] = pref * sinf(PI_F * 0.2f * (float)k * r);
}

// ---------------- init scalA = emb (sorted ids) ----------------
__global__ void k_init_scal(const int* __restrict__ specS, const float* __restrict__ embW,
                            float* __restrict__ scalA)
{
    int tid = blockIdx.x * 256 + threadIdx.x;
    if (tid >= N_NODES * F) return;
    int n = tid >> 7, f = tid & 127;
    scalA[tid] = embW[specS[n]*F + f];
}

// ---------------- fused radial + per-node edge aggregation -> aggG[n][f][m] ----------------
// block = 1 sorted node, 256 threads: f = t&127, mh = t>>7
__global__ __launch_bounds__(256) void k_edge(
    const int layer,
    const int* __restrict__ row_ptr,
    const int* __restrict__ snd_pos,
    const float* __restrict__ sh_pos,
    const float* __restrict__ basis_pos,
    const float* __restrict__ rW1,
    const float* __restrict__ rb1,
    const float* __restrict__ rW2,
    const float* __restrict__ scal_in,
    float* __restrict__ aggG)
{
    __shared__ float W1s[NB*HR];
    __shared__ float b1s[HR];
    __shared__ float hS[GEDGE][HR];     // 4 KB
    __shared__ float rwS[GEDGE*512];    // 32 KB

    const int t = threadIdx.x;
    const int n = blockIdx.x;
    const int f = t & 127;
    const int mh = t >> 7;
    const int e4 = t >> 6;   // wave id 0..3
    const int j64 = t & 63;

    W1s[t] = rW1[layer*NB*HR + t];
    W1s[256 + t] = rW1[layer*NB*HR + 256 + t];
    if (t < HR) b1s[t] = rb1[layer*HR + t];

    const float* W2g = rW2 + (size_t)layer*HR*512;
    const float4* sh4 = (const float4*)sh_pos;

    float acc[8] = {0,0,0,0,0,0,0,0};
    const int istart = row_ptr[n], iend = row_ptr[n+1];
    __syncthreads();

    for (int g0 = istart; g0 < iend; g0 += GEDGE) {
        const int gcnt = min(GEDGE, iend - g0);

        // ---- phase A: h for edges of this group (wave e4 -> e_loc = e4, e4+4, ...)
        #pragma unroll
        for (int q = 0; q < 4; ++q) {
            int e = e4 + q*4;
            float a = b1s[j64];
            if (e < gcnt) {
                const float4* B4 = (const float4*)(basis_pos + (size_t)(g0 + e)*8);
                float4 x0 = B4[0], x1 = B4[1];
                a = fmaf(x0.x, W1s[0*HR + j64], a);
                a = fmaf(x0.y, W1s[1*HR + j64], a);
                a = fmaf(x0.z, W1s[2*HR + j64], a);
                a = fmaf(x0.w, W1s[3*HR + j64], a);
                a = fmaf(x1.x, W1s[4*HR + j64], a);
                a = fmaf(x1.y, W1s[5*HR + j64], a);
                a = fmaf(x1.z, W1s[6*HR + j64], a);
                a = fmaf(x1.w, W1s[7*HR + j64], a);
            }
            hS[e][j64] = a / (1.f + expf(-a));
        }
        __syncthreads();

        // ---- phase B: thread t computes rw columns (2t, 2t+1) for all edges of group
        float r0[GEDGE], r1[GEDGE];
        #pragma unroll
        for (int e = 0; e < GEDGE; ++e) { r0[e] = 0.f; r1[e] = 0.f; }
        for (int jt = 0; jt < 4; ++jt) {
            float2 w[16];
            #pragma unroll
            for (int j = 0; j < 16; ++j)
                w[j] = *(const float2*)(W2g + (size_t)(jt*16 + j)*512 + 2*t);
            #pragma unroll
            for (int e = 0; e < GEDGE; ++e) {
                if (e < gcnt) {
                    const float4 ha = *(const float4*)&hS[e][jt*16 + 0];
                    const float4 hb = *(const float4*)&hS[e][jt*16 + 4];
                    const float4 hc = *(const float4*)&hS[e][jt*16 + 8];
                    const float4 hd = *(const float4*)&hS[e][jt*16 + 12];
                    r0[e]=fmaf(ha.x,w[0].x,r0[e]);  r1[e]=fmaf(ha.x,w[0].y,r1[e]);
                    r0[e]=fmaf(ha.y,w[1].x,r0[e]);  r1[e]=fmaf(ha.y,w[1].y,r1[e]);
                    r0[e]=fmaf(ha.z,w[2].x,r0[e]);  r1[e]=fmaf(ha.z,w[2].y,r1[e]);
                    r0[e]=fmaf(ha.w,w[3].x,r0[e]);  r1[e]=fmaf(ha.w,w[3].y,r1[e]);
                    r0[e]=fmaf(hb.x,w[4].x,r0[e]);  r1[e]=fmaf(hb.x,w[4].y,r1[e]);
                    r0[e]=fmaf(hb.y,w[5].x,r0[e]);  r1[e]=fmaf(hb.y,w[5].y,r1[e]);
                    r0[e]=fmaf(hb.z,w[6].x,r0[e]);  r1[e]=fmaf(hb.z,w[6].y,r1[e]);
                    r0[e]=fmaf(hb.w,w[7].x,r0[e]);  r1[e]=fmaf(hb.w,w[7].y,r1[e]);
                    r0[e]=fmaf(hc.x,w[8].x,r0[e]);  r1[e]=fmaf(hc.x,w[8].y,r1[e]);
                    r0[e]=fmaf(hc.y,w[9].x,r0[e]);  r1[e]=fmaf(hc.y,w[9].y,r1[e]);
                    r0[e]=fmaf(hc.z,w[10].x,r0[e]); r1[e]=fmaf(hc.z,w[10].y,r1[e]);
                    r0[e]=fmaf(hc.w,w[11].x,r0[e]); r1[e]=fmaf(hc.w,w[11].y,r1[e]);
                    r0[e]=fmaf(hd.x,w[12].x,r0[e]); r1[e]=fmaf(hd.x,w[12].y,r1[e]);
                    r0[e]=fmaf(hd.y,w[13].x,r0[e]); r1[e]=fmaf(hd.y,w[13].y,r1[e]);
                    r0[e]=fmaf(hd.z,w[14].x,r0[e]); r1[e]=fmaf(hd.z,w[14].y,r1[e]);
                    r0[e]=fmaf(hd.w,w[15].x,r0[e]); r1[e]=fmaf(hd.w,w[15].y,r1[e]);
                }
            }
        }
        #pragma unroll
        for (int e = 0; e < GEDGE; ++e)
            ((float2*)rwS)[e*256 + t] = make_float2(r0[e], r1[e]);
        __syncthreads();

        // ---- phase C: accumulate messages
        #pragma unroll
        for (int e = 0; e < GEDGE; ++e) {
            if (e < gcnt) {
                const int ii = g0 + e;
                const int snd = snd_pos[ii];
                const float sf = scal_in[(size_t)snd*F + f];
                const float4 rwv = *(const float4*)(rwS + e*512 + 4*f);
                const float4 shA = sh4[(size_t)ii*4 + mh*2 + 0];
                const float4 shB = sh4[(size_t)ii*4 + mh*2 + 1];
                if (mh == 0) {   // m=0..7, l=[0,1,1,1,2,2,2,2]
                    const float a0 = sf*rwv.x, a1 = sf*rwv.y, a2 = sf*rwv.z;
                    acc[0] = fmaf(a0, shA.x, acc[0]);
                    acc[1] = fmaf(a1, shA.y, acc[1]);
                    acc[2] = fmaf(a1, shA.z, acc[2]);
                    acc[3] = fmaf(a1, shA.w, acc[3]);
                    acc[4] = fmaf(a2, shB.x, acc[4]);
                    acc[5] = fmaf(a2, shB.y, acc[5]);
                    acc[6] = fmaf(a2, shB.z, acc[6]);
                    acc[7] = fmaf(a2, shB.w, acc[7]);
                } else {         // m=8..15, l=[2,3,3,3,3,3,3,3]
                    const float a2 = sf*rwv.z, a3 = sf*rwv.w;
                    acc[0] = fmaf(a2, shA.x, acc[0]);
                    acc[1] = fmaf(a3, shA.y, acc[1]);
                    acc[2] = fmaf(a3, shA.z, acc[2]);
                    acc[3] = fmaf(a3, shA.w, acc[3]);
                    acc[4] = fmaf(a3, shB.x, acc[4]);
                    acc[5] = fmaf(a3, shB.y, acc[5]);
                    acc[6] = fmaf(a3, shB.z, acc[6]);
                    acc[7] = fmaf(a3, shB.w, acc[7]);
                }
            }
        }
        __syncthreads();  // protect rwS/hS before next group
    }

    float4* wp = (float4*)(aggG + (size_t)n*2048 + f*16 + mh*8);
    wp[0] = make_float4(acc[0], acc[1], acc[2], acc[3]);
    wp[1] = make_float4(acc[4], acc[5], acc[6], acc[7]);
}

// ---------------- uniform-species GEMM pass: LDS-staged weights + register prefetch ----------------
// src: node-major [n][2048]; Wg: species weight base (4*F*F). Accumulates into acc.
__device__ __forceinline__ void lin_pass_uni(
    const float* __restrict__ src,
    const float* __restrict__ Wg,
    float (*wS)[16][128],     // [4][16][128] = 32 KB
    float (*tA)[16][16],      // [BL][16][16] = 4 KB
    const int n0, const int t, const int f, const int mh,
    float (&acc)[BL][8])
{
    const int n_loc = t >> 6;
    const int f_loc = (t >> 2) & 15;
    const int m4 = (t & 3) * 4;
    const int tq = t * 4;     // float offset of this thread's float4 in a 1024-float half-chunk

    float4 wreg[8];
    float4 treg;
    // prefetch kt = 0
    #pragma unroll
    for (int l = 0; l < 4; ++l) {
        const float* chunk = Wg + (size_t)l*F*F;      // rows f2=0..15 of block l
        wreg[2*l+0] = *(const float4*)(chunk + tq);
        wreg[2*l+1] = *(const float4*)(chunk + 1024 + tq);
    }
    treg = *(const float4*)(src + (size_t)(n0 + n_loc)*2048 + (size_t)f_loc*16 + m4);

    for (int kt = 0; kt < 8; ++kt) {
        __syncthreads();   // previous kt's LDS reads done
        #pragma unroll
        for (int l = 0; l < 4; ++l) {
            *(float4*)(&wS[l][0][0] + tq)        = wreg[2*l+0];
            *(float4*)(&wS[l][0][0] + 1024 + tq) = wreg[2*l+1];
        }
        *(float4*)&tA[n_loc][f_loc][m4] = treg;
        __syncthreads();
        if (kt < 7) {      // prefetch kt+1 while computing kt
            #pragma unroll
            for (int l = 0; l < 4; ++l) {
                const float* chunk = Wg + ((size_t)l*F + (kt+1)*16)*F;
                wreg[2*l+0] = *(const float4*)(chunk + tq);
                wreg[2*l+1] = *(const float4*)(chunk + 1024 + tq);
            }
            treg = *(const float4*)(src + (size_t)(n0 + n_loc)*2048 + (size_t)((kt+1)*16 + f_loc)*16 + m4);
        }
        // compute on LDS-resident tiles (mh branch wave-uniform, outside k-loop)
        if (mh == 0) {
            #pragma unroll 4
            for (int k = 0; k < 16; ++k) {
                const float w0 = wS[0][k][f];
                const float w1 = wS[1][k][f];
                const float w2 = wS[2][k][f];
                #pragma unroll
                for (int b = 0; b < BL; ++b) {
                    const float4 A  = *(const float4*)&tA[b][k][0];
                    const float4 Bv = *(const float4*)&tA[b][k][4];
                    acc[b][0] = fmaf(A.x,  w0, acc[b][0]);
                    acc[b][1] = fmaf(A.y,  w1, acc[b][1]);
                    acc[b][2] = fmaf(A.z,  w1, acc[b][2]);
                    acc[b][3] = fmaf(A.w,  w1, acc[b][3]);
                    acc[b][4] = fmaf(Bv.x, w2, acc[b][4]);
                    acc[b][5] = fmaf(Bv.y, w2, acc[b][5]);
                    acc[b][6] = fmaf(Bv.z, w2, acc[b][6]);
                    acc[b][7] = fmaf(Bv.w, w2, acc[b][7]);
                }
            }
        } else {
            #pragma unroll 4
            for (int k = 0; k < 16; ++k) {
                const float w2 = wS[2][k][f];
                const float w3 = wS[3][k][f];
                #pragma unroll
                for (int b = 0; b < BL; ++b) {
                    const float4 A  = *(const float4*)&tA[b][k][8];
                    const float4 Bv = *(const float4*)&tA[b][k][12];
                    acc[b][0] = fmaf(A.x,  w2, acc[b][0]);
                    acc[b][1] = fmaf(A.y,  w3, acc[b][1]);
                    acc[b][2] = fmaf(A.z,  w3, acc[b][2]);
                    acc[b][3] = fmaf(A.w,  w3, acc[b][3]);
                    acc[b][4] = fmaf(Bv.x, w3, acc[b][4]);
                    acc[b][5] = fmaf(Bv.y, w3, acc[b][5]);
                    acc[b][6] = fmaf(Bv.z, w3, acc[b][6]);
                    acc[b][7] = fmaf(Bv.w, w3, acc[b][7]);
                }
            }
        }
    }
}

// ---------------- slow path for rare mixed-species blocks ----------------
__device__ __forceinline__ void tile_mm_one(const float (&tile)[16][16],
    const float* __restrict__ W, const int kt, const int f, const int mh,
    float (&acc)[8])
{
    if (mh == 0) {
        for (int k = 0; k < 16; ++k) {
            const int f2 = kt*16 + k;
            const float w0 = W[(0*F + f2)*F + f];
            const float w1 = W[(1*F + f2)*F + f];
            const float w2 = W[(2*F + f2)*F + f];
            const float4 A  = *(const float4*)&tile[k][0];
            const float4 Bv = *(const float4*)&tile[k][4];
            acc[0] = fmaf(A.x,  w0, acc[0]);
            acc[1] = fmaf(A.y,  w1, acc[1]);
            acc[2] = fmaf(A.z,  w1, acc[2]);
            acc[3] = fmaf(A.w,  w1, acc[3]);
            acc[4] = fmaf(Bv.x, w2, acc[4]);
            acc[5] = fmaf(Bv.y, w2, acc[5]);
            acc[6] = fmaf(Bv.z, w2, acc[6]);
            acc[7] = fmaf(Bv.w, w2, acc[7]);
        }
    } else {
        for (int k = 0; k < 16; ++k) {
            const int f2 = kt*16 + k;
            const float w2 = W[(2*F + f2)*F + f];
            const float w3 = W[(3*F + f2)*F + f];
            const float4 A  = *(const float4*)&tile[k][8];
            const float4 Bv = *(const float4*)&tile[k][12];
            acc[0] = fmaf(A.x,  w2, acc[0]);
            acc[1] = fmaf(A.y,  w3, acc[1]);
            acc[2] = fmaf(A.z,  w3, acc[2]);
            acc[3] = fmaf(A.w,  w3, acc[3]);
            acc[4] = fmaf(Bv.x, w3, acc[4]);
            acc[5] = fmaf(Bv.y, w3, acc[5]);
            acc[6] = fmaf(Bv.z, w3, acc[6]);
            acc[7] = fmaf(Bv.w, w3, acc[7]);
        }
    }
}

__device__ __forceinline__ void lin_pass_mixed(
    const float* __restrict__ src,
    const float* __restrict__ Wbase,   // layer-resolved weight array base
    const int* sp,
    float (*tA)[16][16],
    const int n0, const int t, const int f, const int mh,
    float (&acc)[BL][8])
{
    const int n_loc = t >> 6;
    const int f_loc = (t >> 2) & 15;
    const int m4 = (t & 3) * 4;
    for (int kt = 0; kt < 8; ++kt) {
        __syncthreads();
        *(float4*)&tA[n_loc][f_loc][m4] =
            *(const float4*)(src + (size_t)(n0 + n_loc)*2048 + (size_t)(kt*16 + f_loc)*16 + m4);
        __syncthreads();
        #pragma unroll
        for (int b = 0; b < BL; ++b)
            tile_mm_one(tA[b], Wbase + ((size_t)sp[b]*4)*(F*F), kt, f, mh, acc[b]);
    }
}

// ---------------- species-batched linears + poly + readouts ----------------
template<int LAYER>
__global__ __launch_bounds__(256) void k_lin(
    const int* __restrict__ specS,
    const int* __restrict__ perm,
    const float* __restrict__ aggG,
    const float* __restrict__ linW,
    const float* __restrict__ prodc,
    const float* __restrict__ scW,
    const float* __restrict__ ro0,
    const float* __restrict__ ro1W1,
    const float* __restrict__ ro1W2,
    float* __restrict__ feats,
    float* __restrict__ scal_out,
    float* __restrict__ out)
{
    __shared__ float wS[4][16][128];   // 32 KB weight tile (current kt)
    __shared__ float tA[BL][16][16];   // 4 KB activation tile
    __shared__ float pS[BL][F];
    __shared__ float yS[BL][16];

    const int t = threadIdx.x;
    const int n0 = blockIdx.x * BL;
    const int f = t & 127;
    const int mh = t >> 7;
    const int j64 = t & 63;

    int sp[BL];
    #pragma unroll
    for (int b = 0; b < BL; ++b) sp[b] = specS[n0 + b];
    const bool uni = (sp[0]==sp[1]) && (sp[1]==sp[2]) && (sp[2]==sp[3]);

    float nv[BL][8];
    #pragma unroll
    for (int b = 0; b < BL; ++b)
        #pragma unroll
        for (int j = 0; j < 8; ++j) nv[b][j] = 0.f;

    const float* linL = linW + ((size_t)LAYER*NSPEC)*4*(F*F);
    const float* scL  = scW  + ((size_t)LAYER*NSPEC)*4*(F*F);

    // ---- pass 1: lin over aggG
    if (uni) lin_pass_uni(aggG, linL + ((size_t)sp[0]*4)*(F*F), wS, tA, n0, t, f, mh, nv);
    else     lin_pass_mixed(aggG, linL, sp, tA, n0, t, f, mh, nv);

    // EPS
    #pragma unroll
    for (int b = 0; b < BL; ++b)
        #pragma unroll
        for (int j = 0; j < 8; ++j) nv[b][j] *= 0.5f;

    // poly gate
    __syncthreads();   // pass-1 LDS traffic done before pS writes? (pS separate; barrier orders pS reuse)
    if (mh == 0) {
        #pragma unroll
        for (int b = 0; b < BL; ++b) pS[b][f] = nv[b][0];
    }
    __syncthreads();
    #pragma unroll
    for (int b = 0; b < BL; ++b) {
        const float* pc = prodc + ((size_t)LAYER*NSPEC + sp[b])*3*F;
        float sg = pS[b][f];
        float poly = pc[f] + pc[F+f]*sg + pc[2*F+f]*sg*sg;
        #pragma unroll
        for (int j = 0; j < 8; ++j) nv[b][j] *= poly;
    }

    // ---- pass 2 (LAYER 1 only): skip-connection over old feats, same accumulators
    if (LAYER == 1) {
        if (uni) lin_pass_uni(feats, scL + ((size_t)sp[0]*4)*(F*F), wS, tA, n0, t, f, mh, nv);
        else     lin_pass_mixed(feats, scL, sp, tA, n0, t, f, mh, nv);
    }
    __syncthreads();

    // write feats
    #pragma unroll
    for (int b = 0; b < BL; ++b) {
        float4* wp = (float4*)(feats + (size_t)(n0+b)*2048 + f*16 + mh*8);
        wp[0] = make_float4(nv[b][0], nv[b][1], nv[b][2], nv[b][3]);
        wp[1] = make_float4(nv[b][4], nv[b][5], nv[b][6], nv[b][7]);
    }
    if (mh == 0) {
        #pragma unroll
        for (int b = 0; b < BL; ++b) scal_out[(size_t)(n0+b)*F + f] = nv[b][0];
    }
    __syncthreads();  // pS reuse below

    if (LAYER == 0) {
        if (mh == 0) {
            #pragma unroll
            for (int b = 0; b < BL; ++b) pS[b][f] = nv[b][0] * ro0[f];
        }
        __syncthreads();
        const int w = t >> 6;   // wave w reduces node w
        float v = pS[w][j64] + pS[w][j64 + 64];
        #pragma unroll
        for (int off = 32; off > 0; off >>= 1) v += __shfl_down(v, off);
        if (j64 == 0) out[(size_t)perm[n0 + w]*2 + 0] = v;
    } else {
        if (mh == 0) {
            #pragma unroll
            for (int b = 0; b < BL; ++b) pS[b][f] = nv[b][0];
        }
        __syncthreads();
        if (t < 64) {
            const int b = t >> 4, c = t & 15;
            float a = 0.f;
            for (int g = 0; g < F; ++g) a = fmaf(pS[b][g], ro1W1[g*16 + c], a);
            a = silu_f(a);
            yS[b][c] = a * ro1W2[c];
        }
        __syncthreads();
        if (t < BL) {
            float s = 0.f;
            #pragma unroll
            for (int j = 0; j < 16; ++j) s += yS[t][j];
            out[(size_t)perm[n0 + t]*2 + 1] = s;
        }
    }
}

extern "C" void kernel_launch(void* const* d_in, const int* in_sizes, int n_in,
                              void* d_out, int out_size, void* d_ws, size_t ws_size,
                              hipStream_t stream)
{
    (void)in_sizes; (void)n_in; (void)out_size; (void)ws_size;
    const float* vectors   = (const float*)d_in[0];
    const int*   spec      = (const int*)d_in[1];
    const int*   senders   = (const int*)d_in[2];
    const int*   receivers = (const int*)d_in[3];
    const float* embW      = (const float*)d_in[4];
    const float* rW1       = (const float*)d_in[5];
    const float* rb1       = (const float*)d_in[6];
    const float* rW2       = (const float*)d_in[7];
    const float* linW      = (const float*)d_in[8];
    const float* prodc     = (const float*)d_in[9];
    const float* scW       = (const float*)d_in[10];
    const float* ro0       = (const float*)d_in[11];
    const float* ro1W1     = (const float*)d_in[12];
    const float* ro1W2     = (const float*)d_in[13];
    float* out = (float*)d_out;

    char* ws = (char*)d_ws;
    float* scalA     = (float*)ws; ws += sizeof(float)*(size_t)N_NODES*F;
    float* scalB     = (float*)ws; ws += sizeof(float)*(size_t)N_NODES*F;
    float* feats     = (float*)ws; ws += sizeof(float)*(size_t)N_NODES*F*16;
    float* aggG      = (float*)ws; ws += sizeof(float)*(size_t)N_NODES*F*16;
    float* sh_pos    = (float*)ws; ws += sizeof(float)*(size_t)N_EDGES*16;
    float* basis_pos = (float*)ws; ws += sizeof(float)*(size_t)N_EDGES*8;
    int*   snd_pos   = (int*)ws;   ws += sizeof(int)*N_EDGES;
    int*   row_ptr   = (int*)ws;   ws += sizeof(int)*(N_NODES+1);
    // zeroed region: counts, cursor, scnt, scur (contiguous)
    int*   counts    = (int*)ws;   ws += sizeof(int)*N_NODES;
    int*   cursor    = (int*)ws;   ws += sizeof(int)*N_NODES;
    int*   scnt      = (int*)ws;   ws += sizeof(int)*16;
    int*   scur      = (int*)ws;   ws += sizeof(int)*16;
    int*   sptr      = (int*)ws;   ws += sizeof(int)*16;
    int*   perm      = (int*)ws;   ws += sizeof(int)*N_NODES;
    int*   inv       = (int*)ws;   ws += sizeof(int)*N_NODES;
    int*   specS     = (int*)ws;   ws += sizeof(int)*N_NODES;
    int*   elist     = (int*)ws;   ws += sizeof(int)*N_EDGES;

    hipMemsetAsync(counts, 0, sizeof(int)*(2*N_NODES + 32), stream);

    const int EB = (N_EDGES + 255) / 256;
    const int NBK = (N_NODES + 255) / 256;

    k_scnt<<<NBK, 256, 0, stream>>>(spec, scnt);
    k_sscan<<<1, 64, 0, stream>>>(scnt, sptr);
    k_sfill<<<NBK, 256, 0, stream>>>(spec, sptr, scur, perm, inv, specS);
    k_count<<<EB, 256, 0, stream>>>(receivers, inv, counts);
    k_scan<<<1, 1024, 0, stream>>>(counts, row_ptr);
    k_fill<<<EB, 256, 0, stream>>>(receivers, inv, row_ptr, cursor, elist);
    k_edge_pre<<<EB, 256, 0, stream>>>(elist, senders, inv, vectors, sh_pos, basis_pos, snd_pos);
    k_init_scal<<<(N_NODES*F + 255)/256, 256, 0, stream>>>(specS, embW, scalA);

    k_edge<<<N_NODES, 256, 0, stream>>>(0, row_ptr, snd_pos, sh_pos, basis_pos,
        rW1, rb1, rW2, scalA, aggG);
    k_lin<0><<<N_NODES/BL, 256, 0, stream>>>(specS, perm, aggG, linW, prodc, scW,
        ro0, ro1W1, ro1W2, feats, scalB, out);

    k_edge<<<N_NODES, 256, 0, stream>>>(1, row_ptr, snd_pos, sh_pos, basis_pos,
        rW1, rb1, rW2, scalB, aggG);
    k_lin<1><<<N_NODES/BL, 256, 0, stream>>>(specS, perm, aggG, linW, prodc, scW,
        ro0, ro1W1, ro1W2, feats, scalA, out);
}

// Round 9
// 1152.548 us; speedup vs baseline: 7.4004x; 1.2492x over previous
//
#include <hip/hip_runtime.h>
#include <math.h>
#include <stdint.h>

#define N_NODES 10000
#define N_EDGES 160000
#define F 128
#define NB 8
#define HR 64
#define NSPEC 10
#define PI_F 3.14159265358979323846f
#define GEDGE 16
#define BL 4

__device__ __forceinline__ float silu_f(float x){ return x / (1.f + expf(-x)); }

// ---------------- species counting sort ----------------
__global__ void k_scnt(const int* __restrict__ spec, int* __restrict__ scnt)
{
    int n = blockIdx.x * 256 + threadIdx.x;
    if (n < N_NODES) atomicAdd(&scnt[spec[n]], 1);
}

__global__ void k_sscan(const int* __restrict__ scnt, int* __restrict__ sptr)
{
    if (threadIdx.x == 0) {
        int acc = 0;
        for (int s = 0; s < NSPEC; ++s) { sptr[s] = acc; acc += scnt[s]; }
        sptr[NSPEC] = acc;
    }
}

__global__ void k_sfill(const int* __restrict__ spec, const int* __restrict__ sptr,
                        int* __restrict__ scur, int* __restrict__ perm,
                        int* __restrict__ inv, int* __restrict__ specS)
{
    int n = blockIdx.x * 256 + threadIdx.x;
    if (n >= N_NODES) return;
    int s = spec[n];
    int pos = sptr[s] + atomicAdd(&scur[s], 1);
    perm[pos] = n; inv[n] = pos; specS[pos] = s;
}

// ---------------- receiver histogram (sorted ids) ----------------
__global__ void k_count(const int* __restrict__ recv, const int* __restrict__ inv,
                        int* __restrict__ counts)
{
    int e = blockIdx.x * 256 + threadIdx.x;
    if (e >= N_EDGES) return;
    atomicAdd(&counts[inv[recv[e]]], 1);
}

// ---------------- block-wide scan -> row_ptr ----------------
__global__ void k_scan(const int* __restrict__ counts, int* __restrict__ row_ptr)
{
    __shared__ int ps[1024];
    const int t = threadIdx.x;
    int base = t * 10;
    int loc[10];
    int sum = 0;
    #pragma unroll
    for (int j = 0; j < 10; ++j) {
        int idx = base + j;
        int c = (idx < N_NODES) ? counts[idx] : 0;
        loc[j] = c; sum += c;
    }
    ps[t] = sum;
    __syncthreads();
    for (int off = 1; off < 1024; off <<= 1) {
        int v = (t >= off) ? ps[t-off] : 0;
        __syncthreads();
        ps[t] += v;
        __syncthreads();
    }
    int ex = ps[t] - sum;
    #pragma unroll
    for (int j = 0; j < 10; ++j) {
        int idx = base + j;
        if (idx < N_NODES) row_ptr[idx] = ex;
        ex += loc[j];
    }
    if (t == 1023) row_ptr[N_NODES] = ex;
}

// ---------------- fill CSR edge list (sorted ids) ----------------
__global__ void k_fill(const int* __restrict__ recv, const int* __restrict__ inv,
                       const int* __restrict__ row_ptr,
                       int* __restrict__ cursor, int* __restrict__ elist)
{
    int e = blockIdx.x * 256 + threadIdx.x;
    if (e >= N_EDGES) return;
    int r = inv[recv[e]];
    int pos = atomicAdd(&cursor[r], 1);
    elist[row_ptr[r] + pos] = e;
}

// ---------------- position-order edge precompute ----------------
__global__ void k_edge_pre(const int* __restrict__ elist, const int* __restrict__ senders,
                           const int* __restrict__ inv, const float* __restrict__ vec,
                           float* __restrict__ sh_pos, float* __restrict__ basis_pos,
                           int* __restrict__ snd_pos)
{
    int p = blockIdx.x * 256 + threadIdx.x;
    if (p >= N_EDGES) return;
    const int e = elist[p];
    snd_pos[p] = inv[senders[e]];
    float x = vec[e*3+0], y = vec[e*3+1], z = vec[e*3+2];
    float r = sqrtf(x*x + y*y + z*z);
    r = fmaxf(r, 1e-9f);
    float invr = 1.f / r;
    x *= invr; y *= invr; z *= invr;
    const float s3=1.7320508075688772f, s5=2.23606797749979f, s7=2.6457513110645907f,
                s15=3.872983346207417f, s42=6.480740698407860f, s70=8.366600265340756f,
                s105=10.246950765959598f;
    float* S = sh_pos + (size_t)p*16;
    S[0]=1.f; S[1]=s3*x; S[2]=s3*y; S[3]=s3*z;
    S[4]=s15*x*y; S[5]=s15*y*z; S[6]=0.5f*s5*(3.f*z*z-1.f); S[7]=s15*x*z;
    S[8]=0.5f*s15*(x*x-y*y);
    S[9]=0.25f*s70*y*(3.f*x*x-y*y); S[10]=s105*x*y*z; S[11]=0.25f*s42*y*(5.f*z*z-1.f);
    S[12]=0.5f*s7*(5.f*z*z*z-3.f*z); S[13]=0.25f*s42*x*(5.f*z*z-1.f);
    S[14]=0.5f*s105*z*(x*x-y*y); S[15]=0.25f*s70*x*(x*x-3.f*y*y);
    float rc = fminf(r, 5.0f);
    float cut = 0.5f * (cosf(PI_F * rc * 0.2f) + 1.f);
    float pref = sqrtf(0.4f) * cut / r;
    float* B = basis_pos + (size_t)p*8;
    #pragma unroll
    for (int k = 1; k <= 8; ++k) B[k-1] = pref * sinf(PI_F * 0.2f * (float)k * r);
}

// ---------------- init scalA = emb (sorted ids) ----------------
__global__ void k_init_scal(const int* __restrict__ specS, const float* __restrict__ embW,
                            float* __restrict__ scalA)
{
    int tid = blockIdx.x * 256 + threadIdx.x;
    if (tid >= N_NODES * F) return;
    int n = tid >> 7, f = tid & 127;
    scalA[tid] = embW[specS[n]*F + f];
}

// ---------------- fused radial + per-node edge aggregation -> aggG[n][f][m] ----------------
// block = 1 sorted node, 256 threads: f = t&127, mh = t>>7
__global__ __launch_bounds__(256) void k_edge(
    const int layer,
    const int* __restrict__ row_ptr,
    const int* __restrict__ snd_pos,
    const float* __restrict__ sh_pos,
    const float* __restrict__ basis_pos,
    const float* __restrict__ rW1,
    const float* __restrict__ rb1,
    const float* __restrict__ rW2,
    const float* __restrict__ scal_in,
    float* __restrict__ aggG)
{
    __shared__ float W1s[NB*HR];
    __shared__ float b1s[HR];
    __shared__ float hS[GEDGE][HR];     // 4 KB
    __shared__ float rwS[GEDGE*512];    // 32 KB

    const int t = threadIdx.x;
    const int n = blockIdx.x;
    const int f = t & 127;
    const int mh = t >> 7;
    const int e4 = t >> 6;   // wave id 0..3
    const int j64 = t & 63;

    W1s[t] = rW1[layer*NB*HR + t];
    W1s[256 + t] = rW1[layer*NB*HR + 256 + t];
    if (t < HR) b1s[t] = rb1[layer*HR + t];

    const float* W2g = rW2 + (size_t)layer*HR*512;
    const float4* sh4 = (const float4*)sh_pos;

    float acc[8] = {0,0,0,0,0,0,0,0};
    const int istart = row_ptr[n], iend = row_ptr[n+1];
    __syncthreads();

    for (int g0 = istart; g0 < iend; g0 += GEDGE) {
        const int gcnt = min(GEDGE, iend - g0);

        // ---- phase A: h for edges of this group (wave e4 -> e_loc = e4, e4+4, ...)
        #pragma unroll
        for (int q = 0; q < 4; ++q) {
            int e = e4 + q*4;
            float a = b1s[j64];
            if (e < gcnt) {
                const float4* B4 = (const float4*)(basis_pos + (size_t)(g0 + e)*8);
                float4 x0 = B4[0], x1 = B4[1];
                a = fmaf(x0.x, W1s[0*HR + j64], a);
                a = fmaf(x0.y, W1s[1*HR + j64], a);
                a = fmaf(x0.z, W1s[2*HR + j64], a);
                a = fmaf(x0.w, W1s[3*HR + j64], a);
                a = fmaf(x1.x, W1s[4*HR + j64], a);
                a = fmaf(x1.y, W1s[5*HR + j64], a);
                a = fmaf(x1.z, W1s[6*HR + j64], a);
                a = fmaf(x1.w, W1s[7*HR + j64], a);
            }
            hS[e][j64] = a / (1.f + expf(-a));
        }
        __syncthreads();

        // ---- phase B: thread t computes rw columns (2t, 2t+1) for all edges of group
        float r0[GEDGE], r1[GEDGE];
        #pragma unroll
        for (int e = 0; e < GEDGE; ++e) { r0[e] = 0.f; r1[e] = 0.f; }
        for (int jt = 0; jt < 4; ++jt) {
            float2 w[16];
            #pragma unroll
            for (int j = 0; j < 16; ++j)
                w[j] = *(const float2*)(W2g + (size_t)(jt*16 + j)*512 + 2*t);
            #pragma unroll
            for (int e = 0; e < GEDGE; ++e) {
                if (e < gcnt) {
                    const float4 ha = *(const float4*)&hS[e][jt*16 + 0];
                    const float4 hb = *(const float4*)&hS[e][jt*16 + 4];
                    const float4 hc = *(const float4*)&hS[e][jt*16 + 8];
                    const float4 hd = *(const float4*)&hS[e][jt*16 + 12];
                    r0[e]=fmaf(ha.x,w[0].x,r0[e]);  r1[e]=fmaf(ha.x,w[0].y,r1[e]);
                    r0[e]=fmaf(ha.y,w[1].x,r0[e]);  r1[e]=fmaf(ha.y,w[1].y,r1[e]);
                    r0[e]=fmaf(ha.z,w[2].x,r0[e]);  r1[e]=fmaf(ha.z,w[2].y,r1[e]);
                    r0[e]=fmaf(ha.w,w[3].x,r0[e]);  r1[e]=fmaf(ha.w,w[3].y,r1[e]);
                    r0[e]=fmaf(hb.x,w[4].x,r0[e]);  r1[e]=fmaf(hb.x,w[4].y,r1[e]);
                    r0[e]=fmaf(hb.y,w[5].x,r0[e]);  r1[e]=fmaf(hb.y,w[5].y,r1[e]);
                    r0[e]=fmaf(hb.z,w[6].x,r0[e]);  r1[e]=fmaf(hb.z,w[6].y,r1[e]);
                    r0[e]=fmaf(hb.w,w[7].x,r0[e]);  r1[e]=fmaf(hb.w,w[7].y,r1[e]);
                    r0[e]=fmaf(hc.x,w[8].x,r0[e]);  r1[e]=fmaf(hc.x,w[8].y,r1[e]);
                    r0[e]=fmaf(hc.y,w[9].x,r0[e]);  r1[e]=fmaf(hc.y,w[9].y,r1[e]);
                    r0[e]=fmaf(hc.z,w[10].x,r0[e]); r1[e]=fmaf(hc.z,w[10].y,r1[e]);
                    r0[e]=fmaf(hc.w,w[11].x,r0[e]); r1[e]=fmaf(hc.w,w[11].y,r1[e]);
                    r0[e]=fmaf(hd.x,w[12].x,r0[e]); r1[e]=fmaf(hd.x,w[12].y,r1[e]);
                    r0[e]=fmaf(hd.y,w[13].x,r0[e]); r1[e]=fmaf(hd.y,w[13].y,r1[e]);
                    r0[e]=fmaf(hd.z,w[14].x,r0[e]); r1[e]=fmaf(hd.z,w[14].y,r1[e]);
                    r0[e]=fmaf(hd.w,w[15].x,r0[e]); r1[e]=fmaf(hd.w,w[15].y,r1[e]);
                }
            }
        }
        #pragma unroll
        for (int e = 0; e < GEDGE; ++e)
            ((float2*)rwS)[e*256 + t] = make_float2(r0[e], r1[e]);
        __syncthreads();

        // ---- phase C: accumulate messages
        #pragma unroll
        for (int e = 0; e < GEDGE; ++e) {
            if (e < gcnt) {
                const int ii = g0 + e;
                const int snd = snd_pos[ii];
                const float sf = scal_in[(size_t)snd*F + f];
                const float4 rwv = *(const float4*)(rwS + e*512 + 4*f);
                const float4 shA = sh4[(size_t)ii*4 + mh*2 + 0];
                const float4 shB = sh4[(size_t)ii*4 + mh*2 + 1];
                if (mh == 0) {   // m=0..7, l=[0,1,1,1,2,2,2,2]
                    const float a0 = sf*rwv.x, a1 = sf*rwv.y, a2 = sf*rwv.z;
                    acc[0] = fmaf(a0, shA.x, acc[0]);
                    acc[1] = fmaf(a1, shA.y, acc[1]);
                    acc[2] = fmaf(a1, shA.z, acc[2]);
                    acc[3] = fmaf(a1, shA.w, acc[3]);
                    acc[4] = fmaf(a2, shB.x, acc[4]);
                    acc[5] = fmaf(a2, shB.y, acc[5]);
                    acc[6] = fmaf(a2, shB.z, acc[6]);
                    acc[7] = fmaf(a2, shB.w, acc[7]);
                } else {         // m=8..15, l=[2,3,3,3,3,3,3,3]
                    const float a2 = sf*rwv.z, a3 = sf*rwv.w;
                    acc[0] = fmaf(a2, shA.x, acc[0]);
                    acc[1] = fmaf(a3, shA.y, acc[1]);
                    acc[2] = fmaf(a3, shA.z, acc[2]);
                    acc[3] = fmaf(a3, shA.w, acc[3]);
                    acc[4] = fmaf(a3, shB.x, acc[4]);
                    acc[5] = fmaf(a3, shB.y, acc[5]);
                    acc[6] = fmaf(a3, shB.z, acc[6]);
                    acc[7] = fmaf(a3, shB.w, acc[7]);
                }
            }
        }
        __syncthreads();  // protect rwS/hS before next group
    }

    float4* wp = (float4*)(aggG + (size_t)n*2048 + f*16 + mh*8);
    wp[0] = make_float4(acc[0], acc[1], acc[2], acc[3]);
    wp[1] = make_float4(acc[4], acc[5], acc[6], acc[7]);
}

// ---------------- uniform-species GEMM pass: synchronous LDS weight staging ----------------
// No registers live across the compute loop (round-8 spill post-mortem).
__device__ __forceinline__ void lin_pass_uni(
    const float* __restrict__ src,
    const float* __restrict__ Wg,
    float (*wS)[16][128],     // [4][16][128] = 32 KB
    float (*tA)[16][16],      // [BL][16][16] = 4 KB
    const int n0, const int t, const int f, const int mh,
    float (&acc)[BL][8])
{
    const int n_loc = t >> 6;
    const int f_loc = (t >> 2) & 15;
    const int m4 = (t & 3) * 4;
    const int tq = t * 4;     // float offset of this thread's float4 within an 8KB l-chunk half

    for (int kt = 0; kt < 8; ++kt) {
        __syncthreads();   // previous kt's LDS reads done
        {
            // burst-load 9 independent float4s, then store to LDS (short register lifetime)
            float4 v0 = *(const float4*)(Wg + 0*(size_t)F*F + (size_t)kt*2048 + tq);
            float4 v1 = *(const float4*)(Wg + 0*(size_t)F*F + (size_t)kt*2048 + 1024 + tq);
            float4 v2 = *(const float4*)(Wg + 1*(size_t)F*F + (size_t)kt*2048 + tq);
            float4 v3 = *(const float4*)(Wg + 1*(size_t)F*F + (size_t)kt*2048 + 1024 + tq);
            float4 v4 = *(const float4*)(Wg + 2*(size_t)F*F + (size_t)kt*2048 + tq);
            float4 v5 = *(const float4*)(Wg + 2*(size_t)F*F + (size_t)kt*2048 + 1024 + tq);
            float4 v6 = *(const float4*)(Wg + 3*(size_t)F*F + (size_t)kt*2048 + tq);
            float4 v7 = *(const float4*)(Wg + 3*(size_t)F*F + (size_t)kt*2048 + 1024 + tq);
            float4 tv = *(const float4*)(src + (size_t)(n0 + n_loc)*2048 + (size_t)(kt*16 + f_loc)*16 + m4);
            *(float4*)(&wS[0][0][0] + tq)        = v0;
            *(float4*)(&wS[0][0][0] + 1024 + tq) = v1;
            *(float4*)(&wS[1][0][0] + tq)        = v2;
            *(float4*)(&wS[1][0][0] + 1024 + tq) = v3;
            *(float4*)(&wS[2][0][0] + tq)        = v4;
            *(float4*)(&wS[2][0][0] + 1024 + tq) = v5;
            *(float4*)(&wS[3][0][0] + tq)        = v6;
            *(float4*)(&wS[3][0][0] + 1024 + tq) = v7;
            *(float4*)&tA[n_loc][f_loc][m4]      = tv;
        }
        __syncthreads();
        // compute on LDS-resident tiles (mh branch wave-uniform, outside k-loop)
        if (mh == 0) {
            #pragma unroll 4
            for (int k = 0; k < 16; ++k) {
                const float w0 = wS[0][k][f];
                const float w1 = wS[1][k][f];
                const float w2 = wS[2][k][f];
                #pragma unroll
                for (int b = 0; b < BL; ++b) {
                    const float4 A  = *(const float4*)&tA[b][k][0];
                    const float4 Bv = *(const float4*)&tA[b][k][4];
                    acc[b][0] = fmaf(A.x,  w0, acc[b][0]);
                    acc[b][1] = fmaf(A.y,  w1, acc[b][1]);
                    acc[b][2] = fmaf(A.z,  w1, acc[b][2]);
                    acc[b][3] = fmaf(A.w,  w1, acc[b][3]);
                    acc[b][4] = fmaf(Bv.x, w2, acc[b][4]);
                    acc[b][5] = fmaf(Bv.y, w2, acc[b][5]);
                    acc[b][6] = fmaf(Bv.z, w2, acc[b][6]);
                    acc[b][7] = fmaf(Bv.w, w2, acc[b][7]);
                }
            }
        } else {
            #pragma unroll 4
            for (int k = 0; k < 16; ++k) {
                const float w2 = wS[2][k][f];
                const float w3 = wS[3][k][f];
                #pragma unroll
                for (int b = 0; b < BL; ++b) {
                    const float4 A  = *(const float4*)&tA[b][k][8];
                    const float4 Bv = *(const float4*)&tA[b][k][12];
                    acc[b][0] = fmaf(A.x,  w2, acc[b][0]);
                    acc[b][1] = fmaf(A.y,  w3, acc[b][1]);
                    acc[b][2] = fmaf(A.z,  w3, acc[b][2]);
                    acc[b][3] = fmaf(A.w,  w3, acc[b][3]);
                    acc[b][4] = fmaf(Bv.x, w3, acc[b][4]);
                    acc[b][5] = fmaf(Bv.y, w3, acc[b][5]);
                    acc[b][6] = fmaf(Bv.z, w3, acc[b][6]);
                    acc[b][7] = fmaf(Bv.w, w3, acc[b][7]);
                }
            }
        }
    }
}

// ---------------- slow path for rare mixed-species blocks ----------------
__device__ __forceinline__ void tile_mm_one(const float (&tile)[16][16],
    const float* __restrict__ W, const int kt, const int f, const int mh,
    float (&acc)[8])
{
    if (mh == 0) {
        for (int k = 0; k < 16; ++k) {
            const int f2 = kt*16 + k;
            const float w0 = W[(0*F + f2)*F + f];
            const float w1 = W[(1*F + f2)*F + f];
            const float w2 = W[(2*F + f2)*F + f];
            const float4 A  = *(const float4*)&tile[k][0];
            const float4 Bv = *(const float4*)&tile[k][4];
            acc[0] = fmaf(A.x,  w0, acc[0]);
            acc[1] = fmaf(A.y,  w1, acc[1]);
            acc[2] = fmaf(A.z,  w1, acc[2]);
            acc[3] = fmaf(A.w,  w1, acc[3]);
            acc[4] = fmaf(Bv.x, w2, acc[4]);
            acc[5] = fmaf(Bv.y, w2, acc[5]);
            acc[6] = fmaf(Bv.z, w2, acc[6]);
            acc[7] = fmaf(Bv.w, w2, acc[7]);
        }
    } else {
        for (int k = 0; k < 16; ++k) {
            const int f2 = kt*16 + k;
            const float w2 = W[(2*F + f2)*F + f];
            const float w3 = W[(3*F + f2)*F + f];
            const float4 A  = *(const float4*)&tile[k][8];
            const float4 Bv = *(const float4*)&tile[k][12];
            acc[0] = fmaf(A.x,  w2, acc[0]);
            acc[1] = fmaf(A.y,  w3, acc[1]);
            acc[2] = fmaf(A.z,  w3, acc[2]);
            acc[3] = fmaf(A.w,  w3, acc[3]);
            acc[4] = fmaf(Bv.x, w3, acc[4]);
            acc[5] = fmaf(Bv.y, w3, acc[5]);
            acc[6] = fmaf(Bv.z, w3, acc[6]);
            acc[7] = fmaf(Bv.w, w3, acc[7]);
        }
    }
}

__device__ __forceinline__ void lin_pass_mixed(
    const float* __restrict__ src,
    const float* __restrict__ Wbase,   // layer-resolved weight array base
    const int* sp,
    float (*tA)[16][16],
    const int n0, const int t, const int f, const int mh,
    float (&acc)[BL][8])
{
    const int n_loc = t >> 6;
    const int f_loc = (t >> 2) & 15;
    const int m4 = (t & 3) * 4;
    for (int kt = 0; kt < 8; ++kt) {
        __syncthreads();
        *(float4*)&tA[n_loc][f_loc][m4] =
            *(const float4*)(src + (size_t)(n0 + n_loc)*2048 + (size_t)(kt*16 + f_loc)*16 + m4);
        __syncthreads();
        #pragma unroll
        for (int b = 0; b < BL; ++b)
            tile_mm_one(tA[b], Wbase + ((size_t)sp[b]*4)*(F*F), kt, f, mh, acc[b]);
    }
}

// ---------------- species-batched linears + poly + readouts ----------------
template<int LAYER>
__global__ __launch_bounds__(256) void k_lin(
    const int* __restrict__ specS,
    const int* __restrict__ perm,
    const float* __restrict__ aggG,
    const float* __restrict__ linW,
    const float* __restrict__ prodc,
    const float* __restrict__ scW,
    const float* __restrict__ ro0,
    const float* __restrict__ ro1W1,
    const float* __restrict__ ro1W2,
    float* __restrict__ feats,
    float* __restrict__ scal_out,
    float* __restrict__ out)
{
    __shared__ float wS[4][16][128];   // 32 KB weight tile (current kt)
    __shared__ float tA[BL][16][16];   // 4 KB activation tile
    __shared__ float pS[BL][F];
    __shared__ float yS[BL][16];

    const int t = threadIdx.x;
    const int n0 = blockIdx.x * BL;
    const int f = t & 127;
    const int mh = t >> 7;
    const int j64 = t & 63;

    int sp[BL];
    #pragma unroll
    for (int b = 0; b < BL; ++b) sp[b] = specS[n0 + b];
    const bool uni = (sp[0]==sp[1]) && (sp[1]==sp[2]) && (sp[2]==sp[3]);

    float nv[BL][8];
    #pragma unroll
    for (int b = 0; b < BL; ++b)
        #pragma unroll
        for (int j = 0; j < 8; ++j) nv[b][j] = 0.f;

    const float* linL = linW + ((size_t)LAYER*NSPEC)*4*(F*F);
    const float* scL  = scW  + ((size_t)LAYER*NSPEC)*4*(F*F);

    // ---- pass 1: lin over aggG
    if (uni) lin_pass_uni(aggG, linL + ((size_t)sp[0]*4)*(F*F), wS, tA, n0, t, f, mh, nv);
    else     lin_pass_mixed(aggG, linL, sp, tA, n0, t, f, mh, nv);

    // EPS
    #pragma unroll
    for (int b = 0; b < BL; ++b)
        #pragma unroll
        for (int j = 0; j < 8; ++j) nv[b][j] *= 0.5f;

    // poly gate
    __syncthreads();
    if (mh == 0) {
        #pragma unroll
        for (int b = 0; b < BL; ++b) pS[b][f] = nv[b][0];
    }
    __syncthreads();
    #pragma unroll
    for (int b = 0; b < BL; ++b) {
        const float* pc = prodc + ((size_t)LAYER*NSPEC + sp[b])*3*F;
        float sg = pS[b][f];
        float poly = pc[f] + pc[F+f]*sg + pc[2*F+f]*sg*sg;
        #pragma unroll
        for (int j = 0; j < 8; ++j) nv[b][j] *= poly;
    }

    // ---- pass 2 (LAYER 1 only): skip-connection over old feats, same accumulators
    if (LAYER == 1) {
        if (uni) lin_pass_uni(feats, scL + ((size_t)sp[0]*4)*(F*F), wS, tA, n0, t, f, mh, nv);
        else     lin_pass_mixed(feats, scL, sp, tA, n0, t, f, mh, nv);
    }
    __syncthreads();

    // write feats
    #pragma unroll
    for (int b = 0; b < BL; ++b) {
        float4* wp = (float4*)(feats + (size_t)(n0+b)*2048 + f*16 + mh*8);
        wp[0] = make_float4(nv[b][0], nv[b][1], nv[b][2], nv[b][3]);
        wp[1] = make_float4(nv[b][4], nv[b][5], nv[b][6], nv[b][7]);
    }
    if (mh == 0) {
        #pragma unroll
        for (int b = 0; b < BL; ++b) scal_out[(size_t)(n0+b)*F + f] = nv[b][0];
    }
    __syncthreads();  // pS reuse below

    if (LAYER == 0) {
        if (mh == 0) {
            #pragma unroll
            for (int b = 0; b < BL; ++b) pS[b][f] = nv[b][0] * ro0[f];
        }
        __syncthreads();
        const int w = t >> 6;   // wave w reduces node w
        float v = pS[w][j64] + pS[w][j64 + 64];
        #pragma unroll
        for (int off = 32; off > 0; off >>= 1) v += __shfl_down(v, off);
        if (j64 == 0) out[(size_t)perm[n0 + w]*2 + 0] = v;
    } else {
        if (mh == 0) {
            #pragma unroll
            for (int b = 0; b < BL; ++b) pS[b][f] = nv[b][0];
        }
        __syncthreads();
        if (t < 64) {
            const int b = t >> 4, c = t & 15;
            float a = 0.f;
            for (int g = 0; g < F; ++g) a = fmaf(pS[b][g], ro1W1[g*16 + c], a);
            a = silu_f(a);
            yS[b][c] = a * ro1W2[c];
        }
        __syncthreads();
        if (t < BL) {
            float s = 0.f;
            #pragma unroll
            for (int j = 0; j < 16; ++j) s += yS[t][j];
            out[(size_t)perm[n0 + t]*2 + 1] = s;
        }
    }
}

extern "C" void kernel_launch(void* const* d_in, const int* in_sizes, int n_in,
                              void* d_out, int out_size, void* d_ws, size_t ws_size,
                              hipStream_t stream)
{
    (void)in_sizes; (void)n_in; (void)out_size; (void)ws_size;
    const float* vectors   = (const float*)d_in[0];
    const int*   spec      = (const int*)d_in[1];
    const int*   senders   = (const int*)d_in[2];
    const int*   receivers = (const int*)d_in[3];
    const float* embW      = (const float*)d_in[4];
    const float* rW1       = (const float*)d_in[5];
    const float* rb1       = (const float*)d_in[6];
    const float* rW2       = (const float*)d_in[7];
    const float* linW      = (const float*)d_in[8];
    const float* prodc     = (const float*)d_in[9];
    const float* scW       = (const float*)d_in[10];
    const float* ro0       = (const float*)d_in[11];
    const float* ro1W1     = (const float*)d_in[12];
    const float* ro1W2     = (const float*)d_in[13];
    float* out = (float*)d_out;

    char* ws = (char*)d_ws;
    float* scalA     = (float*)ws; ws += sizeof(float)*(size_t)N_NODES*F;
    float* scalB     = (float*)ws; ws += sizeof(float)*(size_t)N_NODES*F;
    float* feats     = (float*)ws; ws += sizeof(float)*(size_t)N_NODES*F*16;
    float* aggG      = (float*)ws; ws += sizeof(float)*(size_t)N_NODES*F*16;
    float* sh_pos    = (float*)ws; ws += sizeof(float)*(size_t)N_EDGES*16;
    float* basis_pos = (float*)ws; ws += sizeof(float)*(size_t)N_EDGES*8;
    int*   snd_pos   = (int*)ws;   ws += sizeof(int)*N_EDGES;
    int*   row_ptr   = (int*)ws;   ws += sizeof(int)*(N_NODES+1);
    // zeroed region: counts, cursor, scnt, scur (contiguous)
    int*   counts    = (int*)ws;   ws += sizeof(int)*N_NODES;
    int*   cursor    = (int*)ws;   ws += sizeof(int)*N_NODES;
    int*   scnt      = (int*)ws;   ws += sizeof(int)*16;
    int*   scur      = (int*)ws;   ws += sizeof(int)*16;
    int*   sptr      = (int*)ws;   ws += sizeof(int)*16;
    int*   perm      = (int*)ws;   ws += sizeof(int)*N_NODES;
    int*   inv       = (int*)ws;   ws += sizeof(int)*N_NODES;
    int*   specS     = (int*)ws;   ws += sizeof(int)*N_NODES;
    int*   elist     = (int*)ws;   ws += sizeof(int)*N_EDGES;

    hipMemsetAsync(counts, 0, sizeof(int)*(2*N_NODES + 32), stream);

    const int EB = (N_EDGES + 255) / 256;
    const int NBK = (N_NODES + 255) / 256;

    k_scnt<<<NBK, 256, 0, stream>>>(spec, scnt);
    k_sscan<<<1, 64, 0, stream>>>(scnt, sptr);
    k_sfill<<<NBK, 256, 0, stream>>>(spec, sptr, scur, perm, inv, specS);
    k_count<<<EB, 256, 0, stream>>>(receivers, inv, counts);
    k_scan<<<1, 1024, 0, stream>>>(counts, row_ptr);
    k_fill<<<EB, 256, 0, stream>>>(receivers, inv, row_ptr, cursor, elist);
    k_edge_pre<<<EB, 256, 0, stream>>>(elist, senders, inv, vectors, sh_pos, basis_pos, snd_pos);
    k_init_scal<<<(N_NODES*F + 255)/256, 256, 0, stream>>>(specS, embW, scalA);

    k_edge<<<N_NODES, 256, 0, stream>>>(0, row_ptr, snd_pos, sh_pos, basis_pos,
        rW1, rb1, rW2, scalA, aggG);
    k_lin<0><<<N_NODES/BL, 256, 0, stream>>>(specS, perm, aggG, linW, prodc, scW,
        ro0, ro1W1, ro1W2, feats, scalB, out);

    k_edge<<<N_NODES, 256, 0, stream>>>(1, row_ptr, snd_pos, sh_pos, basis_pos,
        rW1, rb1, rW2, scalB, aggG);
    k_lin<1><<<N_NODES/BL, 256, 0, stream>>>(specS, perm, aggG, linW, prodc, scW,
        ro0, ro1W1, ro1W2, feats, scalA, out);
}

// Round 10
// 1028.545 us; speedup vs baseline: 8.2926x; 1.1206x over previous
//
#include <hip/hip_runtime.h>
#include <math.h>
#include <stdint.h>

#define N_NODES 10000
#define N_EDGES 160000
#define F 128
#define NB 8
#define HR 64
#define NSPEC 10
#define PI_F 3.14159265358979323846f
#define GEDGE 16
#define NPAD 10160
#define NT_MAX 635

typedef unsigned short ushort_t;
typedef __attribute__((ext_vector_type(8))) short short8;   // 8 bf16 = 4 VGPRs
typedef __attribute__((ext_vector_type(4))) float f32x4;    // 4 fp32 acc

__device__ __forceinline__ float silu_f(float x){ return x / (1.f + expf(-x)); }
__device__ __forceinline__ float bfu(ushort_t u) {
    union { unsigned int i; float f; } v; v.i = ((unsigned int)u) << 16; return v.f;
}
__device__ __forceinline__ ushort_t f2bf(float f) {
    union { float f; unsigned int i; } v; v.f = f;
    unsigned int x = v.i;
    unsigned int r = (x + 0x7fffu + ((x >> 16) & 1u)) >> 16;
    return (ushort_t)r;
}

// ---------------- species counting sort ----------------
__global__ void k_scnt(const int* __restrict__ spec, int* __restrict__ scnt)
{
    int n = blockIdx.x * 256 + threadIdx.x;
    if (n < N_NODES) atomicAdd(&scnt[spec[n]], 1);
}

__global__ void k_sscan(const int* __restrict__ scnt, int* __restrict__ sptr,
                        int* __restrict__ psptr, int* __restrict__ tile_spec)
{
    if (threadIdx.x == 0) {
        int acc = 0, pacc = 0;
        for (int s = 0; s < NSPEC; ++s) {
            sptr[s] = acc; psptr[s] = pacc;
            acc += scnt[s];
            pacc += ((scnt[s] + 15) >> 4) << 4;
        }
        sptr[NSPEC] = acc; psptr[NSPEC] = pacc;
        for (int tt = 0; tt < NT_MAX; ++tt) tile_spec[tt] = -1;
        for (int s = 0; s < NSPEC; ++s) {
            int t0 = psptr[s] >> 4;
            int t1 = t0 + ((scnt[s] + 15) >> 4);
            for (int tt = t0; tt < t1; ++tt) tile_spec[tt] = s;
        }
    }
}

__global__ void k_sfill(const int* __restrict__ spec, const int* __restrict__ sptr,
                        const int* __restrict__ psptr,
                        int* __restrict__ scur, int* __restrict__ perm,
                        int* __restrict__ inv, int* __restrict__ specS,
                        int* __restrict__ pn)
{
    int n = blockIdx.x * 256 + threadIdx.x;
    if (n >= N_NODES) return;
    int s = spec[n];
    int pos = sptr[s] + atomicAdd(&scur[s], 1);
    perm[pos] = n; inv[n] = pos; specS[pos] = s;
    pn[pos] = psptr[s] + (pos - sptr[s]);
}

// ---------------- receiver histogram (sorted ids) ----------------
__global__ void k_count(const int* __restrict__ recv, const int* __restrict__ inv,
                        int* __restrict__ counts)
{
    int e = blockIdx.x * 256 + threadIdx.x;
    if (e >= N_EDGES) return;
    atomicAdd(&counts[inv[recv[e]]], 1);
}

// ---------------- block-wide scan -> row_ptr ----------------
__global__ void k_scan(const int* __restrict__ counts, int* __restrict__ row_ptr)
{
    __shared__ int ps[1024];
    const int t = threadIdx.x;
    int base = t * 10;
    int loc[10];
    int sum = 0;
    #pragma unroll
    for (int j = 0; j < 10; ++j) {
        int idx = base + j;
        int c = (idx < N_NODES) ? counts[idx] : 0;
        loc[j] = c; sum += c;
    }
    ps[t] = sum;
    __syncthreads();
    for (int off = 1; off < 1024; off <<= 1) {
        int v = (t >= off) ? ps[t-off] : 0;
        __syncthreads();
        ps[t] += v;
        __syncthreads();
    }
    int ex = ps[t] - sum;
    #pragma unroll
    for (int j = 0; j < 10; ++j) {
        int idx = base + j;
        if (idx < N_NODES) row_ptr[idx] = ex;
        ex += loc[j];
    }
    if (t == 1023) row_ptr[N_NODES] = ex;
}

// ---------------- fill CSR edge list (sorted ids) ----------------
__global__ void k_fill(const int* __restrict__ recv, const int* __restrict__ inv,
                       const int* __restrict__ row_ptr,
                       int* __restrict__ cursor, int* __restrict__ elist)
{
    int e = blockIdx.x * 256 + threadIdx.x;
    if (e >= N_EDGES) return;
    int r = inv[recv[e]];
    int pos = atomicAdd(&cursor[r], 1);
    elist[row_ptr[r] + pos] = e;
}

// ---------------- position-order edge precompute (snd_pos = PADDED row of sender) ----------------
__global__ void k_edge_pre(const int* __restrict__ elist, const int* __restrict__ senders,
                           const int* __restrict__ inv, const int* __restrict__ pn,
                           const float* __restrict__ vec,
                           float* __restrict__ sh_pos, float* __restrict__ basis_pos,
                           int* __restrict__ snd_pos)
{
    int p = blockIdx.x * 256 + threadIdx.x;
    if (p >= N_EDGES) return;
    const int e = elist[p];
    snd_pos[p] = pn[inv[senders[e]]];
    float x = vec[e*3+0], y = vec[e*3+1], z = vec[e*3+2];
    float r = sqrtf(x*x + y*y + z*z);
    r = fmaxf(r, 1e-9f);
    float invr = 1.f / r;
    x *= invr; y *= invr; z *= invr;
    const float s3=1.7320508075688772f, s5=2.23606797749979f, s7=2.6457513110645907f,
                s15=3.872983346207417f, s42=6.480740698407860f, s70=8.366600265340756f,
                s105=10.246950765959598f;
    float* S = sh_pos + (size_t)p*16;
    S[0]=1.f; S[1]=s3*x; S[2]=s3*y; S[3]=s3*z;
    S[4]=s15*x*y; S[5]=s15*y*z; S[6]=0.5f*s5*(3.f*z*z-1.f); S[7]=s15*x*z;
    S[8]=0.5f*s15*(x*x-y*y);
    S[9]=0.25f*s70*y*(3.f*x*x-y*y); S[10]=s105*x*y*z; S[11]=0.25f*s42*y*(5.f*z*z-1.f);
    S[12]=0.5f*s7*(5.f*z*z*z-3.f*z); S[13]=0.25f*s42*x*(5.f*z*z-1.f);
    S[14]=0.5f*s105*z*(x*x-y*y); S[15]=0.25f*s70*x*(x*x-3.f*y*y);
    float rc = fminf(r, 5.0f);
    float cut = 0.5f * (cosf(PI_F * rc * 0.2f) + 1.f);
    float pref = sqrtf(0.4f) * cut / r;
    float* B = basis_pos + (size_t)p*8;
    #pragma unroll
    for (int k = 1; k <= 8; ++k) B[k-1] = pref * sinf(PI_F * 0.2f * (float)k * r);
}

// ---------------- init featsB plane 0 = emb (bf16, padded rows) ----------------
__global__ void k_init_f0(const int* __restrict__ specS, const int* __restrict__ pn,
                          const float* __restrict__ embW, ushort_t* __restrict__ featsB)
{
    int tid = blockIdx.x * 256 + threadIdx.x;
    if (tid >= N_NODES * F) return;
    int n = tid >> 7, f = tid & 127;
    featsB[(size_t)pn[n]*128 + f] = f2bf(embW[specS[n]*F + f]);
}

// ---------------- convert + transpose lin/sc weights to bf16: WB[mat][f_out][f_in] ----------------
__global__ void k_conv_w(const float* __restrict__ linW, const float* __restrict__ scW,
                         ushort_t* __restrict__ WBlin, ushort_t* __restrict__ WBsc)
{
    int tid = blockIdx.x * 256 + threadIdx.x;
    const int TOT = 80 * 16384;   // 2 layers x 10 spec x 4 l matrices of 128x128
    if (tid >= 2*TOT) return;
    const float* src; ushort_t* dst; int rel;
    if (tid < TOT) { src = linW; dst = WBlin; rel = tid; }
    else           { src = scW;  dst = WBsc;  rel = tid - TOT; }
    int mat = rel >> 14;
    int r = rel & 16383;
    int f = r >> 7, f2 = r & 127;
    dst[(size_t)mat*16384 + f*128 + f2] = f2bf(src[(size_t)mat*16384 + f2*128 + f]);
}

// ---------------- fused radial + per-node edge aggregation -> aggB[m][row][f] (bf16) ----------------
// block = 1 sorted node, 256 threads: f = t&127, mh = t>>7
__global__ __launch_bounds__(256) void k_edge(
    const int layer,
    const int* __restrict__ row_ptr,
    const int* __restrict__ snd_pos,
    const int* __restrict__ pn,
    const float* __restrict__ sh_pos,
    const float* __restrict__ basis_pos,
    const float* __restrict__ rW1,
    const float* __restrict__ rb1,
    const float* __restrict__ rW2,
    const ushort_t* __restrict__ fB0,     // featsB plane 0 = scal (bf16, padded rows)
    ushort_t* __restrict__ aggB)
{
    __shared__ float W1s[NB*HR];
    __shared__ float b1s[HR];
    __shared__ float hS[GEDGE][HR];     // 4 KB
    __shared__ float rwS[GEDGE*512];    // 32 KB

    const int t = threadIdx.x;
    const int n = blockIdx.x;
    const int f = t & 127;
    const int mh = t >> 7;
    const int e4 = t >> 6;   // wave id 0..3
    const int j64 = t & 63;

    W1s[t] = rW1[layer*NB*HR + t];
    W1s[256 + t] = rW1[layer*NB*HR + 256 + t];
    if (t < HR) b1s[t] = rb1[layer*HR + t];

    const float* W2g = rW2 + (size_t)layer*HR*512;
    const float4* sh4 = (const float4*)sh_pos;

    float acc[8] = {0,0,0,0,0,0,0,0};
    const int istart = row_ptr[n], iend = row_ptr[n+1];
    __syncthreads();

    for (int g0 = istart; g0 < iend; g0 += GEDGE) {
        const int gcnt = min(GEDGE, iend - g0);

        // ---- phase A: h for edges of this group
        #pragma unroll
        for (int q = 0; q < 4; ++q) {
            int e = e4 + q*4;
            float a = b1s[j64];
            if (e < gcnt) {
                const float4* B4 = (const float4*)(basis_pos + (size_t)(g0 + e)*8);
                float4 x0 = B4[0], x1 = B4[1];
                a = fmaf(x0.x, W1s[0*HR + j64], a);
                a = fmaf(x0.y, W1s[1*HR + j64], a);
                a = fmaf(x0.z, W1s[2*HR + j64], a);
                a = fmaf(x0.w, W1s[3*HR + j64], a);
                a = fmaf(x1.x, W1s[4*HR + j64], a);
                a = fmaf(x1.y, W1s[5*HR + j64], a);
                a = fmaf(x1.z, W1s[6*HR + j64], a);
                a = fmaf(x1.w, W1s[7*HR + j64], a);
            }
            hS[e][j64] = a / (1.f + expf(-a));
        }
        __syncthreads();

        // ---- phase B: thread t computes rw columns (2t, 2t+1)
        float r0[GEDGE], r1[GEDGE];
        #pragma unroll
        for (int e = 0; e < GEDGE; ++e) { r0[e] = 0.f; r1[e] = 0.f; }
        for (int jt = 0; jt < 4; ++jt) {
            float2 w[16];
            #pragma unroll
            for (int j = 0; j < 16; ++j)
                w[j] = *(const float2*)(W2g + (size_t)(jt*16 + j)*512 + 2*t);
            #pragma unroll
            for (int e = 0; e < GEDGE; ++e) {
                if (e < gcnt) {
                    const float4 ha = *(const float4*)&hS[e][jt*16 + 0];
                    const float4 hb = *(const float4*)&hS[e][jt*16 + 4];
                    const float4 hc = *(const float4*)&hS[e][jt*16 + 8];
                    const float4 hd = *(const float4*)&hS[e][jt*16 + 12];
                    r0[e]=fmaf(ha.x,w[0].x,r0[e]);  r1[e]=fmaf(ha.x,w[0].y,r1[e]);
                    r0[e]=fmaf(ha.y,w[1].x,r0[e]);  r1[e]=fmaf(ha.y,w[1].y,r1[e]);
                    r0[e]=fmaf(ha.z,w[2].x,r0[e]);  r1[e]=fmaf(ha.z,w[2].y,r1[e]);
                    r0[e]=fmaf(ha.w,w[3].x,r0[e]);  r1[e]=fmaf(ha.w,w[3].y,r1[e]);
                    r0[e]=fmaf(hb.x,w[4].x,r0[e]);  r1[e]=fmaf(hb.x,w[4].y,r1[e]);
                    r0[e]=fmaf(hb.y,w[5].x,r0[e]);  r1[e]=fmaf(hb.y,w[5].y,r1[e]);
                    r0[e]=fmaf(hb.z,w[6].x,r0[e]);  r1[e]=fmaf(hb.z,w[6].y,r1[e]);
                    r0[e]=fmaf(hb.w,w[7].x,r0[e]);  r1[e]=fmaf(hb.w,w[7].y,r1[e]);
                    r0[e]=fmaf(hc.x,w[8].x,r0[e]);  r1[e]=fmaf(hc.x,w[8].y,r1[e]);
                    r0[e]=fmaf(hc.y,w[9].x,r0[e]);  r1[e]=fmaf(hc.y,w[9].y,r1[e]);
                    r0[e]=fmaf(hc.z,w[10].x,r0[e]); r1[e]=fmaf(hc.z,w[10].y,r1[e]);
                    r0[e]=fmaf(hc.w,w[11].x,r0[e]); r1[e]=fmaf(hc.w,w[11].y,r1[e]);
                    r0[e]=fmaf(hd.x,w[12].x,r0[e]); r1[e]=fmaf(hd.x,w[12].y,r1[e]);
                    r0[e]=fmaf(hd.y,w[13].x,r0[e]); r1[e]=fmaf(hd.y,w[13].y,r1[e]);
                    r0[e]=fmaf(hd.z,w[14].x,r0[e]); r1[e]=fmaf(hd.z,w[14].y,r1[e]);
                    r0[e]=fmaf(hd.w,w[15].x,r0[e]); r1[e]=fmaf(hd.w,w[15].y,r1[e]);
                }
            }
        }
        #pragma unroll
        for (int e = 0; e < GEDGE; ++e)
            ((float2*)rwS)[e*256 + t] = make_float2(r0[e], r1[e]);
        __syncthreads();

        // ---- phase C: accumulate messages
        #pragma unroll
        for (int e = 0; e < GEDGE; ++e) {
            if (e < gcnt) {
                const int ii = g0 + e;
                const int snd = snd_pos[ii];                 // padded row of sender
                const float sf = bfu(fB0[(size_t)snd*128 + f]);
                const float4 rwv = *(const float4*)(rwS + e*512 + 4*f);
                const float4 shA = sh4[(size_t)ii*4 + mh*2 + 0];
                const float4 shB = sh4[(size_t)ii*4 + mh*2 + 1];
                if (mh == 0) {   // m=0..7, l=[0,1,1,1,2,2,2,2]
                    const float a0 = sf*rwv.x, a1 = sf*rwv.y, a2 = sf*rwv.z;
                    acc[0] = fmaf(a0, shA.x, acc[0]);
                    acc[1] = fmaf(a1, shA.y, acc[1]);
                    acc[2] = fmaf(a1, shA.z, acc[2]);
                    acc[3] = fmaf(a1, shA.w, acc[3]);
                    acc[4] = fmaf(a2, shB.x, acc[4]);
                    acc[5] = fmaf(a2, shB.y, acc[5]);
                    acc[6] = fmaf(a2, shB.z, acc[6]);
                    acc[7] = fmaf(a2, shB.w, acc[7]);
                } else {         // m=8..15, l=[2,3,3,3,3,3,3,3]
                    const float a2 = sf*rwv.z, a3 = sf*rwv.w;
                    acc[0] = fmaf(a2, shA.x, acc[0]);
                    acc[1] = fmaf(a3, shA.y, acc[1]);
                    acc[2] = fmaf(a3, shA.z, acc[2]);
                    acc[3] = fmaf(a3, shA.w, acc[3]);
                    acc[4] = fmaf(a3, shB.x, acc[4]);
                    acc[5] = fmaf(a3, shB.y, acc[5]);
                    acc[6] = fmaf(a3, shB.z, acc[6]);
                    acc[7] = fmaf(a3, shB.w, acc[7]);
                }
            }
        }
        __syncthreads();  // protect rwS/hS before next group
    }

    // write aggB[m][row][f] bf16, m-major planes
    const int row = pn[n];
    #pragma unroll
    for (int j = 0; j < 8; ++j) {
        const int m = mh*8 + j;
        aggB[((size_t)m*NPAD + row)*128 + f] = f2bf(acc[j]);
    }
}

// ---------------- bf16 MFMA grouped GEMM: outG[m][rows][f] (+=) A[m][rows][f2] x W[spec][l][f][f2]^T ----------------
// block = (tile of 16 padded rows, m-plane); 4 waves x 2 N-tiles x 4 K-chunks of mfma_16x16x32_bf16
template<int ACC>
__global__ __launch_bounds__(256) void k_gemm(
    const ushort_t* __restrict__ A,     // [16][NPAD][128] bf16
    const ushort_t* __restrict__ WB,    // [NSPEC][4][128][128] bf16 (layer-resolved, transposed)
    const int* __restrict__ tile_spec,
    float* __restrict__ outG)           // [16][NPAD][128] f32
{
    const int tile = blockIdx.x;
    const int m = blockIdx.y;
    const int spec = tile_spec[tile];
    if (spec < 0) return;
    const int l = (m == 0) ? 0 : (m < 4) ? 1 : (m < 9) ? 2 : 3;
    const int t = threadIdx.x;
    const int lane = t & 63;
    const int wv = t >> 6;
    const int r16 = lane & 15;
    const int quad = lane >> 4;

    const ushort_t* Ap = A + ((size_t)m*NPAD + (size_t)tile*16)*128;
    const ushort_t* Wp = WB + ((size_t)(spec*4 + l))*128*128;

    short8 a[4];
    #pragma unroll
    for (int c = 0; c < 4; ++c)
        a[c] = *(const short8*)(Ap + (size_t)r16*128 + c*32 + quad*8);

    #pragma unroll
    for (int nt = 0; nt < 2; ++nt) {
        const int fc = wv*32 + nt*16 + r16;
        f32x4 acc;
        if (ACC) {
            #pragma unroll
            for (int r = 0; r < 4; ++r)
                acc[r] = outG[((size_t)m*NPAD + tile*16 + quad*4 + r)*128 + fc];
        } else {
            acc = (f32x4){0.f, 0.f, 0.f, 0.f};
        }
        #pragma unroll
        for (int c = 0; c < 4; ++c) {
            short8 b = *(const short8*)(Wp + (size_t)fc*128 + c*32 + quad*8);
            acc = __builtin_amdgcn_mfma_f32_16x16x32_bf16(a[c], b, acc, 0, 0, 0);
        }
        #pragma unroll
        for (int r = 0; r < 4; ++r)
            outG[((size_t)m*NPAD + tile*16 + quad*4 + r)*128 + fc] = acc[r];
    }
}

// ---------------- EPS + poly gate in-place on outG ----------------
__global__ void k_poly(const int layer, const int* __restrict__ specS,
                       const int* __restrict__ pn, const float* __restrict__ prodc,
                       float* __restrict__ outG)
{
    int tid = blockIdx.x * 256 + threadIdx.x;
    if (tid >= N_NODES * F) return;
    int n = tid >> 7, f = tid & 127;
    int row = pn[n];
    const float* pc = prodc + ((size_t)layer*NSPEC + specS[n])*3*F;
    float sg = outG[(size_t)row*128 + f] * 0.5f;   // EPS applied to m=0
    float poly = pc[f] + pc[F+f]*sg + pc[2*F+f]*sg*sg;
    float g = 0.5f * poly;                          // EPS * poly for all m
    #pragma unroll
    for (int m = 0; m < 16; ++m) {
        size_t idx = ((size_t)m*NPAD + row)*128 + f;
        outG[idx] *= g;
    }
}

// ---------------- layer-0 epilogue: feats write (bf16) + readout0 ----------------
__global__ __launch_bounds__(256) void k_epi0(
    const int* __restrict__ pn, const int* __restrict__ perm,
    const float* __restrict__ outG, const float* __restrict__ ro0,
    ushort_t* __restrict__ featsB, float* __restrict__ out)
{
    __shared__ float redS[128];
    const int t = threadIdx.x, n = blockIdx.x;
    const int f = t & 127, mh = t >> 7;
    const int row = pn[n];
    float v0 = 0.f;
    #pragma unroll
    for (int j = 0; j < 8; ++j) {
        const int m = mh*8 + j;
        const size_t idx = ((size_t)m*NPAD + row)*128 + f;
        float v = outG[idx];
        featsB[idx] = f2bf(v);
        if (m == 0) v0 = v;
    }
    if (mh == 0) redS[f] = v0 * ro0[f];
    __syncthreads();
    for (int off = 64; off > 0; off >>= 1) {
        if (t < off) redS[t] += redS[t + off];
        __syncthreads();
    }
    if (t == 0) out[(size_t)perm[n]*2 + 0] = redS[0];
}

// ---------------- layer-1 epilogue: readout1 (silu MLP) ----------------
__global__ __launch_bounds__(256) void k_epi1(
    const int* __restrict__ pn, const int* __restrict__ perm,
    const float* __restrict__ outG,
    const float* __restrict__ ro1W1, const float* __restrict__ ro1W2,
    float* __restrict__ out)
{
    __shared__ float sS[128];
    __shared__ float yS[16];
    const int t = threadIdx.x, n = blockIdx.x;
    const int row = pn[n];
    if (t < 128) sS[t] = outG[(size_t)row*128 + t];
    __syncthreads();
    if (t < 16) {
        float a = 0.f;
        for (int g = 0; g < F; ++g) a = fmaf(sS[g], ro1W1[g*16 + t], a);
        a = silu_f(a);
        yS[t] = a * ro1W2[t];
    }
    __syncthreads();
    if (t == 0) {
        float s = 0.f;
        #pragma unroll
        for (int j = 0; j < 16; ++j) s += yS[j];
        out[(size_t)perm[n]*2 + 1] = s;
    }
}

extern "C" void kernel_launch(void* const* d_in, const int* in_sizes, int n_in,
                              void* d_out, int out_size, void* d_ws, size_t ws_size,
                              hipStream_t stream)
{
    (void)in_sizes; (void)n_in; (void)out_size; (void)ws_size;
    const float* vectors   = (const float*)d_in[0];
    const int*   spec      = (const int*)d_in[1];
    const int*   senders   = (const int*)d_in[2];
    const int*   receivers = (const int*)d_in[3];
    const float* embW      = (const float*)d_in[4];
    const float* rW1       = (const float*)d_in[5];
    const float* rb1       = (const float*)d_in[6];
    const float* rW2       = (const float*)d_in[7];
    const float* linW      = (const float*)d_in[8];
    const float* prodc     = (const float*)d_in[9];
    const float* scW       = (const float*)d_in[10];
    const float* ro0       = (const float*)d_in[11];
    const float* ro1W1     = (const float*)d_in[12];
    const float* ro1W2     = (const float*)d_in[13];
    float* out = (float*)d_out;

    char* ws = (char*)d_ws;
    float*    outG      = (float*)ws;    ws += sizeof(float)*(size_t)16*NPAD*128;    // 83.2 MB
    float*    sh_pos    = (float*)ws;    ws += sizeof(float)*(size_t)N_EDGES*16;     // 10.24
    float*    basis_pos = (float*)ws;    ws += sizeof(float)*(size_t)N_EDGES*8;      // 5.12
    ushort_t* featsB    = (ushort_t*)ws; ws += sizeof(ushort_t)*(size_t)16*NPAD*128; // 41.6
    ushort_t* aggB      = (ushort_t*)ws; ws += sizeof(ushort_t)*(size_t)16*NPAD*128; // 41.6
    ushort_t* WBlin     = (ushort_t*)ws; ws += sizeof(ushort_t)*(size_t)80*16384;    // 2.62
    ushort_t* WBsc      = (ushort_t*)ws; ws += sizeof(ushort_t)*(size_t)80*16384;    // 2.62
    int* snd_pos   = (int*)ws; ws += sizeof(int)*N_EDGES;
    int* row_ptr   = (int*)ws; ws += sizeof(int)*(N_NODES+1);
    // zeroed region: counts, cursor, scnt, scur (contiguous)
    int* counts    = (int*)ws; ws += sizeof(int)*N_NODES;
    int* cursor    = (int*)ws; ws += sizeof(int)*N_NODES;
    int* scnt      = (int*)ws; ws += sizeof(int)*16;
    int* scur      = (int*)ws; ws += sizeof(int)*16;
    int* sptr      = (int*)ws; ws += sizeof(int)*16;
    int* psptr     = (int*)ws; ws += sizeof(int)*16;
    int* perm      = (int*)ws; ws += sizeof(int)*N_NODES;
    int* inv       = (int*)ws; ws += sizeof(int)*N_NODES;
    int* specS     = (int*)ws; ws += sizeof(int)*N_NODES;
    int* pn        = (int*)ws; ws += sizeof(int)*N_NODES;
    int* tile_spec = (int*)ws; ws += sizeof(int)*NT_MAX;
    int* elist     = (int*)ws; ws += sizeof(int)*N_EDGES;

    hipMemsetAsync(counts, 0, sizeof(int)*(2*N_NODES + 32), stream);

    const int EB  = (N_EDGES + 255) / 256;
    const int NBK = (N_NODES + 255) / 256;

    k_scnt<<<NBK, 256, 0, stream>>>(spec, scnt);
    k_sscan<<<1, 64, 0, stream>>>(scnt, sptr, psptr, tile_spec);
    k_sfill<<<NBK, 256, 0, stream>>>(spec, sptr, psptr, scur, perm, inv, specS, pn);
    k_count<<<EB, 256, 0, stream>>>(receivers, inv, counts);
    k_scan<<<1, 1024, 0, stream>>>(counts, row_ptr);
    k_fill<<<EB, 256, 0, stream>>>(receivers, inv, row_ptr, cursor, elist);
    k_edge_pre<<<EB, 256, 0, stream>>>(elist, senders, inv, pn, vectors, sh_pos, basis_pos, snd_pos);
    k_init_f0<<<(N_NODES*F + 255)/256, 256, 0, stream>>>(specS, pn, embW, featsB);
    k_conv_w<<<(2*80*16384 + 255)/256, 256, 0, stream>>>(linW, scW, WBlin, WBsc);

    const size_t WL = (size_t)NSPEC*4*128*128;   // per-layer weight stride (bf16 elems)
    dim3 ggrid(NT_MAX, 16);

    // ---- layer 0 ----
    k_edge<<<N_NODES, 256, 0, stream>>>(0, row_ptr, snd_pos, pn, sh_pos, basis_pos,
        rW1, rb1, rW2, featsB, aggB);
    k_gemm<0><<<ggrid, 256, 0, stream>>>(aggB, WBlin + 0*WL, tile_spec, outG);
    k_poly<<<(N_NODES*F + 255)/256, 256, 0, stream>>>(0, specS, pn, prodc, outG);
    k_epi0<<<N_NODES, 256, 0, stream>>>(pn, perm, outG, ro0, featsB, out);

    // ---- layer 1 ----
    k_edge<<<N_NODES, 256, 0, stream>>>(1, row_ptr, snd_pos, pn, sh_pos, basis_pos,
        rW1, rb1, rW2, featsB, aggB);
    k_gemm<0><<<ggrid, 256, 0, stream>>>(aggB, WBlin + 1*WL, tile_spec, outG);
    k_poly<<<(N_NODES*F + 255)/256, 256, 0, stream>>>(1, specS, pn, prodc, outG);
    k_gemm<1><<<ggrid, 256, 0, stream>>>(featsB, WBsc + 1*WL, tile_spec, outG);
    k_epi1<<<N_NODES, 256, 0, stream>>>(pn, perm, outG, ro1W1, ro1W2, out);
}

// Round 11
// 823.091 us; speedup vs baseline: 10.3625x; 1.2496x over previous
//
#include <hip/hip_runtime.h>
#include <math.h>
#include <stdint.h>

#define N_NODES 10000
#define N_EDGES 160000
#define F 128
#define NB 8
#define HR 64
#define NSPEC 10
#define PI_F 3.14159265358979323846f
#define GEDGE 16
#define NPAD 10160
#define NT_MAX 635
#define RWP 516   // rwS row stride (floats): 512 + 4 pad -> 2-way banks

typedef unsigned short ushort_t;
typedef __attribute__((ext_vector_type(8))) short short8;   // 8 bf16 = 4 VGPRs
typedef __attribute__((ext_vector_type(4))) float f32x4;    // 4 fp32 acc

__device__ __forceinline__ float silu_f(float x){ return x / (1.f + expf(-x)); }
__device__ __forceinline__ float bfu(ushort_t u) {
    union { unsigned int i; float f; } v; v.i = ((unsigned int)u) << 16; return v.f;
}
__device__ __forceinline__ ushort_t f2bf(float f) {
    union { float f; unsigned int i; } v; v.f = f;
    unsigned int x = v.i;
    unsigned int r = (x + 0x7fffu + ((x >> 16) & 1u)) >> 16;
    return (ushort_t)r;
}

// ---------------- species counting sort ----------------
__global__ void k_scnt(const int* __restrict__ spec, int* __restrict__ scnt)
{
    int n = blockIdx.x * 256 + threadIdx.x;
    if (n < N_NODES) atomicAdd(&scnt[spec[n]], 1);
}

__global__ void k_sscan(const int* __restrict__ scnt, int* __restrict__ sptr,
                        int* __restrict__ psptr, int* __restrict__ tile_spec)
{
    if (threadIdx.x == 0) {
        int acc = 0, pacc = 0;
        for (int s = 0; s < NSPEC; ++s) {
            sptr[s] = acc; psptr[s] = pacc;
            acc += scnt[s];
            pacc += ((scnt[s] + 15) >> 4) << 4;
        }
        sptr[NSPEC] = acc; psptr[NSPEC] = pacc;
        for (int tt = 0; tt < NT_MAX; ++tt) tile_spec[tt] = -1;
        for (int s = 0; s < NSPEC; ++s) {
            int t0 = psptr[s] >> 4;
            int t1 = t0 + ((scnt[s] + 15) >> 4);
            for (int tt = t0; tt < t1; ++tt) tile_spec[tt] = s;
        }
    }
}

__global__ void k_sfill(const int* __restrict__ spec, const int* __restrict__ sptr,
                        const int* __restrict__ psptr,
                        int* __restrict__ scur, int* __restrict__ perm,
                        int* __restrict__ inv, int* __restrict__ specS,
                        int* __restrict__ pn)
{
    int n = blockIdx.x * 256 + threadIdx.x;
    if (n >= N_NODES) return;
    int s = spec[n];
    int pos = sptr[s] + atomicAdd(&scur[s], 1);
    perm[pos] = n; inv[n] = pos; specS[pos] = s;
    pn[pos] = psptr[s] + (pos - sptr[s]);
}

// ---------------- receiver histogram (sorted ids) ----------------
__global__ void k_count(const int* __restrict__ recv, const int* __restrict__ inv,
                        int* __restrict__ counts)
{
    int e = blockIdx.x * 256 + threadIdx.x;
    if (e >= N_EDGES) return;
    atomicAdd(&counts[inv[recv[e]]], 1);
}

// ---------------- block-wide scan -> row_ptr ----------------
__global__ void k_scan(const int* __restrict__ counts, int* __restrict__ row_ptr)
{
    __shared__ int ps[1024];
    const int t = threadIdx.x;
    int base = t * 10;
    int loc[10];
    int sum = 0;
    #pragma unroll
    for (int j = 0; j < 10; ++j) {
        int idx = base + j;
        int c = (idx < N_NODES) ? counts[idx] : 0;
        loc[j] = c; sum += c;
    }
    ps[t] = sum;
    __syncthreads();
    for (int off = 1; off < 1024; off <<= 1) {
        int v = (t >= off) ? ps[t-off] : 0;
        __syncthreads();
        ps[t] += v;
        __syncthreads();
    }
    int ex = ps[t] - sum;
    #pragma unroll
    for (int j = 0; j < 10; ++j) {
        int idx = base + j;
        if (idx < N_NODES) row_ptr[idx] = ex;
        ex += loc[j];
    }
    if (t == 1023) row_ptr[N_NODES] = ex;
}

// ---------------- fill CSR edge list (sorted ids) ----------------
__global__ void k_fill(const int* __restrict__ recv, const int* __restrict__ inv,
                       const int* __restrict__ row_ptr,
                       int* __restrict__ cursor, int* __restrict__ elist)
{
    int e = blockIdx.x * 256 + threadIdx.x;
    if (e >= N_EDGES) return;
    int r = inv[recv[e]];
    int pos = atomicAdd(&cursor[r], 1);
    elist[row_ptr[r] + pos] = e;
}

// ---------------- position-order edge precompute (snd_pos = PADDED row of sender) ----------------
__global__ void k_edge_pre(const int* __restrict__ elist, const int* __restrict__ senders,
                           const int* __restrict__ inv, const int* __restrict__ pn,
                           const float* __restrict__ vec,
                           float* __restrict__ sh_pos, float* __restrict__ basis_pos,
                           int* __restrict__ snd_pos)
{
    int p = blockIdx.x * 256 + threadIdx.x;
    if (p >= N_EDGES) return;
    const int e = elist[p];
    snd_pos[p] = pn[inv[senders[e]]];
    float x = vec[e*3+0], y = vec[e*3+1], z = vec[e*3+2];
    float r = sqrtf(x*x + y*y + z*z);
    r = fmaxf(r, 1e-9f);
    float invr = 1.f / r;
    x *= invr; y *= invr; z *= invr;
    const float s3=1.7320508075688772f, s5=2.23606797749979f, s7=2.6457513110645907f,
                s15=3.872983346207417f, s42=6.480740698407860f, s70=8.366600265340756f,
                s105=10.246950765959598f;
    float* S = sh_pos + (size_t)p*16;
    S[0]=1.f; S[1]=s3*x; S[2]=s3*y; S[3]=s3*z;
    S[4]=s15*x*y; S[5]=s15*y*z; S[6]=0.5f*s5*(3.f*z*z-1.f); S[7]=s15*x*z;
    S[8]=0.5f*s15*(x*x-y*y);
    S[9]=0.25f*s70*y*(3.f*x*x-y*y); S[10]=s105*x*y*z; S[11]=0.25f*s42*y*(5.f*z*z-1.f);
    S[12]=0.5f*s7*(5.f*z*z*z-3.f*z); S[13]=0.25f*s42*x*(5.f*z*z-1.f);
    S[14]=0.5f*s105*z*(x*x-y*y); S[15]=0.25f*s70*x*(x*x-3.f*y*y);
    float rc = fminf(r, 5.0f);
    float cut = 0.5f * (cosf(PI_F * rc * 0.2f) + 1.f);
    float pref = sqrtf(0.4f) * cut / r;
    float* B = basis_pos + (size_t)p*8;
    #pragma unroll
    for (int k = 1; k <= 8; ++k) B[k-1] = pref * sinf(PI_F * 0.2f * (float)k * r);
}

// ---------------- init featsB plane 0 = emb (bf16, padded rows) ----------------
__global__ void k_init_f0(const int* __restrict__ specS, const int* __restrict__ pn,
                          const float* __restrict__ embW, ushort_t* __restrict__ featsB)
{
    int tid = blockIdx.x * 256 + threadIdx.x;
    if (tid >= N_NODES * F) return;
    int n = tid >> 7, f = tid & 127;
    featsB[(size_t)pn[n]*128 + f] = f2bf(embW[specS[n]*F + f]);
}

// ---------------- convert + transpose lin/sc weights to bf16: WB[mat][f_out][f_in] ----------------
__global__ void k_conv_w(const float* __restrict__ linW, const float* __restrict__ scW,
                         ushort_t* __restrict__ WBlin, ushort_t* __restrict__ WBsc)
{
    int tid = blockIdx.x * 256 + threadIdx.x;
    const int TOT = 80 * 16384;   // 2 layers x 10 spec x 4 l matrices of 128x128
    if (tid >= 2*TOT) return;
    const float* src; ushort_t* dst; int rel;
    if (tid < TOT) { src = linW; dst = WBlin; rel = tid; }
    else           { src = scW;  dst = WBsc;  rel = tid - TOT; }
    int mat = rel >> 14;
    int r = rel & 16383;
    int f = r >> 7, f2 = r & 127;
    dst[(size_t)mat*16384 + f*128 + f2] = f2bf(src[(size_t)mat*16384 + f2*128 + f]);
}

// ---------------- convert + transpose radial W2 to bf16: W2T[layer][n=512][k=64] ----------------
__global__ void k_conv_w2(const float* __restrict__ rW2, ushort_t* __restrict__ W2T)
{
    int tid = blockIdx.x * 256 + threadIdx.x;
    if (tid >= 2*512*64) return;
    int l = tid >> 15; int r = tid & 32767; int n = r >> 6; int k = r & 63;
    W2T[tid] = f2bf(rW2[(size_t)l*HR*512 + (size_t)k*512 + n]);
}

// ---------------- fused radial(MFMA) + per-node edge aggregation -> aggB[m][row][f] (bf16) ----------------
// block = 1 sorted node, 256 threads: f = t&127, mh = t>>7
__global__ __launch_bounds__(256) void k_edge(
    const int layer,
    const int* __restrict__ row_ptr,
    const int* __restrict__ snd_pos,
    const int* __restrict__ pn,
    const float* __restrict__ sh_pos,
    const float* __restrict__ basis_pos,
    const float* __restrict__ rW1,
    const float* __restrict__ rb1,
    const ushort_t* __restrict__ W2Tl,    // layer-resolved [512][64] bf16
    const ushort_t* __restrict__ fB0,     // featsB plane 0 = scal (bf16, padded rows)
    ushort_t* __restrict__ aggB)
{
    __shared__ float W1s[NB*HR];
    __shared__ float b1s[HR];
    __shared__ ushort_t hB[GEDGE][72];    // bf16 h, 72-stride for bank spread (2.3 KB)
    __shared__ float rwS[GEDGE*RWP];      // 33 KB

    const int t = threadIdx.x;
    const int n = blockIdx.x;
    const int f = t & 127;
    const int mh = t >> 7;
    const int wv = t >> 6;      // wave id 0..3
    const int lane = t & 63;
    const int j64 = lane;
    const int r16 = lane & 15;
    const int quad = lane >> 4;

    W1s[t] = rW1[layer*NB*HR + t];
    W1s[256 + t] = rW1[layer*NB*HR + 256 + t];
    if (t < HR) b1s[t] = rb1[layer*HR + t];

    const float4* sh4 = (const float4*)sh_pos;

    float acc[8] = {0,0,0,0,0,0,0,0};
    const int istart = row_ptr[n], iend = row_ptr[n+1];
    __syncthreads();

    for (int g0 = istart; g0 < iend; g0 += GEDGE) {
        const int gcnt = min(GEDGE, iend - g0);

        // ---- phase A: h (bf16) for edges of this group; wave wv covers e = wv, wv+4, ...
        #pragma unroll
        for (int q = 0; q < 4; ++q) {
            int e = (t >> 6) + q*4;
            float a = b1s[j64];
            if (e < gcnt) {
                const float4* B4 = (const float4*)(basis_pos + (size_t)(g0 + e)*8);
                float4 x0 = B4[0], x1 = B4[1];
                a = fmaf(x0.x, W1s[0*HR + j64], a);
                a = fmaf(x0.y, W1s[1*HR + j64], a);
                a = fmaf(x0.z, W1s[2*HR + j64], a);
                a = fmaf(x0.w, W1s[3*HR + j64], a);
                a = fmaf(x1.x, W1s[4*HR + j64], a);
                a = fmaf(x1.y, W1s[5*HR + j64], a);
                a = fmaf(x1.z, W1s[6*HR + j64], a);
                a = fmaf(x1.w, W1s[7*HR + j64], a);
            }
            hB[e][j64] = f2bf(a / (1.f + expf(-a)));
        }
        __syncthreads();

        // ---- phase B (MFMA): rw[16 edges][512 cols] = h(16x64) @ W2(64x512)
        {
            short8 a0 = *(const short8*)&hB[r16][quad*8];
            short8 a1 = *(const short8*)&hB[r16][32 + quad*8];
            #pragma unroll
            for (int nt = 0; nt < 8; ++nt) {
                const int col = wv*128 + nt*16 + r16;
                short8 b0 = *(const short8*)(W2Tl + (size_t)col*64 + quad*8);
                short8 b1 = *(const short8*)(W2Tl + (size_t)col*64 + 32 + quad*8);
                f32x4 c = (f32x4){0.f, 0.f, 0.f, 0.f};
                c = __builtin_amdgcn_mfma_f32_16x16x32_bf16(a0, b0, c, 0, 0, 0);
                c = __builtin_amdgcn_mfma_f32_16x16x32_bf16(a1, b1, c, 0, 0, 0);
                #pragma unroll
                for (int r = 0; r < 4; ++r)
                    rwS[(quad*4 + r)*RWP + col] = c[r];
            }
        }
        __syncthreads();

        // ---- phase C: accumulate messages
        #pragma unroll
        for (int e = 0; e < GEDGE; ++e) {
            if (e < gcnt) {
                const int ii = g0 + e;
                const int snd = snd_pos[ii];                 // padded row of sender
                const float sf = bfu(fB0[(size_t)snd*128 + f]);
                const float4 rwv = *(const float4*)(rwS + e*RWP + 4*f);
                const float4 shA = sh4[(size_t)ii*4 + mh*2 + 0];
                const float4 shB = sh4[(size_t)ii*4 + mh*2 + 1];
                if (mh == 0) {   // m=0..7, l=[0,1,1,1,2,2,2,2]
                    const float a0 = sf*rwv.x, a1 = sf*rwv.y, a2 = sf*rwv.z;
                    acc[0] = fmaf(a0, shA.x, acc[0]);
                    acc[1] = fmaf(a1, shA.y, acc[1]);
                    acc[2] = fmaf(a1, shA.z, acc[2]);
                    acc[3] = fmaf(a1, shA.w, acc[3]);
                    acc[4] = fmaf(a2, shB.x, acc[4]);
                    acc[5] = fmaf(a2, shB.y, acc[5]);
                    acc[6] = fmaf(a2, shB.z, acc[6]);
                    acc[7] = fmaf(a2, shB.w, acc[7]);
                } else {         // m=8..15, l=[2,3,3,3,3,3,3,3]
                    const float a2 = sf*rwv.z, a3 = sf*rwv.w;
                    acc[0] = fmaf(a2, shA.x, acc[0]);
                    acc[1] = fmaf(a3, shA.y, acc[1]);
                    acc[2] = fmaf(a3, shA.z, acc[2]);
                    acc[3] = fmaf(a3, shA.w, acc[3]);
                    acc[4] = fmaf(a3, shB.x, acc[4]);
                    acc[5] = fmaf(a3, shB.y, acc[5]);
                    acc[6] = fmaf(a3, shB.z, acc[6]);
                    acc[7] = fmaf(a3, shB.w, acc[7]);
                }
            }
        }
        __syncthreads();  // protect rwS/hB before next group
    }

    // write aggB[m][row][f] bf16, m-major planes
    const int row = pn[n];
    #pragma unroll
    for (int j = 0; j < 8; ++j) {
        const int m = mh*8 + j;
        aggB[((size_t)m*NPAD + row)*128 + f] = f2bf(acc[j]);
    }
}

// ---------------- bf16 MFMA grouped GEMM: outG[m][rows][f] (+=) A[m][rows][f2] x W[spec][l][f][f2]^T ----------------
template<int ACC>
__global__ __launch_bounds__(256) void k_gemm(
    const ushort_t* __restrict__ A,     // [16][NPAD][128] bf16
    const ushort_t* __restrict__ WB,    // [NSPEC][4][128][128] bf16 (layer-resolved, transposed)
    const int* __restrict__ tile_spec,
    float* __restrict__ outG)           // [16][NPAD][128] f32
{
    const int tile = blockIdx.x;
    const int m = blockIdx.y;
    const int spec = tile_spec[tile];
    if (spec < 0) return;
    const int l = (m == 0) ? 0 : (m < 4) ? 1 : (m < 9) ? 2 : 3;
    const int t = threadIdx.x;
    const int lane = t & 63;
    const int wv = t >> 6;
    const int r16 = lane & 15;
    const int quad = lane >> 4;

    const ushort_t* Ap = A + ((size_t)m*NPAD + (size_t)tile*16)*128;
    const ushort_t* Wp = WB + ((size_t)(spec*4 + l))*128*128;

    short8 a[4];
    #pragma unroll
    for (int c = 0; c < 4; ++c)
        a[c] = *(const short8*)(Ap + (size_t)r16*128 + c*32 + quad*8);

    #pragma unroll
    for (int nt = 0; nt < 2; ++nt) {
        const int fc = wv*32 + nt*16 + r16;
        f32x4 acc;
        if (ACC) {
            #pragma unroll
            for (int r = 0; r < 4; ++r)
                acc[r] = outG[((size_t)m*NPAD + tile*16 + quad*4 + r)*128 + fc];
        } else {
            acc = (f32x4){0.f, 0.f, 0.f, 0.f};
        }
        #pragma unroll
        for (int c = 0; c < 4; ++c) {
            short8 b = *(const short8*)(Wp + (size_t)fc*128 + c*32 + quad*8);
            acc = __builtin_amdgcn_mfma_f32_16x16x32_bf16(a[c], b, acc, 0, 0, 0);
        }
        #pragma unroll
        for (int r = 0; r < 4; ++r)
            outG[((size_t)m*NPAD + tile*16 + quad*4 + r)*128 + fc] = acc[r];
    }
}

// ---------------- EPS + poly gate in-place on outG (layer 1 only; layer 0 fused in epi0) ----------------
__global__ void k_poly(const int layer, const int* __restrict__ specS,
                       const int* __restrict__ pn, const float* __restrict__ prodc,
                       float* __restrict__ outG)
{
    int tid = blockIdx.x * 256 + threadIdx.x;
    if (tid >= N_NODES * F) return;
    int n = tid >> 7, f = tid & 127;
    int row = pn[n];
    const float* pc = prodc + ((size_t)layer*NSPEC + specS[n])*3*F;
    float sg = outG[(size_t)row*128 + f] * 0.5f;   // EPS applied to m=0
    float poly = pc[f] + pc[F+f]*sg + pc[2*F+f]*sg*sg;
    float g = 0.5f * poly;                          // EPS * poly for all m
    #pragma unroll
    for (int m = 0; m < 16; ++m) {
        size_t idx = ((size_t)m*NPAD + row)*128 + f;
        outG[idx] *= g;
    }
}

// ---------------- layer-0 epilogue: poly + feats write (bf16) + readout0 ----------------
__global__ __launch_bounds__(256) void k_epi0(
    const int* __restrict__ specS, const int* __restrict__ pn, const int* __restrict__ perm,
    const float* __restrict__ outG, const float* __restrict__ prodc,
    const float* __restrict__ ro0,
    ushort_t* __restrict__ featsB, float* __restrict__ out)
{
    __shared__ float pS[128];
    __shared__ float redS[128];
    const int t = threadIdx.x, n = blockIdx.x;
    const int f = t & 127, mh = t >> 7;
    const int row = pn[n];
    if (mh == 0) {
        const float* pc = prodc + (size_t)specS[n]*3*F;   // layer 0
        float sg = outG[(size_t)row*128 + f] * 0.5f;
        pS[f] = 0.5f * (pc[f] + pc[F+f]*sg + pc[2*F+f]*sg*sg);
    }
    __syncthreads();
    const float g = pS[f];
    float v0 = 0.f;
    #pragma unroll
    for (int j = 0; j < 8; ++j) {
        const int m = mh*8 + j;
        const size_t idx = ((size_t)m*NPAD + row)*128 + f;
        float v = outG[idx] * g;
        featsB[idx] = f2bf(v);
        if (m == 0) v0 = v;
    }
    if (mh == 0) redS[f] = v0 * ro0[f];
    __syncthreads();
    for (int off = 64; off > 0; off >>= 1) {
        if (t < off) redS[t] += redS[t + off];
        __syncthreads();
    }
    if (t == 0) out[(size_t)perm[n]*2 + 0] = redS[0];
}

// ---------------- layer-1 epilogue: readout1 (silu MLP) ----------------
__global__ __launch_bounds__(256) void k_epi1(
    const int* __restrict__ pn, const int* __restrict__ perm,
    const float* __restrict__ outG,
    const float* __restrict__ ro1W1, const float* __restrict__ ro1W2,
    float* __restrict__ out)
{
    __shared__ float sS[128];
    __shared__ float yS[16];
    const int t = threadIdx.x, n = blockIdx.x;
    const int row = pn[n];
    if (t < 128) sS[t] = outG[(size_t)row*128 + t];
    __syncthreads();
    if (t < 16) {
        float a = 0.f;
        for (int g = 0; g < F; ++g) a = fmaf(sS[g], ro1W1[g*16 + t], a);
        a = silu_f(a);
        yS[t] = a * ro1W2[t];
    }
    __syncthreads();
    if (t == 0) {
        float s = 0.f;
        #pragma unroll
        for (int j = 0; j < 16; ++j) s += yS[j];
        out[(size_t)perm[n]*2 + 1] = s;
    }
}

extern "C" void kernel_launch(void* const* d_in, const int* in_sizes, int n_in,
                              void* d_out, int out_size, void* d_ws, size_t ws_size,
                              hipStream_t stream)
{
    (void)in_sizes; (void)n_in; (void)out_size; (void)ws_size;
    const float* vectors   = (const float*)d_in[0];
    const int*   spec      = (const int*)d_in[1];
    const int*   senders   = (const int*)d_in[2];
    const int*   receivers = (const int*)d_in[3];
    const float* embW      = (const float*)d_in[4];
    const float* rW1       = (const float*)d_in[5];
    const float* rb1       = (const float*)d_in[6];
    const float* rW2       = (const float*)d_in[7];
    const float* linW      = (const float*)d_in[8];
    const float* prodc     = (const float*)d_in[9];
    const float* scW       = (const float*)d_in[10];
    const float* ro0       = (const float*)d_in[11];
    const float* ro1W1     = (const float*)d_in[12];
    const float* ro1W2     = (const float*)d_in[13];
    float* out = (float*)d_out;

    char* ws = (char*)d_ws;
    float*    outG      = (float*)ws;    ws += sizeof(float)*(size_t)16*NPAD*128;    // 83.2 MB
    float*    sh_pos    = (float*)ws;    ws += sizeof(float)*(size_t)N_EDGES*16;     // 10.24
    float*    basis_pos = (float*)ws;    ws += sizeof(float)*(size_t)N_EDGES*8;      // 5.12
    ushort_t* featsB    = (ushort_t*)ws; ws += sizeof(ushort_t)*(size_t)16*NPAD*128; // 41.6
    ushort_t* aggB      = (ushort_t*)ws; ws += sizeof(ushort_t)*(size_t)16*NPAD*128; // 41.6
    ushort_t* WBlin     = (ushort_t*)ws; ws += sizeof(ushort_t)*(size_t)80*16384;    // 2.62
    ushort_t* WBsc      = (ushort_t*)ws; ws += sizeof(ushort_t)*(size_t)80*16384;    // 2.62
    ushort_t* W2T       = (ushort_t*)ws; ws += sizeof(ushort_t)*(size_t)2*512*64;    // 0.13
    int* snd_pos   = (int*)ws; ws += sizeof(int)*N_EDGES;
    int* row_ptr   = (int*)ws; ws += sizeof(int)*(N_NODES+1);
    // zeroed region: counts, cursor, scnt, scur (contiguous)
    int* counts    = (int*)ws; ws += sizeof(int)*N_NODES;
    int* cursor    = (int*)ws; ws += sizeof(int)*N_NODES;
    int* scnt      = (int*)ws; ws += sizeof(int)*16;
    int* scur      = (int*)ws; ws += sizeof(int)*16;
    int* sptr      = (int*)ws; ws += sizeof(int)*16;
    int* psptr     = (int*)ws; ws += sizeof(int)*16;
    int* perm      = (int*)ws; ws += sizeof(int)*N_NODES;
    int* inv       = (int*)ws; ws += sizeof(int)*N_NODES;
    int* specS     = (int*)ws; ws += sizeof(int)*N_NODES;
    int* pn        = (int*)ws; ws += sizeof(int)*N_NODES;
    int* tile_spec = (int*)ws; ws += sizeof(int)*NT_MAX;
    int* elist     = (int*)ws; ws += sizeof(int)*N_EDGES;

    hipMemsetAsync(counts, 0, sizeof(int)*(2*N_NODES + 32), stream);

    const int EB  = (N_EDGES + 255) / 256;
    const int NBK = (N_NODES + 255) / 256;

    k_scnt<<<NBK, 256, 0, stream>>>(spec, scnt);
    k_sscan<<<1, 64, 0, stream>>>(scnt, sptr, psptr, tile_spec);
    k_sfill<<<NBK, 256, 0, stream>>>(spec, sptr, psptr, scur, perm, inv, specS, pn);
    k_count<<<EB, 256, 0, stream>>>(receivers, inv, counts);
    k_scan<<<1, 1024, 0, stream>>>(counts, row_ptr);
    k_fill<<<EB, 256, 0, stream>>>(receivers, inv, row_ptr, cursor, elist);
    k_edge_pre<<<EB, 256, 0, stream>>>(elist, senders, inv, pn, vectors, sh_pos, basis_pos, snd_pos);
    k_init_f0<<<(N_NODES*F + 255)/256, 256, 0, stream>>>(specS, pn, embW, featsB);
    k_conv_w<<<(2*80*16384 + 255)/256, 256, 0, stream>>>(linW, scW, WBlin, WBsc);
    k_conv_w2<<<(2*512*64 + 255)/256, 256, 0, stream>>>(rW2, W2T);

    const size_t WL = (size_t)NSPEC*4*128*128;   // per-layer weight stride (bf16 elems)
    dim3 ggrid(NT_MAX, 16);

    // ---- layer 0 ----
    k_edge<<<N_NODES, 256, 0, stream>>>(0, row_ptr, snd_pos, pn, sh_pos, basis_pos,
        rW1, rb1, W2T, featsB, aggB);
    k_gemm<0><<<ggrid, 256, 0, stream>>>(aggB, WBlin + 0*WL, tile_spec, outG);
    k_epi0<<<N_NODES, 256, 0, stream>>>(specS, pn, perm, outG, prodc, ro0, featsB, out);

    // ---- layer 1 ----
    k_edge<<<N_NODES, 256, 0, stream>>>(1, row_ptr, snd_pos, pn, sh_pos, basis_pos,
        rW1, rb1, W2T + 512*64, featsB, aggB);
    k_gemm<0><<<ggrid, 256, 0, stream>>>(aggB, WBlin + 1*WL, tile_spec, outG);
    k_poly<<<(N_NODES*F + 255)/256, 256, 0, stream>>>(1, specS, pn, prodc, outG);
    k_gemm<1><<<ggrid, 256, 0, stream>>>(featsB, WBsc + 1*WL, tile_spec, outG);
    k_epi1<<<N_NODES, 256, 0, stream>>>(pn, perm, outG, ro1W1, ro1W2, out);
}

// Round 12
// 806.690 us; speedup vs baseline: 10.5732x; 1.0203x over previous
//
#include <hip/hip_runtime.h>
#include <math.h>
#include <stdint.h>

#define N_NODES 10000
#define N_EDGES 160000
#define F 128
#define NB 8
#define HR 64
#define NSPEC 10
#define PI_F 3.14159265358979323846f
#define GEDGE 16
#define NPAD 10160
#define NT_MAX 635
#define RWP 524   // rwB row stride (bf16 halfwords): 512 + 12 pad

typedef unsigned short ushort_t;
typedef __attribute__((ext_vector_type(8))) short short8;   // 8 bf16 = 4 VGPRs
typedef __attribute__((ext_vector_type(4))) float f32x4;    // 4 fp32 acc

__device__ __forceinline__ float silu_f(float x){ return x / (1.f + expf(-x)); }
__device__ __forceinline__ float bfu(ushort_t u) {
    union { unsigned int i; float f; } v; v.i = ((unsigned int)u) << 16; return v.f;
}
__device__ __forceinline__ float bflo(unsigned int w){ return bfu((ushort_t)(w & 0xffffu)); }
__device__ __forceinline__ float bfhi(unsigned int w){ return bfu((ushort_t)(w >> 16)); }
__device__ __forceinline__ ushort_t f2bf(float f) {
    union { float f; unsigned int i; } v; v.f = f;
    unsigned int x = v.i;
    unsigned int r = (x + 0x7fffu + ((x >> 16) & 1u)) >> 16;
    return (ushort_t)r;
}

// ---------------- species counting sort ----------------
__global__ void k_scnt(const int* __restrict__ spec, int* __restrict__ scnt)
{
    int n = blockIdx.x * 256 + threadIdx.x;
    if (n < N_NODES) atomicAdd(&scnt[spec[n]], 1);
}

__global__ void k_sscan(const int* __restrict__ scnt, int* __restrict__ sptr,
                        int* __restrict__ psptr, int* __restrict__ tile_spec)
{
    if (threadIdx.x == 0) {
        int acc = 0, pacc = 0;
        for (int s = 0; s < NSPEC; ++s) {
            sptr[s] = acc; psptr[s] = pacc;
            acc += scnt[s];
            pacc += ((scnt[s] + 15) >> 4) << 4;
        }
        sptr[NSPEC] = acc; psptr[NSPEC] = pacc;
        for (int tt = 0; tt < NT_MAX; ++tt) tile_spec[tt] = -1;
        for (int s = 0; s < NSPEC; ++s) {
            int t0 = psptr[s] >> 4;
            int t1 = t0 + ((scnt[s] + 15) >> 4);
            for (int tt = t0; tt < t1; ++tt) tile_spec[tt] = s;
        }
    }
}

__global__ void k_sfill(const int* __restrict__ spec, const int* __restrict__ sptr,
                        const int* __restrict__ psptr,
                        int* __restrict__ scur, int* __restrict__ perm,
                        int* __restrict__ inv, int* __restrict__ specS,
                        int* __restrict__ pn)
{
    int n = blockIdx.x * 256 + threadIdx.x;
    if (n >= N_NODES) return;
    int s = spec[n];
    int pos = sptr[s] + atomicAdd(&scur[s], 1);
    perm[pos] = n; inv[n] = pos; specS[pos] = s;
    pn[pos] = psptr[s] + (pos - sptr[s]);
}

// ---------------- receiver histogram (sorted ids) ----------------
__global__ void k_count(const int* __restrict__ recv, const int* __restrict__ inv,
                        int* __restrict__ counts)
{
    int e = blockIdx.x * 256 + threadIdx.x;
    if (e >= N_EDGES) return;
    atomicAdd(&counts[inv[recv[e]]], 1);
}

// ---------------- block-wide scan -> row_ptr ----------------
__global__ void k_scan(const int* __restrict__ counts, int* __restrict__ row_ptr)
{
    __shared__ int ps[1024];
    const int t = threadIdx.x;
    int base = t * 10;
    int loc[10];
    int sum = 0;
    #pragma unroll
    for (int j = 0; j < 10; ++j) {
        int idx = base + j;
        int c = (idx < N_NODES) ? counts[idx] : 0;
        loc[j] = c; sum += c;
    }
    ps[t] = sum;
    __syncthreads();
    for (int off = 1; off < 1024; off <<= 1) {
        int v = (t >= off) ? ps[t-off] : 0;
        __syncthreads();
        ps[t] += v;
        __syncthreads();
    }
    int ex = ps[t] - sum;
    #pragma unroll
    for (int j = 0; j < 10; ++j) {
        int idx = base + j;
        if (idx < N_NODES) row_ptr[idx] = ex;
        ex += loc[j];
    }
    if (t == 1023) row_ptr[N_NODES] = ex;
}

// ---------------- fill CSR edge list (sorted ids) ----------------
__global__ void k_fill(const int* __restrict__ recv, const int* __restrict__ inv,
                       const int* __restrict__ row_ptr,
                       int* __restrict__ cursor, int* __restrict__ elist)
{
    int e = blockIdx.x * 256 + threadIdx.x;
    if (e >= N_EDGES) return;
    int r = inv[recv[e]];
    int pos = atomicAdd(&cursor[r], 1);
    elist[row_ptr[r] + pos] = e;
}

// ---------------- position-order edge precompute (snd_pos = PADDED row of sender) ----------------
__global__ void k_edge_pre(const int* __restrict__ elist, const int* __restrict__ senders,
                           const int* __restrict__ inv, const int* __restrict__ pn,
                           const float* __restrict__ vec,
                           float* __restrict__ sh_pos, float* __restrict__ basis_pos,
                           int* __restrict__ snd_pos)
{
    int p = blockIdx.x * 256 + threadIdx.x;
    if (p >= N_EDGES) return;
    const int e = elist[p];
    snd_pos[p] = pn[inv[senders[e]]];
    float x = vec[e*3+0], y = vec[e*3+1], z = vec[e*3+2];
    float r = sqrtf(x*x + y*y + z*z);
    r = fmaxf(r, 1e-9f);
    float invr = 1.f / r;
    x *= invr; y *= invr; z *= invr;
    const float s3=1.7320508075688772f, s5=2.23606797749979f, s7=2.6457513110645907f,
                s15=3.872983346207417f, s42=6.480740698407860f, s70=8.366600265340756f,
                s105=10.246950765959598f;
    float* S = sh_pos + (size_t)p*16;
    S[0]=1.f; S[1]=s3*x; S[2]=s3*y; S[3]=s3*z;
    S[4]=s15*x*y; S[5]=s15*y*z; S[6]=0.5f*s5*(3.f*z*z-1.f); S[7]=s15*x*z;
    S[8]=0.5f*s15*(x*x-y*y);
    S[9]=0.25f*s70*y*(3.f*x*x-y*y); S[10]=s105*x*y*z; S[11]=0.25f*s42*y*(5.f*z*z-1.f);
    S[12]=0.5f*s7*(5.f*z*z*z-3.f*z); S[13]=0.25f*s42*x*(5.f*z*z-1.f);
    S[14]=0.5f*s105*z*(x*x-y*y); S[15]=0.25f*s70*x*(x*x-3.f*y*y);
    float rc = fminf(r, 5.0f);
    float cut = 0.5f * (cosf(PI_F * rc * 0.2f) + 1.f);
    float pref = sqrtf(0.4f) * cut / r;
    float* B = basis_pos + (size_t)p*8;
    #pragma unroll
    for (int k = 1; k <= 8; ++k) B[k-1] = pref * sinf(PI_F * 0.2f * (float)k * r);
}

// ---------------- init featsB plane 0 = emb (bf16, padded rows) ----------------
__global__ void k_init_f0(const int* __restrict__ specS, const int* __restrict__ pn,
                          const float* __restrict__ embW, ushort_t* __restrict__ featsB)
{
    int tid = blockIdx.x * 256 + threadIdx.x;
    if (tid >= N_NODES * F) return;
    int n = tid >> 7, f = tid & 127;
    featsB[(size_t)pn[n]*128 + f] = f2bf(embW[specS[n]*F + f]);
}

// ---------------- convert + transpose lin/sc weights to bf16: WB[mat][f_out][f_in] ----------------
__global__ void k_conv_w(const float* __restrict__ linW, const float* __restrict__ scW,
                         ushort_t* __restrict__ WBlin, ushort_t* __restrict__ WBsc)
{
    int tid = blockIdx.x * 256 + threadIdx.x;
    const int TOT = 80 * 16384;   // 2 layers x 10 spec x 4 l matrices of 128x128
    if (tid >= 2*TOT) return;
    const float* src; ushort_t* dst; int rel;
    if (tid < TOT) { src = linW; dst = WBlin; rel = tid; }
    else           { src = scW;  dst = WBsc;  rel = tid - TOT; }
    int mat = rel >> 14;
    int r = rel & 16383;
    int f = r >> 7, f2 = r & 127;
    dst[(size_t)mat*16384 + f*128 + f2] = f2bf(src[(size_t)mat*16384 + f2*128 + f]);
}

// ---------------- convert + transpose radial W2 to bf16: W2T[layer][n=512][k=64] ----------------
__global__ void k_conv_w2(const float* __restrict__ rW2, ushort_t* __restrict__ W2T)
{
    int tid = blockIdx.x * 256 + threadIdx.x;
    if (tid >= 2*512*64) return;
    int l = tid >> 15; int r = tid & 32767; int n = r >> 6; int k = r & 63;
    W2T[tid] = f2bf(rW2[(size_t)l*HR*512 + (size_t)k*512 + n]);
}

// ---------------- fused radial(MFMA) + per-node edge aggregation -> aggB[m][row][f] (bf16) ----------------
// block = 1 sorted node, 256 threads: f = t&127, mh = t>>7
// LDS ~26 KB -> 6 blocks/CU; 2 barriers per 16-edge group (hB/shS double-buffered)
__global__ __launch_bounds__(256) void k_edge(
    const int layer,
    const int* __restrict__ row_ptr,
    const int* __restrict__ snd_pos,
    const int* __restrict__ pn,
    const float* __restrict__ sh_pos,
    const float* __restrict__ basis_pos,
    const float* __restrict__ rW1,
    const float* __restrict__ rb1,
    const ushort_t* __restrict__ W2Tl,    // layer-resolved [512][64] bf16
    const ushort_t* __restrict__ fB0,     // featsB plane 0 = scal (bf16, padded rows)
    ushort_t* __restrict__ aggB)
{
    __shared__ float W1s[NB*HR];            // 2 KB
    __shared__ float b1s[HR];               // 256 B
    __shared__ ushort_t hB[2][GEDGE][72];   // 4.6 KB (dbuf bf16 h)
    __shared__ ushort_t rwB[GEDGE][RWP];    // 16.8 KB (bf16 rw)
    __shared__ float shS[2][GEDGE][16];     // 2 KB (dbuf staged sh)
    __shared__ int  sndS[2][GEDGE];         // 128 B

    const int t = threadIdx.x;
    const int n = blockIdx.x;
    const int f = t & 127;
    const int mh = t >> 7;
    const int wv = t >> 6;      // wave id 0..3
    const int lane = t & 63;
    const int j64 = lane;
    const int r16 = lane & 15;
    const int quad = lane >> 4;

    W1s[t] = rW1[layer*NB*HR + t];
    W1s[256 + t] = rW1[layer*NB*HR + 256 + t];
    if (t < HR) b1s[t] = rb1[layer*HR + t];

    float acc[8] = {0,0,0,0,0,0,0,0};
    const int istart = row_ptr[n], iend = row_ptr[n+1];
    __syncthreads();

    int buf = 0;
    for (int g0 = istart; g0 < iend; g0 += GEDGE, buf ^= 1) {
        const int gcnt = min(GEDGE, iend - g0);

        // ---- stage sh (coalesced 256 floats) + snd ids into dbuf
        {
            const int es = t >> 4, ms = t & 15;
            shS[buf][es][ms] = (es < gcnt) ? sh_pos[(size_t)(g0 + es)*16 + ms] : 0.f;
            if (t < GEDGE) sndS[buf][t] = (t < gcnt) ? snd_pos[g0 + t] : 0;
        }
        // ---- phase A: h (bf16) for edges of this group; wave wv covers e = wv, wv+4, ...
        #pragma unroll
        for (int q = 0; q < 4; ++q) {
            int e = wv + q*4;
            float a = b1s[j64];
            if (e < gcnt) {
                const float4* B4 = (const float4*)(basis_pos + (size_t)(g0 + e)*8);
                float4 x0 = B4[0], x1 = B4[1];
                a = fmaf(x0.x, W1s[0*HR + j64], a);
                a = fmaf(x0.y, W1s[1*HR + j64], a);
                a = fmaf(x0.z, W1s[2*HR + j64], a);
                a = fmaf(x0.w, W1s[3*HR + j64], a);
                a = fmaf(x1.x, W1s[4*HR + j64], a);
                a = fmaf(x1.y, W1s[5*HR + j64], a);
                a = fmaf(x1.z, W1s[6*HR + j64], a);
                a = fmaf(x1.w, W1s[7*HR + j64], a);
            }
            hB[buf][e][j64] = f2bf(a / (1.f + expf(-a)));
        }
        __syncthreads();   // (1) hB/shS/sndS ready; prior phase-C rwB reads complete

        // ---- phase B (MFMA): rw[16 edges][512 cols] = h(16x64) @ W2(64x512) -> bf16 LDS
        {
            short8 a0 = *(const short8*)&hB[buf][r16][quad*8];
            short8 a1 = *(const short8*)&hB[buf][r16][32 + quad*8];
            #pragma unroll
            for (int nt = 0; nt < 8; ++nt) {
                const int col = wv*128 + nt*16 + r16;
                short8 b0 = *(const short8*)(W2Tl + (size_t)col*64 + quad*8);
                short8 b1 = *(const short8*)(W2Tl + (size_t)col*64 + 32 + quad*8);
                f32x4 c = (f32x4){0.f, 0.f, 0.f, 0.f};
                c = __builtin_amdgcn_mfma_f32_16x16x32_bf16(a0, b0, c, 0, 0, 0);
                c = __builtin_amdgcn_mfma_f32_16x16x32_bf16(a1, b1, c, 0, 0, 0);
                #pragma unroll
                for (int r = 0; r < 4; ++r)
                    rwB[quad*4 + r][col] = f2bf(c[r]);
            }
        }
        __syncthreads();   // (2) rwB ready

        // ---- phase C: accumulate messages (LDS-only reads + one global gather)
        #pragma unroll
        for (int e = 0; e < GEDGE; ++e) {
            if (e < gcnt) {
                const int snd = sndS[buf][e];
                const float sf = bfu(fB0[(size_t)snd*128 + f]);
                const uint2 rw2 = *(const uint2*)&rwB[e][4*f];
                const float rl0 = bflo(rw2.x), rl1 = bfhi(rw2.x);
                const float rl2 = bflo(rw2.y), rl3 = bfhi(rw2.y);
                const float4 shA = *(const float4*)&shS[buf][e][mh*8];
                const float4 shB = *(const float4*)&shS[buf][e][mh*8 + 4];
                if (mh == 0) {   // m=0..7, l=[0,1,1,1,2,2,2,2]
                    const float a0 = sf*rl0, a1 = sf*rl1, a2 = sf*rl2;
                    acc[0] = fmaf(a0, shA.x, acc[0]);
                    acc[1] = fmaf(a1, shA.y, acc[1]);
                    acc[2] = fmaf(a1, shA.z, acc[2]);
                    acc[3] = fmaf(a1, shA.w, acc[3]);
                    acc[4] = fmaf(a2, shB.x, acc[4]);
                    acc[5] = fmaf(a2, shB.y, acc[5]);
                    acc[6] = fmaf(a2, shB.z, acc[6]);
                    acc[7] = fmaf(a2, shB.w, acc[7]);
                } else {         // m=8..15, l=[2,3,3,3,3,3,3,3]
                    const float a2 = sf*rl2, a3 = sf*rl3;
                    acc[0] = fmaf(a2, shA.x, acc[0]);
                    acc[1] = fmaf(a3, shA.y, acc[1]);
                    acc[2] = fmaf(a3, shA.z, acc[2]);
                    acc[3] = fmaf(a3, shA.w, acc[3]);
                    acc[4] = fmaf(a3, shB.x, acc[4]);
                    acc[5] = fmaf(a3, shB.y, acc[5]);
                    acc[6] = fmaf(a3, shB.z, acc[6]);
                    acc[7] = fmaf(a3, shB.w, acc[7]);
                }
            }
        }
        // no barrier here: next iteration's barrier (1) orders rwB reuse
    }

    // write aggB[m][row][f] bf16, m-major planes
    const int row = pn[n];
    #pragma unroll
    for (int j = 0; j < 8; ++j) {
        const int m = mh*8 + j;
        aggB[((size_t)m*NPAD + row)*128 + f] = f2bf(acc[j]);
    }
}

// ---------------- bf16 MFMA grouped GEMM: outG[m][rows][f] (+=) A[m][rows][f2] x W[spec][l][f][f2]^T ----------------
template<int ACC>
__global__ __launch_bounds__(256) void k_gemm(
    const ushort_t* __restrict__ A,     // [16][NPAD][128] bf16
    const ushort_t* __restrict__ WB,    // [NSPEC][4][128][128] bf16 (layer-resolved, transposed)
    const int* __restrict__ tile_spec,
    float* __restrict__ outG)           // [16][NPAD][128] f32
{
    const int tile = blockIdx.x;
    const int m = blockIdx.y;
    const int spec = tile_spec[tile];
    if (spec < 0) return;
    const int l = (m == 0) ? 0 : (m < 4) ? 1 : (m < 9) ? 2 : 3;
    const int t = threadIdx.x;
    const int lane = t & 63;
    const int wv = t >> 6;
    const int r16 = lane & 15;
    const int quad = lane >> 4;

    const ushort_t* Ap = A + ((size_t)m*NPAD + (size_t)tile*16)*128;
    const ushort_t* Wp = WB + ((size_t)(spec*4 + l))*128*128;

    short8 a[4];
    #pragma unroll
    for (int c = 0; c < 4; ++c)
        a[c] = *(const short8*)(Ap + (size_t)r16*128 + c*32 + quad*8);

    #pragma unroll
    for (int nt = 0; nt < 2; ++nt) {
        const int fc = wv*32 + nt*16 + r16;
        f32x4 acc;
        if (ACC) {
            #pragma unroll
            for (int r = 0; r < 4; ++r)
                acc[r] = outG[((size_t)m*NPAD + tile*16 + quad*4 + r)*128 + fc];
        } else {
            acc = (f32x4){0.f, 0.f, 0.f, 0.f};
        }
        #pragma unroll
        for (int c = 0; c < 4; ++c) {
            short8 b = *(const short8*)(Wp + (size_t)fc*128 + c*32 + quad*8);
            acc = __builtin_amdgcn_mfma_f32_16x16x32_bf16(a[c], b, acc, 0, 0, 0);
        }
        #pragma unroll
        for (int r = 0; r < 4; ++r)
            outG[((size_t)m*NPAD + tile*16 + quad*4 + r)*128 + fc] = acc[r];
    }
}

// ---------------- EPS + poly gate in-place on outG (layer 1 only; layer 0 fused in epi0) ----------------
__global__ void k_poly(const int layer, const int* __restrict__ specS,
                       const int* __restrict__ pn, const float* __restrict__ prodc,
                       float* __restrict__ outG)
{
    int tid = blockIdx.x * 256 + threadIdx.x;
    if (tid >= N_NODES * F) return;
    int n = tid >> 7, f = tid & 127;
    int row = pn[n];
    const float* pc = prodc + ((size_t)layer*NSPEC + specS[n])*3*F;
    float sg = outG[(size_t)row*128 + f] * 0.5f;   // EPS applied to m=0
    float poly = pc[f] + pc[F+f]*sg + pc[2*F+f]*sg*sg;
    float g = 0.5f * poly;                          // EPS * poly for all m
    #pragma unroll
    for (int m = 0; m < 16; ++m) {
        size_t idx = ((size_t)m*NPAD + row)*128 + f;
        outG[idx] *= g;
    }
}

// ---------------- layer-0 epilogue: poly + feats write (bf16) + readout0 ----------------
__global__ __launch_bounds__(256) void k_epi0(
    const int* __restrict__ specS, const int* __restrict__ pn, const int* __restrict__ perm,
    const float* __restrict__ outG, const float* __restrict__ prodc,
    const float* __restrict__ ro0,
    ushort_t* __restrict__ featsB, float* __restrict__ out)
{
    __shared__ float pS[128];
    __shared__ float redS[128];
    const int t = threadIdx.x, n = blockIdx.x;
    const int f = t & 127, mh = t >> 7;
    const int row = pn[n];
    if (mh == 0) {
        const float* pc = prodc + (size_t)specS[n]*3*F;   // layer 0
        float sg = outG[(size_t)row*128 + f] * 0.5f;
        pS[f] = 0.5f * (pc[f] + pc[F+f]*sg + pc[2*F+f]*sg*sg);
    }
    __syncthreads();
    const float g = pS[f];
    float v0 = 0.f;
    #pragma unroll
    for (int j = 0; j < 8; ++j) {
        const int m = mh*8 + j;
        const size_t idx = ((size_t)m*NPAD + row)*128 + f;
        float v = outG[idx] * g;
        featsB[idx] = f2bf(v);
        if (m == 0) v0 = v;
    }
    if (mh == 0) redS[f] = v0 * ro0[f];
    __syncthreads();
    for (int off = 64; off > 0; off >>= 1) {
        if (t < off) redS[t] += redS[t + off];
        __syncthreads();
    }
    if (t == 0) out[(size_t)perm[n]*2 + 0] = redS[0];
}

// ---------------- layer-1 epilogue: readout1 (silu MLP) ----------------
__global__ __launch_bounds__(256) void k_epi1(
    const int* __restrict__ pn, const int* __restrict__ perm,
    const float* __restrict__ outG,
    const float* __restrict__ ro1W1, const float* __restrict__ ro1W2,
    float* __restrict__ out)
{
    __shared__ float sS[128];
    __shared__ float yS[16];
    const int t = threadIdx.x, n = blockIdx.x;
    const int row = pn[n];
    if (t < 128) sS[t] = outG[(size_t)row*128 + t];
    __syncthreads();
    if (t < 16) {
        float a = 0.f;
        for (int g = 0; g < F; ++g) a = fmaf(sS[g], ro1W1[g*16 + t], a);
        a = silu_f(a);
        yS[t] = a * ro1W2[t];
    }
    __syncthreads();
    if (t == 0) {
        float s = 0.f;
        #pragma unroll
        for (int j = 0; j < 16; ++j) s += yS[j];
        out[(size_t)perm[n]*2 + 1] = s;
    }
}

extern "C" void kernel_launch(void* const* d_in, const int* in_sizes, int n_in,
                              void* d_out, int out_size, void* d_ws, size_t ws_size,
                              hipStream_t stream)
{
    (void)in_sizes; (void)n_in; (void)out_size; (void)ws_size;
    const float* vectors   = (const float*)d_in[0];
    const int*   spec      = (const int*)d_in[1];
    const int*   senders   = (const int*)d_in[2];
    const int*   receivers = (const int*)d_in[3];
    const float* embW      = (const float*)d_in[4];
    const float* rW1       = (const float*)d_in[5];
    const float* rb1       = (const float*)d_in[6];
    const float* rW2       = (const float*)d_in[7];
    const float* linW      = (const float*)d_in[8];
    const float* prodc     = (const float*)d_in[9];
    const float* scW       = (const float*)d_in[10];
    const float* ro0       = (const float*)d_in[11];
    const float* ro1W1     = (const float*)d_in[12];
    const float* ro1W2     = (const float*)d_in[13];
    float* out = (float*)d_out;

    char* ws = (char*)d_ws;
    float*    outG      = (float*)ws;    ws += sizeof(float)*(size_t)16*NPAD*128;    // 83.2 MB
    float*    sh_pos    = (float*)ws;    ws += sizeof(float)*(size_t)N_EDGES*16;     // 10.24
    float*    basis_pos = (float*)ws;    ws += sizeof(float)*(size_t)N_EDGES*8;      // 5.12
    ushort_t* featsB    = (ushort_t*)ws; ws += sizeof(ushort_t)*(size_t)16*NPAD*128; // 41.6
    ushort_t* aggB      = (ushort_t*)ws; ws += sizeof(ushort_t)*(size_t)16*NPAD*128; // 41.6
    ushort_t* WBlin     = (ushort_t*)ws; ws += sizeof(ushort_t)*(size_t)80*16384;    // 2.62
    ushort_t* WBsc      = (ushort_t*)ws; ws += sizeof(ushort_t)*(size_t)80*16384;    // 2.62
    ushort_t* W2T       = (ushort_t*)ws; ws += sizeof(ushort_t)*(size_t)2*512*64;    // 0.13
    int* snd_pos   = (int*)ws; ws += sizeof(int)*N_EDGES;
    int* row_ptr   = (int*)ws; ws += sizeof(int)*(N_NODES+1);
    // zeroed region: counts, cursor, scnt, scur (contiguous)
    int* counts    = (int*)ws; ws += sizeof(int)*N_NODES;
    int* cursor    = (int*)ws; ws += sizeof(int)*N_NODES;
    int* scnt      = (int*)ws; ws += sizeof(int)*16;
    int* scur      = (int*)ws; ws += sizeof(int)*16;
    int* sptr      = (int*)ws; ws += sizeof(int)*16;
    int* psptr     = (int*)ws; ws += sizeof(int)*16;
    int* perm      = (int*)ws; ws += sizeof(int)*N_NODES;
    int* inv       = (int*)ws; ws += sizeof(int)*N_NODES;
    int* specS     = (int*)ws; ws += sizeof(int)*N_NODES;
    int* pn        = (int*)ws; ws += sizeof(int)*N_NODES;
    int* tile_spec = (int*)ws; ws += sizeof(int)*NT_MAX;
    int* elist     = (int*)ws; ws += sizeof(int)*N_EDGES;

    hipMemsetAsync(counts, 0, sizeof(int)*(2*N_NODES + 32), stream);

    const int EB  = (N_EDGES + 255) / 256;
    const int NBK = (N_NODES + 255) / 256;

    k_scnt<<<NBK, 256, 0, stream>>>(spec, scnt);
    k_sscan<<<1, 64, 0, stream>>>(scnt, sptr, psptr, tile_spec);
    k_sfill<<<NBK, 256, 0, stream>>>(spec, sptr, psptr, scur, perm, inv, specS, pn);
    k_count<<<EB, 256, 0, stream>>>(receivers, inv, counts);
    k_scan<<<1, 1024, 0, stream>>>(counts, row_ptr);
    k_fill<<<EB, 256, 0, stream>>>(receivers, inv, row_ptr, cursor, elist);
    k_edge_pre<<<EB, 256, 0, stream>>>(elist, senders, inv, pn, vectors, sh_pos, basis_pos, snd_pos);
    k_init_f0<<<(N_NODES*F + 255)/256, 256, 0, stream>>>(specS, pn, embW, featsB);
    k_conv_w<<<(2*80*16384 + 255)/256, 256, 0, stream>>>(linW, scW, WBlin, WBsc);
    k_conv_w2<<<(2*512*64 + 255)/256, 256, 0, stream>>>(rW2, W2T);

    const size_t WL = (size_t)NSPEC*4*128*128;   // per-layer weight stride (bf16 elems)
    dim3 ggrid(NT_MAX, 16);

    // ---- layer 0 ----
    k_edge<<<N_NODES, 256, 0, stream>>>(0, row_ptr, snd_pos, pn, sh_pos, basis_pos,
        rW1, rb1, W2T, featsB, aggB);
    k_gemm<0><<<ggrid, 256, 0, stream>>>(aggB, WBlin + 0*WL, tile_spec, outG);
    k_epi0<<<N_NODES, 256, 0, stream>>>(specS, pn, perm, outG, prodc, ro0, featsB, out);

    // ---- layer 1 ----
    k_edge<<<N_NODES, 256, 0, stream>>>(1, row_ptr, snd_pos, pn, sh_pos, basis_pos,
        rW1, rb1, W2T + 512*64, featsB, aggB);
    k_gemm<0><<<ggrid, 256, 0, stream>>>(aggB, WBlin + 1*WL, tile_spec, outG);
    k_poly<<<(N_NODES*F + 255)/256, 256, 0, stream>>>(1, specS, pn, prodc, outG);
    k_gemm<1><<<ggrid, 256, 0, stream>>>(featsB, WBsc + 1*WL, tile_spec, outG);
    k_epi1<<<N_NODES, 256, 0, stream>>>(pn, perm, outG, ro1W1, ro1W2, out);
}

// Round 13
// 373.076 us; speedup vs baseline: 22.8621x; 2.1623x over previous
//
#include <hip/hip_runtime.h>
#include <math.h>
#include <stdint.h>

#define N_NODES 10000
#define N_EDGES 160000
#define F 128
#define NB 8
#define HR 64
#define NSPEC 10
#define PI_F 3.14159265358979323846f
#define GEDGE 16
#define NPAD 10160
#define NT_MAX 635

typedef unsigned short ushort_t;
typedef __attribute__((ext_vector_type(8))) short short8;   // 8 bf16 = 4 VGPRs
typedef __attribute__((ext_vector_type(4))) float f32x4;    // 4 fp32 acc

__device__ __forceinline__ float silu_f(float x){ return x / (1.f + expf(-x)); }
__device__ __forceinline__ float bfu(ushort_t u) {
    union { unsigned int i; float f; } v; v.i = ((unsigned int)u) << 16; return v.f;
}
__device__ __forceinline__ ushort_t f2bf(float f) {
    union { float f; unsigned int i; } v; v.f = f;
    unsigned int x = v.i;
    unsigned int r = (x + 0x7fffu + ((x >> 16) & 1u)) >> 16;
    return (ushort_t)r;
}

// ---------------- species counting sort ----------------
__global__ void k_scnt(const int* __restrict__ spec, int* __restrict__ scnt)
{
    int n = blockIdx.x * 256 + threadIdx.x;
    if (n < N_NODES) atomicAdd(&scnt[spec[n]], 1);
}

__global__ void k_sscan(const int* __restrict__ scnt, int* __restrict__ sptr,
                        int* __restrict__ psptr, int* __restrict__ tile_spec)
{
    if (threadIdx.x == 0) {
        int acc = 0, pacc = 0;
        for (int s = 0; s < NSPEC; ++s) {
            sptr[s] = acc; psptr[s] = pacc;
            acc += scnt[s];
            pacc += ((scnt[s] + 15) >> 4) << 4;
        }
        sptr[NSPEC] = acc; psptr[NSPEC] = pacc;
        for (int tt = 0; tt < NT_MAX; ++tt) tile_spec[tt] = -1;
        for (int s = 0; s < NSPEC; ++s) {
            int t0 = psptr[s] >> 4;
            int t1 = t0 + ((scnt[s] + 15) >> 4);
            for (int tt = t0; tt < t1; ++tt) tile_spec[tt] = s;
        }
    }
}

__global__ void k_sfill(const int* __restrict__ spec, const int* __restrict__ sptr,
                        const int* __restrict__ psptr,
                        int* __restrict__ scur, int* __restrict__ perm,
                        int* __restrict__ inv, int* __restrict__ specS,
                        int* __restrict__ pn)
{
    int n = blockIdx.x * 256 + threadIdx.x;
    if (n >= N_NODES) return;
    int s = spec[n];
    int pos = sptr[s] + atomicAdd(&scur[s], 1);
    perm[pos] = n; inv[n] = pos; specS[pos] = s;
    pn[pos] = psptr[s] + (pos - sptr[s]);
}

// ---------------- receiver histogram (sorted ids) ----------------
__global__ void k_count(const int* __restrict__ recv, const int* __restrict__ inv,
                        int* __restrict__ counts)
{
    int e = blockIdx.x * 256 + threadIdx.x;
    if (e >= N_EDGES) return;
    atomicAdd(&counts[inv[recv[e]]], 1);
}

// ---------------- block-wide scan -> row_ptr ----------------
__global__ void k_scan(const int* __restrict__ counts, int* __restrict__ row_ptr)
{
    __shared__ int ps[1024];
    const int t = threadIdx.x;
    int base = t * 10;
    int loc[10];
    int sum = 0;
    #pragma unroll
    for (int j = 0; j < 10; ++j) {
        int idx = base + j;
        int c = (idx < N_NODES) ? counts[idx] : 0;
        loc[j] = c; sum += c;
    }
    ps[t] = sum;
    __syncthreads();
    for (int off = 1; off < 1024; off <<= 1) {
        int v = (t >= off) ? ps[t-off] : 0;
        __syncthreads();
        ps[t] += v;
        __syncthreads();
    }
    int ex = ps[t] - sum;
    #pragma unroll
    for (int j = 0; j < 10; ++j) {
        int idx = base + j;
        if (idx < N_NODES) row_ptr[idx] = ex;
        ex += loc[j];
    }
    if (t == 1023) row_ptr[N_NODES] = ex;
}

// ---------------- fill CSR edge list (sorted ids) ----------------
__global__ void k_fill(const int* __restrict__ recv, const int* __restrict__ inv,
                       const int* __restrict__ row_ptr,
                       int* __restrict__ cursor, int* __restrict__ elist)
{
    int e = blockIdx.x * 256 + threadIdx.x;
    if (e >= N_EDGES) return;
    int r = inv[recv[e]];
    int pos = atomicAdd(&cursor[r], 1);
    elist[row_ptr[r] + pos] = e;
}

// ---------------- position-order edge precompute: basis + sender padded row ----------------
__global__ void k_edge_pre(const int* __restrict__ elist, const int* __restrict__ senders,
                           const int* __restrict__ inv, const int* __restrict__ pn,
                           const float* __restrict__ vec,
                           float* __restrict__ basis_pos, int* __restrict__ snd_pos)
{
    int p = blockIdx.x * 256 + threadIdx.x;
    if (p >= N_EDGES) return;
    const int e = elist[p];
    snd_pos[p] = pn[inv[senders[e]]];
    float x = vec[e*3+0], y = vec[e*3+1], z = vec[e*3+2];
    float r = sqrtf(x*x + y*y + z*z);
    r = fmaxf(r, 1e-9f);
    float rc = fminf(r, 5.0f);
    float cut = 0.5f * (cosf(PI_F * rc * 0.2f) + 1.f);
    float pref = sqrtf(0.4f) * cut / r;
    float* B = basis_pos + (size_t)p*8;
    #pragma unroll
    for (int k = 1; k <= 8; ++k) B[k-1] = pref * sinf(PI_F * 0.2f * (float)k * r);
}

// ---------------- init fB0 = emb (bf16, padded rows) ----------------
__global__ void k_init_f0(const int* __restrict__ specS, const int* __restrict__ pn,
                          const float* __restrict__ embW, ushort_t* __restrict__ fB0)
{
    int tid = blockIdx.x * 256 + threadIdx.x;
    if (tid >= N_NODES * F) return;
    int n = tid >> 7, f = tid & 127;
    fB0[(size_t)pn[n]*128 + f] = f2bf(embW[specS[n]*F + f]);
}

// ---------------- convert l=0 lin/sc weights to bf16 transposed: WB[..][f_out][f_in] ----------------
__global__ void k_conv_w(const float* __restrict__ linW, const float* __restrict__ scW,
                         ushort_t* __restrict__ WBlin0, ushort_t* __restrict__ WBsc0)
{
    int tid = blockIdx.x * 256 + threadIdx.x;
    const int LINTOT = 2*NSPEC*16384;
    if (tid < LINTOT) {
        int mat = tid >> 14;                 // 0..19: layer*10+spec
        int r = tid & 16383;
        int fo = r >> 7, fi = r & 127;
        WBlin0[(size_t)mat*16384 + fo*128 + fi] =
            f2bf(linW[((size_t)mat*4 + 0)*16384 + fi*128 + fo]);
    } else if (tid < LINTOT + NSPEC*16384) {
        int t2 = tid - LINTOT;
        int spec = t2 >> 14;
        int r = t2 & 16383;
        int fo = r >> 7, fi = r & 127;
        WBsc0[(size_t)spec*16384 + fo*128 + fi] =
            f2bf(scW[((size_t)(NSPEC + spec)*4 + 0)*16384 + fi*128 + fo]);   // layer 1
    }
}

// ---------------- radial W2 l=0 columns to bf16: W2T0[layer][f=128][k=64] ----------------
__global__ void k_conv_w2(const float* __restrict__ rW2, ushort_t* __restrict__ W2T0)
{
    int tid = blockIdx.x * 256 + threadIdx.x;
    if (tid >= 2*128*64) return;
    int l = tid >> 13; int r = tid & 8191; int f = r >> 6; int k = r & 63;
    W2T0[tid] = f2bf(rW2[(size_t)l*HR*512 + (size_t)k*512 + 4*f]);
}

// ---------------- fused radial(MFMA) + per-node edge aggregation, m=0 only -> aggB0[row][f] ----------------
// block = 1 sorted node, 256 threads; LDS ~16.3 KB -> 8 blocks/CU
__global__ __launch_bounds__(256) void k_edge(
    const int layer,
    const int* __restrict__ row_ptr,
    const int* __restrict__ snd_pos,
    const int* __restrict__ pn,
    const float* __restrict__ basis_pos,
    const float* __restrict__ rW1,
    const float* __restrict__ rb1,
    const ushort_t* __restrict__ W2T0l,   // layer-resolved [128][64] bf16
    const ushort_t* __restrict__ fB_in,   // scal bf16, padded rows
    ushort_t* __restrict__ aggB0)
{
    __shared__ float W1s[NB*HR];            // 2 KB
    __shared__ float b1s[HR];               // 256 B
    __shared__ ushort_t hB[2][GEDGE][72];   // 4.6 KB dbuf bf16 h
    __shared__ ushort_t rwB[2][GEDGE][136]; // 8.7 KB dbuf bf16 rw (l=0 cols)
    __shared__ int sndS[2][GEDGE];          // 128 B
    __shared__ float accS[F];               // 512 B

    const int t = threadIdx.x;
    const int n = blockIdx.x;
    const int f = t & 127;
    const int mh = t >> 7;
    const int wv = t >> 6;
    const int lane = t & 63;
    const int j64 = lane;
    const int r16 = lane & 15;
    const int quad = lane >> 4;

    W1s[t] = rW1[layer*NB*HR + t];
    W1s[256 + t] = rW1[layer*NB*HR + 256 + t];
    if (t < HR) b1s[t] = rb1[layer*HR + t];

    float acc = 0.f;
    const int istart = row_ptr[n], iend = row_ptr[n+1];
    __syncthreads();

    int buf = 0;
    for (int g0 = istart; g0 < iend; g0 += GEDGE, buf ^= 1) {
        const int gcnt = min(GEDGE, iend - g0);

        if (t < GEDGE) sndS[buf][t] = (t < gcnt) ? snd_pos[g0 + t] : 0;

        // ---- phase A: h (bf16); wave wv covers e = wv, wv+4, wv+8, wv+12
        #pragma unroll
        for (int q = 0; q < 4; ++q) {
            int e = wv + q*4;
            float a = b1s[j64];
            if (e < gcnt) {
                const float4* B4 = (const float4*)(basis_pos + (size_t)(g0 + e)*8);
                float4 x0 = B4[0], x1 = B4[1];
                a = fmaf(x0.x, W1s[0*HR + j64], a);
                a = fmaf(x0.y, W1s[1*HR + j64], a);
                a = fmaf(x0.z, W1s[2*HR + j64], a);
                a = fmaf(x0.w, W1s[3*HR + j64], a);
                a = fmaf(x1.x, W1s[4*HR + j64], a);
                a = fmaf(x1.y, W1s[5*HR + j64], a);
                a = fmaf(x1.z, W1s[6*HR + j64], a);
                a = fmaf(x1.w, W1s[7*HR + j64], a);
            }
            hB[buf][e][j64] = f2bf(a / (1.f + expf(-a)));
        }
        __syncthreads();   // (1) hB/sndS ready; rwB[buf] reads from 2 groups ago complete

        // ---- phase B (MFMA): rw0[16 e][128 f] = h(16x64) @ W2_l0(64x128)
        {
            short8 a0 = *(const short8*)&hB[buf][r16][quad*8];
            short8 a1 = *(const short8*)&hB[buf][r16][32 + quad*8];
            #pragma unroll
            for (int nt = 0; nt < 2; ++nt) {
                const int col = wv*32 + nt*16 + r16;
                short8 b0 = *(const short8*)(W2T0l + (size_t)col*64 + quad*8);
                short8 b1 = *(const short8*)(W2T0l + (size_t)col*64 + 32 + quad*8);
                f32x4 c = (f32x4){0.f, 0.f, 0.f, 0.f};
                c = __builtin_amdgcn_mfma_f32_16x16x32_bf16(a0, b0, c, 0, 0, 0);
                c = __builtin_amdgcn_mfma_f32_16x16x32_bf16(a1, b1, c, 0, 0, 0);
                #pragma unroll
                for (int r = 0; r < 4; ++r)
                    rwB[buf][quad*4 + r][col] = f2bf(c[r]);
            }
        }
        __syncthreads();   // (2) rwB[buf] ready

        // ---- phase C: acc[f] += sf[e][f] * rw0[e][f]  (half-block handles 8 edges)
        #pragma unroll
        for (int e8 = 0; e8 < 8; ++e8) {
            const int e = mh*8 + e8;
            if (e < gcnt) {
                const int snd = sndS[buf][e];
                const float sf = bfu(fB_in[(size_t)snd*128 + f]);
                const float rl = bfu(rwB[buf][e][f]);
                acc = fmaf(sf, rl, acc);
            }
        }
        // no trailing barrier: dbuf + next iteration's barriers order reuse
    }

    if (mh == 1) accS[f] = acc;
    __syncthreads();
    if (mh == 0) aggB0[(size_t)pn[n]*128 + f] = f2bf(acc + accS[f]);
}

// ---------------- bf16 MFMA grouped GEMM (single m-plane): out[rows][f] = A[rows][f2] x W[spec]^T ----------------
__global__ __launch_bounds__(256) void k_gemm0(
    const ushort_t* __restrict__ A,     // [NPAD][128] bf16
    const ushort_t* __restrict__ WB,    // [NSPEC][128][128] bf16 transposed
    const int* __restrict__ tile_spec,
    float* __restrict__ outF)           // [NPAD][128] f32
{
    const int tile = blockIdx.x;
    const int spec = tile_spec[tile];
    if (spec < 0) return;
    const int t = threadIdx.x;
    const int lane = t & 63;
    const int wv = t >> 6;
    const int r16 = lane & 15;
    const int quad = lane >> 4;

    const ushort_t* Ap = A + (size_t)tile*16*128;
    const ushort_t* Wp = WB + (size_t)spec*16384;

    short8 a[4];
    #pragma unroll
    for (int c = 0; c < 4; ++c)
        a[c] = *(const short8*)(Ap + (size_t)r16*128 + c*32 + quad*8);

    #pragma unroll
    for (int nt = 0; nt < 2; ++nt) {
        const int col = wv*32 + nt*16 + r16;
        f32x4 acc = (f32x4){0.f, 0.f, 0.f, 0.f};
        #pragma unroll
        for (int c = 0; c < 4; ++c) {
            short8 b = *(const short8*)(Wp + (size_t)col*128 + c*32 + quad*8);
            acc = __builtin_amdgcn_mfma_f32_16x16x32_bf16(a[c], b, acc, 0, 0, 0);
        }
        #pragma unroll
        for (int r = 0; r < 4; ++r)
            outF[((size_t)tile*16 + quad*4 + r)*128 + col] = acc[r];
    }
}

// ---------------- layer-0 epilogue: poly gate + next scal (bf16) + readout0 ----------------
__global__ __launch_bounds__(128) void k_epi0(
    const int* __restrict__ specS, const int* __restrict__ pn, const int* __restrict__ perm,
    const float* __restrict__ out0, const float* __restrict__ prodc,
    const float* __restrict__ ro0,
    ushort_t* __restrict__ fB1, float* __restrict__ out)
{
    __shared__ float redS[F];
    const int t = threadIdx.x, n = blockIdx.x;
    const int row = pn[n];
    const float* pc = prodc + (size_t)specS[n]*3*F;   // layer 0
    float s = out0[(size_t)row*128 + t] * 0.5f;       // new0 (EPS applied)
    float poly = pc[t] + pc[F+t]*s + pc[2*F+t]*s*s;
    float val = s * poly;                             // feats1 m0
    fB1[(size_t)row*128 + t] = f2bf(val);
    redS[t] = val * ro0[t];
    __syncthreads();
    #pragma unroll
    for (int off = 64; off > 0; off >>= 1) {
        if (t < off) redS[t] += redS[t + off];
        __syncthreads();
    }
    if (t == 0) out[(size_t)perm[n]*2 + 0] = redS[0];
}

// ---------------- layer-1 epilogue: poly + sc + readout1 (silu MLP) ----------------
__global__ __launch_bounds__(128) void k_epi1(
    const int* __restrict__ specS, const int* __restrict__ pn, const int* __restrict__ perm,
    const float* __restrict__ linO, const float* __restrict__ scO,
    const float* __restrict__ prodc,
    const float* __restrict__ ro1W1, const float* __restrict__ ro1W2,
    float* __restrict__ out)
{
    __shared__ float sS[F];
    __shared__ float yS[16];
    const int t = threadIdx.x, n = blockIdx.x;
    const int row = pn[n];
    const float* pc = prodc + ((size_t)NSPEC + specS[n])*3*F;   // layer 1
    float s = linO[(size_t)row*128 + t] * 0.5f;
    float poly = pc[t] + pc[F+t]*s + pc[2*F+t]*s*s;
    sS[t] = s * poly + scO[(size_t)row*128 + t];   // scal after layer 1
    __syncthreads();
    if (t < 16) {
        float a = 0.f;
        for (int g = 0; g < F; ++g) a = fmaf(sS[g], ro1W1[g*16 + t], a);
        a = silu_f(a);
        yS[t] = a * ro1W2[t];
    }
    __syncthreads();
    if (t == 0) {
        float sum = 0.f;
        #pragma unroll
        for (int j = 0; j < 16; ++j) sum += yS[j];
        out[(size_t)perm[n]*2 + 1] = sum;
    }
}

extern "C" void kernel_launch(void* const* d_in, const int* in_sizes, int n_in,
                              void* d_out, int out_size, void* d_ws, size_t ws_size,
                              hipStream_t stream)
{
    (void)in_sizes; (void)n_in; (void)out_size; (void)ws_size;
    const float* vectors   = (const float*)d_in[0];
    const int*   spec      = (const int*)d_in[1];
    const int*   senders   = (const int*)d_in[2];
    const int*   receivers = (const int*)d_in[3];
    const float* embW      = (const float*)d_in[4];
    const float* rW1       = (const float*)d_in[5];
    const float* rb1       = (const float*)d_in[6];
    const float* rW2       = (const float*)d_in[7];
    const float* linW      = (const float*)d_in[8];
    const float* prodc     = (const float*)d_in[9];
    const float* scW       = (const float*)d_in[10];
    const float* ro0       = (const float*)d_in[11];
    const float* ro1W1     = (const float*)d_in[12];
    const float* ro1W2     = (const float*)d_in[13];
    float* out = (float*)d_out;

    char* ws = (char*)d_ws;
    float*    basis_pos = (float*)ws;    ws += sizeof(float)*(size_t)N_EDGES*8;       // 5.1 MB
    float*    out0      = (float*)ws;    ws += sizeof(float)*(size_t)NPAD*128;        // 5.2
    float*    linO      = (float*)ws;    ws += sizeof(float)*(size_t)NPAD*128;        // 5.2
    float*    scO       = (float*)ws;    ws += sizeof(float)*(size_t)NPAD*128;        // 5.2
    ushort_t* fB0       = (ushort_t*)ws; ws += sizeof(ushort_t)*(size_t)NPAD*128;     // 2.6
    ushort_t* fB1       = (ushort_t*)ws; ws += sizeof(ushort_t)*(size_t)NPAD*128;     // 2.6
    ushort_t* aggB0     = (ushort_t*)ws; ws += sizeof(ushort_t)*(size_t)NPAD*128;     // 2.6
    ushort_t* WBlin0    = (ushort_t*)ws; ws += sizeof(ushort_t)*(size_t)2*NSPEC*16384;// 0.66
    ushort_t* WBsc0     = (ushort_t*)ws; ws += sizeof(ushort_t)*(size_t)NSPEC*16384;  // 0.33
    ushort_t* W2T0      = (ushort_t*)ws; ws += sizeof(ushort_t)*(size_t)2*128*64;     // 0.03
    int* snd_pos   = (int*)ws; ws += sizeof(int)*N_EDGES;
    int* row_ptr   = (int*)ws; ws += sizeof(int)*(N_NODES+1);
    // zeroed region: counts, cursor, scnt, scur (contiguous)
    int* counts    = (int*)ws; ws += sizeof(int)*N_NODES;
    int* cursor    = (int*)ws; ws += sizeof(int)*N_NODES;
    int* scnt      = (int*)ws; ws += sizeof(int)*16;
    int* scur      = (int*)ws; ws += sizeof(int)*16;
    int* sptr      = (int*)ws; ws += sizeof(int)*16;
    int* psptr     = (int*)ws; ws += sizeof(int)*16;
    int* perm      = (int*)ws; ws += sizeof(int)*N_NODES;
    int* inv       = (int*)ws; ws += sizeof(int)*N_NODES;
    int* specS     = (int*)ws; ws += sizeof(int)*N_NODES;
    int* pn        = (int*)ws; ws += sizeof(int)*N_NODES;
    int* tile_spec = (int*)ws; ws += sizeof(int)*NT_MAX;
    int* elist     = (int*)ws; ws += sizeof(int)*N_EDGES;

    hipMemsetAsync(counts, 0, sizeof(int)*(2*N_NODES + 32), stream);

    const int EB  = (N_EDGES + 255) / 256;
    const int NBK = (N_NODES + 255) / 256;

    k_scnt<<<NBK, 256, 0, stream>>>(spec, scnt);
    k_sscan<<<1, 64, 0, stream>>>(scnt, sptr, psptr, tile_spec);
    k_sfill<<<NBK, 256, 0, stream>>>(spec, sptr, psptr, scur, perm, inv, specS, pn);
    k_count<<<EB, 256, 0, stream>>>(receivers, inv, counts);
    k_scan<<<1, 1024, 0, stream>>>(counts, row_ptr);
    k_fill<<<EB, 256, 0, stream>>>(receivers, inv, row_ptr, cursor, elist);
    k_edge_pre<<<EB, 256, 0, stream>>>(elist, senders, inv, pn, vectors, basis_pos, snd_pos);
    k_init_f0<<<(N_NODES*F + 255)/256, 256, 0, stream>>>(specS, pn, embW, fB0);
    k_conv_w<<<(3*NSPEC*16384 + 255)/256, 256, 0, stream>>>(linW, scW, WBlin0, WBsc0);
    k_conv_w2<<<(2*128*64 + 255)/256, 256, 0, stream>>>(rW2, W2T0);

    // ---- layer 0 (m=0 path only) ----
    k_edge<<<N_NODES, 256, 0, stream>>>(0, row_ptr, snd_pos, pn, basis_pos,
        rW1, rb1, W2T0, fB0, aggB0);
    k_gemm0<<<NT_MAX, 256, 0, stream>>>(aggB0, WBlin0, tile_spec, out0);
    k_epi0<<<N_NODES, 128, 0, stream>>>(specS, pn, perm, out0, prodc, ro0, fB1, out);

    // ---- layer 1 (m=0 path only) ----
    k_edge<<<N_NODES, 256, 0, stream>>>(1, row_ptr, snd_pos, pn, basis_pos,
        rW1, rb1, W2T0 + 128*64, fB1, aggB0);
    k_gemm0<<<NT_MAX, 256, 0, stream>>>(aggB0, WBlin0 + (size_t)NSPEC*16384, tile_spec, linO);
    k_gemm0<<<NT_MAX, 256, 0, stream>>>(fB1, WBsc0, tile_spec, scO);
    k_epi1<<<N_NODES, 128, 0, stream>>>(specS, pn, perm, linO, scO, prodc, ro1W1, ro1W2, out);
}

// Round 14
// 346.497 us; speedup vs baseline: 24.6158x; 1.0767x over previous
//
#include <hip/hip_runtime.h>
#include <math.h>
#include <stdint.h>

#define N_NODES 10000
#define N_EDGES 160000
#define F 128
#define NB 8
#define HR 64
#define NSPEC 10
#define PI_F 3.14159265358979323846f
#define NPAD 10160
#define NT_MAX 635
#define ETILES 2500   // N_EDGES / 64

typedef unsigned short ushort_t;
typedef __attribute__((ext_vector_type(8))) short short8;   // 8 bf16 = 4 VGPRs
typedef __attribute__((ext_vector_type(4))) float f32x4;    // 4 fp32 acc

__device__ __forceinline__ float silu_f(float x){ return x / (1.f + expf(-x)); }
__device__ __forceinline__ float bfu(ushort_t u) {
    union { unsigned int i; float f; } v; v.i = ((unsigned int)u) << 16; return v.f;
}
__device__ __forceinline__ ushort_t f2bf(float f) {
    union { float f; unsigned int i; } v; v.f = f;
    unsigned int x = v.i;
    unsigned int r = (x + 0x7fffu + ((x >> 16) & 1u)) >> 16;
    return (ushort_t)r;
}

// ---------------- species counting sort ----------------
__global__ void k_scnt(const int* __restrict__ spec, int* __restrict__ scnt)
{
    int n = blockIdx.x * 256 + threadIdx.x;
    if (n < N_NODES) atomicAdd(&scnt[spec[n]], 1);
}

__global__ void k_sscan(const int* __restrict__ scnt, int* __restrict__ sptr,
                        int* __restrict__ psptr, int* __restrict__ tile_spec)
{
    if (threadIdx.x == 0) {
        int acc = 0, pacc = 0;
        for (int s = 0; s < NSPEC; ++s) {
            sptr[s] = acc; psptr[s] = pacc;
            acc += scnt[s];
            pacc += ((scnt[s] + 15) >> 4) << 4;
        }
        sptr[NSPEC] = acc; psptr[NSPEC] = pacc;
        for (int tt = 0; tt < NT_MAX; ++tt) tile_spec[tt] = -1;
        for (int s = 0; s < NSPEC; ++s) {
            int t0 = psptr[s] >> 4;
            int t1 = t0 + ((scnt[s] + 15) >> 4);
            for (int tt = t0; tt < t1; ++tt) tile_spec[tt] = s;
        }
    }
}

__global__ void k_sfill(const int* __restrict__ spec, const int* __restrict__ sptr,
                        const int* __restrict__ psptr,
                        int* __restrict__ scur, int* __restrict__ perm,
                        int* __restrict__ inv, int* __restrict__ specS,
                        int* __restrict__ pn)
{
    int n = blockIdx.x * 256 + threadIdx.x;
    if (n >= N_NODES) return;
    int s = spec[n];
    int pos = sptr[s] + atomicAdd(&scur[s], 1);
    perm[pos] = n; inv[n] = pos; specS[pos] = s;
    pn[pos] = psptr[s] + (pos - sptr[s]);
}

// ---------------- receiver histogram (sorted ids) ----------------
__global__ void k_count(const int* __restrict__ recv, const int* __restrict__ inv,
                        int* __restrict__ counts)
{
    int e = blockIdx.x * 256 + threadIdx.x;
    if (e >= N_EDGES) return;
    atomicAdd(&counts[inv[recv[e]]], 1);
}

// ---------------- block-wide scan -> row_ptr ----------------
__global__ void k_scan(const int* __restrict__ counts, int* __restrict__ row_ptr)
{
    __shared__ int ps[1024];
    const int t = threadIdx.x;
    int base = t * 10;
    int loc[10];
    int sum = 0;
    #pragma unroll
    for (int j = 0; j < 10; ++j) {
        int idx = base + j;
        int c = (idx < N_NODES) ? counts[idx] : 0;
        loc[j] = c; sum += c;
    }
    ps[t] = sum;
    __syncthreads();
    for (int off = 1; off < 1024; off <<= 1) {
        int v = (t >= off) ? ps[t-off] : 0;
        __syncthreads();
        ps[t] += v;
        __syncthreads();
    }
    int ex = ps[t] - sum;
    #pragma unroll
    for (int j = 0; j < 10; ++j) {
        int idx = base + j;
        if (idx < N_NODES) row_ptr[idx] = ex;
        ex += loc[j];
    }
    if (t == 1023) row_ptr[N_NODES] = ex;
}

// ---------------- CSR fill fused with basis + sender-row precompute (position order) ----------------
__global__ void k_fill_pre(const int* __restrict__ recv, const int* __restrict__ senders,
                           const int* __restrict__ inv, const int* __restrict__ pn,
                           const int* __restrict__ row_ptr, int* __restrict__ cursor,
                           const float* __restrict__ vec,
                           float* __restrict__ basis_pos, int* __restrict__ sndrow)
{
    int e = blockIdx.x * 256 + threadIdx.x;
    if (e >= N_EDGES) return;
    int r = inv[recv[e]];
    int q = row_ptr[r] + atomicAdd(&cursor[r], 1);
    sndrow[q] = pn[inv[senders[e]]];
    float x = vec[e*3+0], y = vec[e*3+1], z = vec[e*3+2];
    float rr = sqrtf(x*x + y*y + z*z);
    rr = fmaxf(rr, 1e-9f);
    float rc = fminf(rr, 5.0f);
    float cut = 0.5f * (cosf(PI_F * rc * 0.2f) + 1.f);
    float pref = sqrtf(0.4f) * cut / rr;
    float B[8];
    #pragma unroll
    for (int k = 1; k <= 8; ++k) B[k-1] = pref * sinf(PI_F * 0.2f * (float)k * rr);
    float4* dst = (float4*)(basis_pos + (size_t)q*8);
    dst[0] = make_float4(B[0], B[1], B[2], B[3]);
    dst[1] = make_float4(B[4], B[5], B[6], B[7]);
}

// ---------------- init fB0 = emb (bf16, padded rows) ----------------
__global__ void k_init_f0(const int* __restrict__ specS, const int* __restrict__ pn,
                          const float* __restrict__ embW, ushort_t* __restrict__ fB0)
{
    int tid = blockIdx.x * 256 + threadIdx.x;
    if (tid >= N_NODES * F) return;
    int n = tid >> 7, f = tid & 127;
    fB0[(size_t)pn[n]*128 + f] = f2bf(embW[specS[n]*F + f]);
}

// ---------------- fused weight conversion: lin l=0 (2 layers), sc l=0 (layer1), W2 l=0 cols ----------------
__global__ void k_conv(const float* __restrict__ linW, const float* __restrict__ scW,
                       const float* __restrict__ rW2,
                       ushort_t* __restrict__ WBlin0, ushort_t* __restrict__ WBsc0,
                       ushort_t* __restrict__ W2T0)
{
    int tid = blockIdx.x * 256 + threadIdx.x;
    const int LINTOT = 2*NSPEC*16384;
    const int SCTOT  = NSPEC*16384;
    if (tid < LINTOT) {
        int mat = tid >> 14;                 // layer*10+spec
        int r = tid & 16383;
        int fo = r >> 7, fi = r & 127;
        WBlin0[(size_t)mat*16384 + fo*128 + fi] =
            f2bf(linW[((size_t)mat*4 + 0)*16384 + fi*128 + fo]);
    } else if (tid < LINTOT + SCTOT) {
        int t2 = tid - LINTOT;
        int spec = t2 >> 14;
        int r = t2 & 16383;
        int fo = r >> 7, fi = r & 127;
        WBsc0[(size_t)spec*16384 + fo*128 + fi] =
            f2bf(scW[((size_t)(NSPEC + spec)*4 + 0)*16384 + fi*128 + fo]);   // layer 1
    } else if (tid < LINTOT + SCTOT + 2*128*64) {
        int t2 = tid - LINTOT - SCTOT;
        int l = t2 >> 13; int r = t2 & 8191; int f = r >> 6; int k = r & 63;
        W2T0[t2] = f2bf(rW2[(size_t)l*HR*512 + (size_t)k*512 + 4*f]);
    }
}

// ---------------- edge-parallel radial MLP (both layers): rw0[l][p][128] bf16 ----------------
// 2500 blocks x 256 threads; wave wv owns positions base+wv*16+0..15 independently
__global__ __launch_bounds__(256) void k_rw(
    const float* __restrict__ basis_pos,
    const float* __restrict__ rW1,
    const float* __restrict__ rb1,
    const ushort_t* __restrict__ W2T0,
    ushort_t* __restrict__ rw0)
{
    __shared__ float W1s[2][NB*HR];         // 4 KB
    __shared__ float b1s[2][HR];            // 512 B
    __shared__ ushort_t hB[4][16][72];      // 9.2 KB

    const int t = threadIdx.x;
    const int wv = t >> 6;
    const int lane = t & 63;
    const int j64 = lane;
    const int r16 = lane & 15;
    const int quad = lane >> 4;

    W1s[0][t] = rW1[t];       W1s[0][256 + t] = rW1[256 + t];
    W1s[1][t] = rW1[512 + t]; W1s[1][256 + t] = rW1[768 + t];
    if (t < HR) { b1s[0][t] = rb1[t]; b1s[1][t] = rb1[HR + t]; }

    const int p0 = blockIdx.x * 64 + wv * 16;
    __syncthreads();

    for (int l = 0; l < 2; ++l) {
        // ---- phase A: h (bf16) for this wave's 16 positions
        #pragma unroll 4
        for (int e = 0; e < 16; ++e) {
            const float4* B4 = (const float4*)(basis_pos + (size_t)(p0 + e)*8);
            float4 x0 = B4[0], x1 = B4[1];
            float a = b1s[l][j64];
            a = fmaf(x0.x, W1s[l][0*HR + j64], a);
            a = fmaf(x0.y, W1s[l][1*HR + j64], a);
            a = fmaf(x0.z, W1s[l][2*HR + j64], a);
            a = fmaf(x0.w, W1s[l][3*HR + j64], a);
            a = fmaf(x1.x, W1s[l][4*HR + j64], a);
            a = fmaf(x1.y, W1s[l][5*HR + j64], a);
            a = fmaf(x1.z, W1s[l][6*HR + j64], a);
            a = fmaf(x1.w, W1s[l][7*HR + j64], a);
            hB[wv][e][j64] = f2bf(a / (1.f + expf(-a)));
        }
        __syncthreads();

        // ---- phase B: MFMA rw0_l[16 pos][128 f] = h(16x64) @ W2_l0(64x128)
        {
            short8 a0 = *(const short8*)&hB[wv][r16][quad*8];
            short8 a1 = *(const short8*)&hB[wv][r16][32 + quad*8];
            const ushort_t* W2l = W2T0 + l*8192;
            ushort_t* dst = rw0 + (size_t)l*N_EDGES*128;
            #pragma unroll
            for (int nt = 0; nt < 8; ++nt) {
                const int col = nt*16 + r16;
                short8 b0 = *(const short8*)(W2l + (size_t)col*64 + quad*8);
                short8 b1 = *(const short8*)(W2l + (size_t)col*64 + 32 + quad*8);
                f32x4 c = (f32x4){0.f, 0.f, 0.f, 0.f};
                c = __builtin_amdgcn_mfma_f32_16x16x32_bf16(a0, b0, c, 0, 0, 0);
                c = __builtin_amdgcn_mfma_f32_16x16x32_bf16(a1, b1, c, 0, 0, 0);
                #pragma unroll
                for (int r = 0; r < 4; ++r)
                    dst[(size_t)(p0 + quad*4 + r)*128 + col] = f2bf(c[r]);
            }
        }
        __syncthreads();   // hB reuse for next layer
    }
}

// ---------------- per-node m=0 aggregation: aggB0[row][f] = sum_p scal[snd]*rw0[p] ----------------
// 2 nodes per 256-thread block
__global__ __launch_bounds__(256) void k_agg0(
    const int* __restrict__ row_ptr,
    const int* __restrict__ sndrow,
    const int* __restrict__ pn,
    const ushort_t* __restrict__ rw0l,
    const ushort_t* __restrict__ fB_in,
    ushort_t* __restrict__ aggB0)
{
    const int t = threadIdx.x;
    const int n = blockIdx.x*2 + (t >> 7);
    const int f = t & 127;
    const int p0 = row_ptr[n], p1 = row_ptr[n+1];
    float acc = 0.f;
    #pragma unroll 4
    for (int p = p0; p < p1; ++p) {
        const int snd = sndrow[p];
        const float sf = bfu(fB_in[(size_t)snd*128 + f]);
        const float rl = bfu(rw0l[(size_t)p*128 + f]);
        acc = fmaf(sf, rl, acc);
    }
    aggB0[(size_t)pn[n]*128 + f] = f2bf(acc);
}

// ---------------- layer-0 fused: lin GEMM + poly + fB1 write + readout0 ----------------
__global__ __launch_bounds__(256) void k_gemm_epi0(
    const ushort_t* __restrict__ aggB0,
    const ushort_t* __restrict__ WBlin0,
    const int* __restrict__ tile_spec,
    const int* __restrict__ scnt, const int* __restrict__ sptr,
    const int* __restrict__ psptr, const int* __restrict__ perm,
    const float* __restrict__ prodc, const float* __restrict__ ro0,
    ushort_t* __restrict__ fB1, float* __restrict__ out)
{
    __shared__ float redS[16][65];
    const int tile = blockIdx.x;
    const int spec = tile_spec[tile];
    if (spec < 0) return;
    const int t = threadIdx.x;
    const int lane = t & 63;
    const int wv = t >> 6;
    const int r16 = lane & 15;
    const int quad = lane >> 4;

    const ushort_t* Ap = aggB0 + (size_t)tile*16*128;
    const ushort_t* Wp = WBlin0 + (size_t)spec*16384;
    const float* pc = prodc + (size_t)spec*3*F;

    short8 a[4];
    #pragma unroll
    for (int c = 0; c < 4; ++c)
        a[c] = *(const short8*)(Ap + (size_t)r16*128 + c*32 + quad*8);

    float pr[4] = {0.f, 0.f, 0.f, 0.f};
    #pragma unroll
    for (int nt = 0; nt < 2; ++nt) {
        const int col = wv*32 + nt*16 + r16;
        f32x4 acc = (f32x4){0.f, 0.f, 0.f, 0.f};
        #pragma unroll
        for (int c = 0; c < 4; ++c) {
            short8 b = *(const short8*)(Wp + (size_t)col*128 + c*32 + quad*8);
            acc = __builtin_amdgcn_mfma_f32_16x16x32_bf16(a[c], b, acc, 0, 0, 0);
        }
        const float w0 = ro0[col];
        const float p0c = pc[col], p1c = pc[F+col], p2c = pc[2*F+col];
        #pragma unroll
        for (int r = 0; r < 4; ++r) {
            float s = acc[r] * 0.5f;
            float val = s * (p0c + p1c*s + p2c*s*s);
            fB1[((size_t)tile*16 + quad*4 + r)*128 + col] = f2bf(val);
            pr[r] = fmaf(val, w0, pr[r]);
        }
    }
    #pragma unroll
    for (int r = 0; r < 4; ++r) redS[quad*4 + r][wv*16 + r16] = pr[r];
    __syncthreads();
    if (t < 16) {
        int rel = tile*16 + t - psptr[spec];
        if (rel < scnt[spec]) {
            float s = 0.f;
            for (int j = 0; j < 64; ++j) s += redS[t][j];
            out[(size_t)perm[sptr[spec] + rel]*2 + 0] = s;
        }
    }
}

// ---------------- layer-1 fused: lin GEMM + sc GEMM + poly + MLP readout1 ----------------
__global__ __launch_bounds__(256) void k_gemm_epi1(
    const ushort_t* __restrict__ aggB0,
    const ushort_t* __restrict__ fB1,
    const ushort_t* __restrict__ WBlin1,
    const ushort_t* __restrict__ WBsc0,
    const int* __restrict__ tile_spec,
    const int* __restrict__ scnt, const int* __restrict__ sptr,
    const int* __restrict__ psptr, const int* __restrict__ perm,
    const float* __restrict__ prodc,
    const float* __restrict__ ro1W1, const float* __restrict__ ro1W2,
    float* __restrict__ out)
{
    __shared__ float sS[16][132];
    __shared__ float yS[16][17];
    const int tile = blockIdx.x;
    const int spec = tile_spec[tile];
    if (spec < 0) return;
    const int t = threadIdx.x;
    const int lane = t & 63;
    const int wv = t >> 6;
    const int r16 = lane & 15;
    const int quad = lane >> 4;

    const ushort_t* Ap = aggB0 + (size_t)tile*16*128;
    const ushort_t* Fp = fB1   + (size_t)tile*16*128;
    const ushort_t* Wl = WBlin1 + (size_t)spec*16384;
    const ushort_t* Ws = WBsc0  + (size_t)spec*16384;
    const float* pc = prodc + ((size_t)NSPEC + spec)*3*F;

    short8 a1[4], a2[4];
    #pragma unroll
    for (int c = 0; c < 4; ++c) {
        a1[c] = *(const short8*)(Ap + (size_t)r16*128 + c*32 + quad*8);
        a2[c] = *(const short8*)(Fp + (size_t)r16*128 + c*32 + quad*8);
    }

    #pragma unroll
    for (int nt = 0; nt < 2; ++nt) {
        const int col = wv*32 + nt*16 + r16;
        f32x4 accl = (f32x4){0.f, 0.f, 0.f, 0.f};
        f32x4 accs = (f32x4){0.f, 0.f, 0.f, 0.f};
        #pragma unroll
        for (int c = 0; c < 4; ++c) {
            short8 bl = *(const short8*)(Wl + (size_t)col*128 + c*32 + quad*8);
            short8 bs = *(const short8*)(Ws + (size_t)col*128 + c*32 + quad*8);
            accl = __builtin_amdgcn_mfma_f32_16x16x32_bf16(a1[c], bl, accl, 0, 0, 0);
            accs = __builtin_amdgcn_mfma_f32_16x16x32_bf16(a2[c], bs, accs, 0, 0, 0);
        }
        const float p0c = pc[col], p1c = pc[F+col], p2c = pc[2*F+col];
        #pragma unroll
        for (int r = 0; r < 4; ++r) {
            float s = accl[r] * 0.5f;
            sS[quad*4 + r][col] = s * (p0c + p1c*s + p2c*s*s) + accs[r];
        }
    }
    __syncthreads();

    {   // per-node 128->16 silu MLP
        const int node = t >> 4, c = t & 15;
        float a = 0.f;
        #pragma unroll 8
        for (int g = 0; g < F; ++g) a = fmaf(sS[node][g], ro1W1[g*16 + c], a);
        a = silu_f(a);
        yS[node][c] = a * ro1W2[c];
    }
    __syncthreads();
    if (t < 16) {
        int rel = tile*16 + t - psptr[spec];
        if (rel < scnt[spec]) {
            float s = 0.f;
            #pragma unroll
            for (int j = 0; j < 16; ++j) s += yS[t][j];
            out[(size_t)perm[sptr[spec] + rel]*2 + 1] = s;
        }
    }
}

extern "C" void kernel_launch(void* const* d_in, const int* in_sizes, int n_in,
                              void* d_out, int out_size, void* d_ws, size_t ws_size,
                              hipStream_t stream)
{
    (void)in_sizes; (void)n_in; (void)out_size; (void)ws_size;
    const float* vectors   = (const float*)d_in[0];
    const int*   spec      = (const int*)d_in[1];
    const int*   senders   = (const int*)d_in[2];
    const int*   receivers = (const int*)d_in[3];
    const float* embW      = (const float*)d_in[4];
    const float* rW1       = (const float*)d_in[5];
    const float* rb1       = (const float*)d_in[6];
    const float* rW2       = (const float*)d_in[7];
    const float* linW      = (const float*)d_in[8];
    const float* prodc     = (const float*)d_in[9];
    const float* scW       = (const float*)d_in[10];
    const float* ro0       = (const float*)d_in[11];
    const float* ro1W1     = (const float*)d_in[12];
    const float* ro1W2     = (const float*)d_in[13];
    float* out = (float*)d_out;

    char* ws = (char*)d_ws;
    float*    basis_pos = (float*)ws;    ws += sizeof(float)*(size_t)N_EDGES*8;        // 5.1 MB
    ushort_t* rw0       = (ushort_t*)ws; ws += sizeof(ushort_t)*(size_t)2*N_EDGES*128; // 81.9
    ushort_t* fB0       = (ushort_t*)ws; ws += sizeof(ushort_t)*(size_t)NPAD*128;      // 2.6
    ushort_t* fB1       = (ushort_t*)ws; ws += sizeof(ushort_t)*(size_t)NPAD*128;      // 2.6
    ushort_t* aggB0     = (ushort_t*)ws; ws += sizeof(ushort_t)*(size_t)NPAD*128;      // 2.6
    ushort_t* WBlin0    = (ushort_t*)ws; ws += sizeof(ushort_t)*(size_t)2*NSPEC*16384; // 0.66
    ushort_t* WBsc0     = (ushort_t*)ws; ws += sizeof(ushort_t)*(size_t)NSPEC*16384;   // 0.33
    ushort_t* W2T0      = (ushort_t*)ws; ws += sizeof(ushort_t)*(size_t)2*128*64;      // 0.03
    int* sndrow    = (int*)ws; ws += sizeof(int)*N_EDGES;
    int* row_ptr   = (int*)ws; ws += sizeof(int)*(N_NODES+1);
    // zeroed region: counts, cursor, scnt, scur (contiguous)
    int* counts    = (int*)ws; ws += sizeof(int)*N_NODES;
    int* cursor    = (int*)ws; ws += sizeof(int)*N_NODES;
    int* scnt      = (int*)ws; ws += sizeof(int)*16;
    int* scur      = (int*)ws; ws += sizeof(int)*16;
    int* sptr      = (int*)ws; ws += sizeof(int)*16;
    int* psptr     = (int*)ws; ws += sizeof(int)*16;
    int* perm      = (int*)ws; ws += sizeof(int)*N_NODES;
    int* inv       = (int*)ws; ws += sizeof(int)*N_NODES;
    int* specS     = (int*)ws; ws += sizeof(int)*N_NODES;
    int* pn        = (int*)ws; ws += sizeof(int)*N_NODES;
    int* tile_spec = (int*)ws; ws += sizeof(int)*NT_MAX;

    hipMemsetAsync(counts, 0, sizeof(int)*(2*N_NODES + 32), stream);

    const int EB  = (N_EDGES + 255) / 256;
    const int NBK = (N_NODES + 255) / 256;
    const int CONVTOT = 2*NSPEC*16384 + NSPEC*16384 + 2*128*64;

    k_scnt<<<NBK, 256, 0, stream>>>(spec, scnt);
    k_conv<<<(CONVTOT + 255)/256, 256, 0, stream>>>(linW, scW, rW2, WBlin0, WBsc0, W2T0);
    k_sscan<<<1, 64, 0, stream>>>(scnt, sptr, psptr, tile_spec);
    k_sfill<<<NBK, 256, 0, stream>>>(spec, sptr, psptr, scur, perm, inv, specS, pn);
    k_init_f0<<<(N_NODES*F + 255)/256, 256, 0, stream>>>(specS, pn, embW, fB0);
    k_count<<<EB, 256, 0, stream>>>(receivers, inv, counts);
    k_scan<<<1, 1024, 0, stream>>>(counts, row_ptr);
    k_fill_pre<<<EB, 256, 0, stream>>>(receivers, senders, inv, pn, row_ptr, cursor,
                                       vectors, basis_pos, sndrow);
    k_rw<<<ETILES, 256, 0, stream>>>(basis_pos, rW1, rb1, W2T0, rw0);

    // ---- layer 0 ----
    k_agg0<<<N_NODES/2, 256, 0, stream>>>(row_ptr, sndrow, pn, rw0, fB0, aggB0);
    k_gemm_epi0<<<NT_MAX, 256, 0, stream>>>(aggB0, WBlin0, tile_spec,
        scnt, sptr, psptr, perm, prodc, ro0, fB1, out);

    // ---- layer 1 ----
    k_agg0<<<N_NODES/2, 256, 0, stream>>>(row_ptr, sndrow, pn, rw0 + (size_t)N_EDGES*128, fB1, aggB0);
    k_gemm_epi1<<<NT_MAX, 256, 0, stream>>>(aggB0, fB1, WBlin0 + (size_t)NSPEC*16384, WBsc0,
        tile_spec, scnt, sptr, psptr, perm, prodc, ro1W1, ro1W2, out);
}